// Round 1
// baseline (1558.386 us; speedup 1.0000x reference)
//
#include <hip/hip_runtime.h>
#include <cstdint>
#include <cstddef>

// DynamicHierarchicalAttention — fp32 correctness-first pipeline.
// B=2 T=2048 D=512 H=8 HD=64.  All dynamic sizes (m1,m2,n_tok) computed on
// device in meta_kernel; all kernels launched with worst-case grids + early
// exit reading sizes from ws (graph-capture safe: identical work each call).

#define TB 2
#define TT 2048
#define TD 512
#define TH 8
#define THD 64

// meta slots (ints at start of ws)
#define MI_M1 0
#define MI_M2 1
#define MI_NTOK 2
#define MI_OFF_CW 3
#define MI_OFF_BW 4
#define MI_OFF_GW 5
#define MI_MCHAR 6
#define MI_MBLOCK 7
#define MI_MGLOB 8
#define MI_SEQC 9
#define MI_SEQB 10
#define MI_SEQG 11

__device__ __forceinline__ double fracd(double x) { return x - floor(x); }

// ---------------------------------------------------------------------------
// meta: c1/c2, block ids (f64 cum, margin >> 1e-9), run starts/counts, gmap.
// Thread 0 serial for scans (no dependent-load chains: cum = (i+1)*c direct),
// then parallel gmap fill (qualifying tokens are a contiguous suffix since
// ids1, ids2 are non-decreasing).
// ---------------------------------------------------------------------------
__global__ __launch_bounds__(256)
void meta_kernel(const float* __restrict__ mw, const float* __restrict__ mb,
                 const float* __restrict__ gw, const float* __restrict__ gb,
                 int* __restrict__ mi,
                 int* __restrict__ start1, float* __restrict__ cnt1,
                 int* __restrict__ start2, float* __restrict__ cnt2,
                 int* __restrict__ gmap)
{
  __shared__ int ids1[TT];
  __shared__ int ids2[TT];
  __shared__ int sh[1];
  const int t = threadIdx.x;
  if (t == 0) {
    double c1 = 0.0;
    for (int i = 0; i < TD; ++i) c1 += (double)mw[i];
    c1 += (double)mb[0];

    int id = 0, run = 0;
    double prev = fracd((double)TT * c1);   // frac[T-1] (roll wrap)
    for (int i = 0; i < TT; ++i) {
      double f = fracd((double)(i + 1) * c1);
      if (f < prev) {
        if (id >= 1) { start1[id - 1] = run; cnt1[id - 1] = (float)(i - run); }
        ++id; run = i;
      }
      ids1[i] = id;
      prev = f;
    }
    if (id >= 1) { start1[id - 1] = run; cnt1[id - 1] = (float)(TT - run); }
    const int m1 = id;

    double c2 = 0.0;
    for (int i = 0; i < TD; ++i) c2 += (double)gw[i];
    c2 += (double)gb[0];

    int id2 = 0, run2 = 0, j0 = -1;
    prev = fracd((double)m1 * c2);
    for (int i = 0; i < m1; ++i) {
      double f = fracd((double)(i + 1) * c2);
      if (f < prev) {
        if (id2 >= 1) { start2[id2 - 1] = run2; cnt2[id2 - 1] = (float)(i - run2); }
        ++id2; run2 = i;
        if (id2 == 1) j0 = i;
      }
      ids2[i] = id2;
      prev = f;
    }
    if (id2 >= 1) { start2[id2 - 1] = run2; cnt2[id2 - 1] = (float)(m1 - run2); }
    const int m2 = id2;

    // first token whose global id >= 1: token with ids1 >= j0+1
    int i0 = TT;
    if (m1 >= 1 && m2 >= 1 && j0 >= 0) i0 = start1[j0];
    const int ntok = TT - i0;
    sh[0] = i0;

    mi[MI_M1] = m1; mi[MI_M2] = m2; mi[MI_NTOK] = ntok;
    const int offcw = TB * ntok * TD;
    mi[MI_OFF_CW] = offcw;
    mi[MI_OFF_BW] = offcw + TB * TT * TT;
    mi[MI_OFF_GW] = offcw + TB * TT * TT + TB * m1 * m1;
    mi[MI_MCHAR] = TB * TT;
    mi[MI_MBLOCK] = TB * m1;
    mi[MI_MGLOB] = TB * m2;
    mi[MI_SEQC] = TT;
    mi[MI_SEQB] = m1;
    mi[MI_SEQG] = m2;
  }
  __syncthreads();
  const int i0 = sh[0];
  for (int i = i0 + t; i < TT; i += 256)
    gmap[i - i0] = ids2[ids1[i] - 1] - 1;
}

// ---------------------------------------------------------------------------
// C[M,N] = A[M,512] @ W[N,512]^T + bias.  128x128 tile, 8x8 split micro
// (row/col sets {ty*4+i, 64+ty*4+i} to keep LDS reads 2-way-conflict free).
// M dynamic via mi[m_slot]; worst-case grid, row-guarded.
// ---------------------------------------------------------------------------
__global__ __launch_bounds__(256)
void gemm_bias(const float* __restrict__ A, const float* __restrict__ W,
               const float* __restrict__ bias, float* __restrict__ C,
               const int* __restrict__ mi, int m_slot, int N)
{
  const int M = mi[m_slot];
  const int bm = blockIdx.y * 128;
  if (bm >= M) return;
  const int bn = blockIdx.x * 128;
  __shared__ float As[8][132];
  __shared__ float Ws[8][132];
  const int t = threadIdx.x;
  const int ty = t >> 4, tx = t & 15;
  const int lr = t >> 1;
  const int lc = (t & 1) << 2;
  float acc[8][8];
#pragma unroll
  for (int i = 0; i < 8; ++i)
#pragma unroll
    for (int j = 0; j < 8; ++j) acc[i][j] = 0.f;

  for (int kk = 0; kk < TD; kk += 8) {
    __syncthreads();
    float4 av = make_float4(0.f, 0.f, 0.f, 0.f);
    const int arow = bm + lr;
    if (arow < M) av = *(const float4*)&A[(size_t)arow * TD + kk + lc];
    const float4 wv = *(const float4*)&W[(size_t)(bn + lr) * TD + kk + lc];
    As[lc + 0][lr] = av.x; As[lc + 1][lr] = av.y; As[lc + 2][lr] = av.z; As[lc + 3][lr] = av.w;
    Ws[lc + 0][lr] = wv.x; Ws[lc + 1][lr] = wv.y; Ws[lc + 2][lr] = wv.z; Ws[lc + 3][lr] = wv.w;
    __syncthreads();
#pragma unroll
    for (int k = 0; k < 8; ++k) {
      const float4 a0 = *(const float4*)&As[k][ty * 4];
      const float4 a1 = *(const float4*)&As[k][ty * 4 + 64];
      const float4 b0 = *(const float4*)&Ws[k][tx * 4];
      const float4 b1 = *(const float4*)&Ws[k][tx * 4 + 64];
      const float ar[8] = {a0.x, a0.y, a0.z, a0.w, a1.x, a1.y, a1.z, a1.w};
      const float br[8] = {b0.x, b0.y, b0.z, b0.w, b1.x, b1.y, b1.z, b1.w};
#pragma unroll
      for (int i = 0; i < 8; ++i)
#pragma unroll
        for (int j = 0; j < 8; ++j)
          acc[i][j] = fmaf(ar[i], br[j], acc[i][j]);
    }
  }
#pragma unroll
  for (int i = 0; i < 8; ++i) {
    const int row = bm + ((i < 4) ? (ty * 4 + i) : (64 + ty * 4 + i - 4));
    if (row >= M) continue;
    float* cp = &C[(size_t)row * N + bn];
    float4 o0, o1;
    o0.x = acc[i][0] + bias[bn + tx * 4 + 0];
    o0.y = acc[i][1] + bias[bn + tx * 4 + 1];
    o0.z = acc[i][2] + bias[bn + tx * 4 + 2];
    o0.w = acc[i][3] + bias[bn + tx * 4 + 3];
    o1.x = acc[i][4] + bias[bn + 64 + tx * 4 + 0];
    o1.y = acc[i][5] + bias[bn + 64 + tx * 4 + 1];
    o1.z = acc[i][6] + bias[bn + 64 + tx * 4 + 2];
    o1.w = acc[i][7] + bias[bn + 64 + tx * 4 + 3];
    *(float4*)&cp[tx * 4] = o0;
    *(float4*)&cp[64 + tx * 4] = o1;
  }
}

// ---------------------------------------------------------------------------
// attention pass 1: per (b,h, 64 q rows): l[q] = sum_k exp(s/8) (no max
// shift, |s| small) and attn_out[q, h*64+d] = (sum_k exp(s/8) V) / l.
// 64x64 tiles, 4x4 micro on both QK^T and E@V.
// ---------------------------------------------------------------------------
__global__ __launch_bounds__(256)
void attn_pass1(const float* __restrict__ qkv, float* __restrict__ lbuf,
                float* __restrict__ aout, const int* __restrict__ mi, int seq_slot)
{
  const int seq = mi[seq_slot];
  const int q0 = blockIdx.x * 64;
  if (q0 >= seq) return;
  const int b = blockIdx.y >> 3, h = blockIdx.y & 7;
  const int t = threadIdx.x;
  const int ty = t >> 4, tx = t & 15;

  __shared__ float Qs[64][68];   // [d][q]
  __shared__ float Ks[64][68];   // [d][k]
  __shared__ float Vs[64][68];   // [k][d]
  __shared__ float Es[64][68];   // [k][q]
  __shared__ float Lp[64][17];
  __shared__ float Lrow[64];

#pragma unroll
  for (int rr = 0; rr < 4; ++rr) {
    const int l4 = rr * 256 + t;
    const int qi = l4 >> 4;
    const int d0 = (l4 & 15) << 2;
    float4 v = make_float4(0.f, 0.f, 0.f, 0.f);
    if (q0 + qi < seq)
      v = *(const float4*)&qkv[((size_t)(b * seq + q0 + qi)) * 1536 + h * 64 + d0];
    Qs[d0 + 0][qi] = v.x; Qs[d0 + 1][qi] = v.y; Qs[d0 + 2][qi] = v.z; Qs[d0 + 3][qi] = v.w;
  }
  if (t < 64) Lrow[t] = 0.f;

  float oacc[4][4];
#pragma unroll
  for (int i = 0; i < 4; ++i)
#pragma unroll
    for (int j = 0; j < 4; ++j) oacc[i][j] = 0.f;

  const int nkt = (seq + 63) >> 6;
  for (int kt = 0; kt < nkt; ++kt) {
    const int k0 = kt * 64;
    __syncthreads();
#pragma unroll
    for (int rr = 0; rr < 4; ++rr) {
      const int l4 = rr * 256 + t;
      const int ki = l4 >> 4;
      const int d0 = (l4 & 15) << 2;
      float4 kv = make_float4(0.f, 0.f, 0.f, 0.f);
      float4 vv = make_float4(0.f, 0.f, 0.f, 0.f);
      if (k0 + ki < seq) {
        const float* base = &qkv[((size_t)(b * seq + k0 + ki)) * 1536 + h * 64];
        kv = *(const float4*)(base + 512);
        kv.x = base[512 + d0 + 0]; kv.y = base[512 + d0 + 1];
        kv.z = base[512 + d0 + 2]; kv.w = base[512 + d0 + 3];
        vv = *(const float4*)(base + 1024 + d0);
      }
      Ks[d0 + 0][ki] = kv.x; Ks[d0 + 1][ki] = kv.y; Ks[d0 + 2][ki] = kv.z; Ks[d0 + 3][ki] = kv.w;
      *(float4*)&Vs[ki][d0] = vv;
    }
    __syncthreads();
    // scores: q = ty*4+i, k = tx*4+j
    float s[4][4];
#pragma unroll
    for (int i = 0; i < 4; ++i)
#pragma unroll
      for (int j = 0; j < 4; ++j) s[i][j] = 0.f;
#pragma unroll 8
    for (int dd = 0; dd < 64; ++dd) {
      const float4 qa = *(const float4*)&Qs[dd][ty * 4];
      const float4 kb = *(const float4*)&Ks[dd][tx * 4];
      const float a[4] = {qa.x, qa.y, qa.z, qa.w};
      const float bb[4] = {kb.x, kb.y, kb.z, kb.w};
#pragma unroll
      for (int i = 0; i < 4; ++i)
#pragma unroll
        for (int j = 0; j < 4; ++j)
          s[i][j] = fmaf(a[i], bb[j], s[i][j]);
    }
#pragma unroll
    for (int i = 0; i < 4; ++i) {
      float lpi = 0.f;
#pragma unroll
      for (int j = 0; j < 4; ++j) {
        const int kg = k0 + tx * 4 + j;
        const float e = (kg < seq) ? __expf(s[i][j] * 0.125f) : 0.f;
        Es[tx * 4 + j][ty * 4 + i] = e;
        lpi += e;
      }
      Lp[ty * 4 + i][tx] = lpi;
    }
    __syncthreads();
    // E @ V : q = ty*4+i, d = tx*4+j
#pragma unroll 8
    for (int k = 0; k < 64; ++k) {
      const float4 e4 = *(const float4*)&Es[k][ty * 4];
      const float4 v4 = *(const float4*)&Vs[k][tx * 4];
      const float e[4] = {e4.x, e4.y, e4.z, e4.w};
      const float v[4] = {v4.x, v4.y, v4.z, v4.w};
#pragma unroll
      for (int i = 0; i < 4; ++i)
#pragma unroll
        for (int j = 0; j < 4; ++j)
          oacc[i][j] = fmaf(e[i], v[j], oacc[i][j]);
    }
    if (t < 64) {
      float ss = 0.f;
#pragma unroll
      for (int xx = 0; xx < 16; ++xx) ss += Lp[t][xx];
      Lrow[t] += ss;
    }
  }
  __syncthreads();
#pragma unroll
  for (int i = 0; i < 4; ++i) {
    const int q = ty * 4 + i;
    const int qg = q0 + q;
    if (qg < seq) {
      const float invl = 1.f / Lrow[q];
      float4 o;
      o.x = oacc[i][0] * invl; o.y = oacc[i][1] * invl;
      o.z = oacc[i][2] * invl; o.w = oacc[i][3] * invl;
      *(float4*)&aout[((size_t)(b * seq + qg)) * 512 + h * 64 + tx * 4] = o;
    }
  }
  if (t < 64 && q0 + t < seq)
    lbuf[(size_t)blockIdx.y * 2048 + q0 + t] = Lrow[t];
}

// ---------------------------------------------------------------------------
// attention pass 2: w[b,q,k] = (1/8) * sum_h exp(s/8)/l.  128x128 tile,
// 8x8 split micro, loop heads inside, write to d_out at dynamic offset.
// ---------------------------------------------------------------------------
__global__ __launch_bounds__(256)
void attn_pass2(const float* __restrict__ qkv, const float* __restrict__ lbuf,
                float* __restrict__ outb, const int* __restrict__ mi,
                int seq_slot, int off_slot)
{
  const int seq = mi[seq_slot];
  const int q0 = blockIdx.y * 128;
  const int k0 = blockIdx.x * 128;
  if (q0 >= seq || k0 >= seq) return;
  const int b = blockIdx.z;
  const int woff = mi[off_slot];
  float* wout = outb + (size_t)woff + (size_t)b * seq * seq;

  __shared__ float Qs[64][132];  // [d][q]
  __shared__ float Ks[64][132];  // [d][k]
  __shared__ float Linv[128];
  const int t = threadIdx.x;
  const int ty = t >> 4, tx = t & 15;
  float acc[8][8];
#pragma unroll
  for (int i = 0; i < 8; ++i)
#pragma unroll
    for (int j = 0; j < 8; ++j) acc[i][j] = 0.f;

  for (int h = 0; h < TH; ++h) {
    __syncthreads();
#pragma unroll
    for (int rr = 0; rr < 8; ++rr) {
      const int l4 = rr * 256 + t;
      const int ri = l4 >> 4;
      const int d0 = (l4 & 15) << 2;
      float4 qv = make_float4(0.f, 0.f, 0.f, 0.f);
      float4 kv = make_float4(0.f, 0.f, 0.f, 0.f);
      if (q0 + ri < seq)
        qv = *(const float4*)&qkv[((size_t)(b * seq + q0 + ri)) * 1536 + h * 64 + d0];
      if (k0 + ri < seq)
        kv = *(const float4*)&qkv[((size_t)(b * seq + k0 + ri)) * 1536 + 512 + h * 64 + d0];
      Qs[d0 + 0][ri] = qv.x; Qs[d0 + 1][ri] = qv.y; Qs[d0 + 2][ri] = qv.z; Qs[d0 + 3][ri] = qv.w;
      Ks[d0 + 0][ri] = kv.x; Ks[d0 + 1][ri] = kv.y; Ks[d0 + 2][ri] = kv.z; Ks[d0 + 3][ri] = kv.w;
    }
    if (t < 128) {
      const float lv = (q0 + t < seq) ? lbuf[((size_t)(b * TH + h)) * 2048 + q0 + t] : 1.f;
      Linv[t] = 1.f / lv;
    }
    __syncthreads();
    float s[8][8];
#pragma unroll
    for (int i = 0; i < 8; ++i)
#pragma unroll
      for (int j = 0; j < 8; ++j) s[i][j] = 0.f;
#pragma unroll 4
    for (int dd = 0; dd < 64; ++dd) {
      const float4 a0 = *(const float4*)&Qs[dd][ty * 4];
      const float4 a1 = *(const float4*)&Qs[dd][64 + ty * 4];
      const float4 b0 = *(const float4*)&Ks[dd][tx * 4];
      const float4 b1 = *(const float4*)&Ks[dd][64 + tx * 4];
      const float ar[8] = {a0.x, a0.y, a0.z, a0.w, a1.x, a1.y, a1.z, a1.w};
      const float br[8] = {b0.x, b0.y, b0.z, b0.w, b1.x, b1.y, b1.z, b1.w};
#pragma unroll
      for (int i = 0; i < 8; ++i)
#pragma unroll
        for (int j = 0; j < 8; ++j)
          s[i][j] = fmaf(ar[i], br[j], s[i][j]);
    }
#pragma unroll
    for (int i = 0; i < 8; ++i) {
      const int rl = (i < 4) ? (ty * 4 + i) : (64 + ty * 4 + i - 4);
      const float li = Linv[rl];
#pragma unroll
      for (int j = 0; j < 8; ++j)
        acc[i][j] = fmaf(__expf(s[i][j] * 0.125f), li, acc[i][j]);
    }
  }
  const bool fast = ((seq & 3) == 0) && ((woff & 3) == 0);
#pragma unroll
  for (int i = 0; i < 8; ++i) {
    const int rl = (i < 4) ? (ty * 4 + i) : (64 + ty * 4 + i - 4);
    const int qg = q0 + rl;
    if (qg >= seq) continue;
    float* rowp = wout + (size_t)qg * seq;
    const int c0 = k0 + tx * 4;
    const int c1 = c0 + 64;
    if (fast && c0 + 3 < seq) {
      const float4 o = make_float4(acc[i][0] * 0.125f, acc[i][1] * 0.125f,
                                   acc[i][2] * 0.125f, acc[i][3] * 0.125f);
      *(float4*)&rowp[c0] = o;
    } else {
#pragma unroll
      for (int j = 0; j < 4; ++j)
        if (c0 + j < seq) rowp[c0 + j] = acc[i][j] * 0.125f;
    }
    if (fast && c1 + 3 < seq) {
      const float4 o = make_float4(acc[i][4] * 0.125f, acc[i][5] * 0.125f,
                                   acc[i][6] * 0.125f, acc[i][7] * 0.125f);
      *(float4*)&rowp[c1] = o;
    } else {
#pragma unroll
      for (int j = 0; j < 4; ++j)
        if (c1 + j < seq) rowp[c1 + j] = acc[i][j + 4] * 0.125f;
    }
  }
}

// ---------------------------------------------------------------------------
// merge: dst[b,j,:] = mean over contiguous run [start[j], start[j]+cnt[j]).
// ---------------------------------------------------------------------------
__global__ __launch_bounds__(256)
void merge_kernel(const float* __restrict__ src, float* __restrict__ dst,
                  const int* __restrict__ start, const float* __restrict__ cnt,
                  const int* __restrict__ mi, int seqin_slot, int seqout_slot)
{
  const int j = blockIdx.x;
  const int b = blockIdx.y;
  const int seqo = mi[seqout_slot];
  if (j >= seqo) return;
  const int seqi = mi[seqin_slot];
  const int s = start[j];
  const float cf = cnt[j];
  const int n = (int)cf;
  const int d0 = threadIdx.x * 2;
  float s0 = 0.f, s1 = 0.f;
  const float* p = &src[((size_t)b * seqi + s) * TD + d0];
  for (int i = 0; i < n; ++i) {
    const float2 v = *(const float2*)p;
    s0 += v.x; s1 += v.y;
    p += TD;
  }
  const float inv = 1.f / (cf + 1e-10f);
  float2 o; o.x = s0 * inv; o.y = s1 * inv;
  *(float2*)&dst[((size_t)b * seqo + j) * TD + d0] = o;
}

// ---------------------------------------------------------------------------
// expand: expanded[b,j,:] = glob_out[b, gmap[j], :]  (written at d_out offset 0)
// ---------------------------------------------------------------------------
__global__ __launch_bounds__(256)
void expand_kernel(const float* __restrict__ gout, float* __restrict__ dout,
                   const int* __restrict__ gmap, const int* __restrict__ mi)
{
  const int j = blockIdx.x;
  const int b = blockIdx.y;
  const int ntok = mi[MI_NTOK];
  if (j >= ntok) return;
  const int m2 = mi[MI_M2];
  const int g = gmap[j];
  const int d0 = threadIdx.x * 2;
  const float2 v = *(const float2*)&gout[((size_t)b * m2 + g) * TD + d0];
  *(float2*)&dout[((size_t)b * ntok + j) * TD + d0] = v;
}

// ---------------------------------------------------------------------------
extern "C" void kernel_launch(void* const* d_in, const int* in_sizes, int n_in,
                              void* d_out, int out_size, void* d_ws, size_t ws_size,
                              hipStream_t stream)
{
  const float* x   = (const float*)d_in[0];
  const float* cWi = (const float*)d_in[1];
  const float* cbi = (const float*)d_in[2];
  const float* cWo = (const float*)d_in[3];
  const float* cbo = (const float*)d_in[4];
  const float* bWi = (const float*)d_in[5];
  const float* bbi = (const float*)d_in[6];
  const float* bWo = (const float*)d_in[7];
  const float* bbo = (const float*)d_in[8];
  const float* gWi = (const float*)d_in[9];
  const float* gbi = (const float*)d_in[10];
  const float* gWo = (const float*)d_in[11];
  const float* gbo = (const float*)d_in[12];
  const float* mw  = (const float*)d_in[13];
  const float* mbv = (const float*)d_in[14];
  const float* gw  = (const float*)d_in[15];
  const float* gbv = (const float*)d_in[16];
  float* outf = (float*)d_out;

  // workspace layout (~48.3 MB needed)
  char* wsb = (char*)d_ws;
  int*   mi     = (int*)(wsb);
  int*   start1 = (int*)(wsb + 1024);
  float* cnt1   = (float*)(wsb + 1024 + 8192);
  int*   start2 = (int*)(wsb + 1024 + 2 * 8192);
  float* cnt2   = (float*)(wsb + 1024 + 3 * 8192);
  int*   gmap   = (int*)(wsb + 1024 + 4 * 8192);
  float* lbuf   = (float*)(wsb + 1024 + 5 * 8192);   // 32768 floats
  float* qkv    = (float*)(wsb + 196608);            // 4096 x 1536
  float* attn_o = qkv + 6291456;                     // 4096 x 512
  float* stg_o  = attn_o + 2097152;                  // char_out -> block_out -> glob_out
  float* stg_m  = stg_o + 2097152;                   // blocks -> glob

  const dim3 blk(256);

  meta_kernel<<<dim3(1), blk, 0, stream>>>(mw, mbv, gw, gbv, mi, start1, cnt1, start2, cnt2, gmap);

  // ---- char stage ----
  gemm_bias<<<dim3(12, 32), blk, 0, stream>>>(x, cWi, cbi, qkv, mi, MI_MCHAR, 1536);
  attn_pass1<<<dim3(32, 16), blk, 0, stream>>>(qkv, lbuf, attn_o, mi, MI_SEQC);
  attn_pass2<<<dim3(16, 16, 2), blk, 0, stream>>>(qkv, lbuf, outf, mi, MI_SEQC, MI_OFF_CW);
  gemm_bias<<<dim3(4, 32), blk, 0, stream>>>(attn_o, cWo, cbo, stg_o, mi, MI_MCHAR, 512);
  merge_kernel<<<dim3(2048, 2), blk, 0, stream>>>(stg_o, stg_m, start1, cnt1, mi, MI_SEQC, MI_SEQB);

  // ---- block stage ----
  gemm_bias<<<dim3(12, 32), blk, 0, stream>>>(stg_m, bWi, bbi, qkv, mi, MI_MBLOCK, 1536);
  attn_pass1<<<dim3(32, 16), blk, 0, stream>>>(qkv, lbuf, attn_o, mi, MI_SEQB);
  attn_pass2<<<dim3(16, 16, 2), blk, 0, stream>>>(qkv, lbuf, outf, mi, MI_SEQB, MI_OFF_BW);
  gemm_bias<<<dim3(4, 32), blk, 0, stream>>>(attn_o, bWo, bbo, stg_o, mi, MI_MBLOCK, 512);
  merge_kernel<<<dim3(2048, 2), blk, 0, stream>>>(stg_o, stg_m, start2, cnt2, mi, MI_SEQB, MI_SEQG);

  // ---- glob stage ----
  gemm_bias<<<dim3(12, 32), blk, 0, stream>>>(stg_m, gWi, gbi, qkv, mi, MI_MGLOB, 1536);
  attn_pass1<<<dim3(32, 16), blk, 0, stream>>>(qkv, lbuf, attn_o, mi, MI_SEQG);
  attn_pass2<<<dim3(16, 16, 2), blk, 0, stream>>>(qkv, lbuf, outf, mi, MI_SEQG, MI_OFF_GW);
  gemm_bias<<<dim3(4, 32), blk, 0, stream>>>(attn_o, gWo, gbo, stg_o, mi, MI_MGLOB, 512);
  expand_kernel<<<dim3(2048, 2), blk, 0, stream>>>(stg_o, outf, gmap, mi);

  (void)in_sizes; (void)n_in; (void)out_size; (void)ws_size;
}

// Round 2
// 884.507 us; speedup vs baseline: 1.7619x; 1.7619x over previous
//
#include <hip/hip_runtime.h>
#include <cstdint>
#include <cstddef>

// DynamicHierarchicalAttention — split-f16 MFMA pipeline.
// B=2 T=2048 D=512 H=8 HD=64.  Precision-critical matmuls (QKV/proj GEMM,
// QK^T, E@V) use fp32->2xf16 split with 3 MFMAs (error ~2^-22, fp32-grade).
// attn_pass2 (head-mean attention weights) uses plain f16 MFMA (dw/w=ds/8,
// tolerance huge).  All dynamic sizes from device meta kernel; worst-case
// grids + early exit (graph-capture safe).

#define TB 2
#define TT 2048
#define TD 512
#define TH 8
#define THD 64

#define MI_M1 0
#define MI_M2 1
#define MI_NTOK 2
#define MI_OFF_CW 3
#define MI_OFF_BW 4
#define MI_OFF_GW 5
#define MI_MCHAR 6
#define MI_MBLOCK 7
#define MI_MGLOB 8
#define MI_SEQC 9
#define MI_SEQB 10
#define MI_SEQG 11

typedef _Float16 half8 __attribute__((ext_vector_type(8)));
typedef _Float16 half4 __attribute__((ext_vector_type(4)));
typedef float floatx4 __attribute__((ext_vector_type(4)));

__device__ __forceinline__ floatx4 mfma16(half8 a, half8 b, floatx4 c) {
  return __builtin_amdgcn_mfma_f32_16x16x32_f16(a, b, c, 0, 0, 0);
}

__device__ __forceinline__ void split8(const float* v, half8& hi, half8& lo) {
#pragma unroll
  for (int j = 0; j < 8; ++j) {
    const _Float16 h = (_Float16)v[j];
    hi[j] = h;
    lo[j] = (_Float16)(v[j] - (float)h);
  }
}

__device__ __forceinline__ double fracd(double x) { return x - floor(x); }

// ---------------------------------------------------------------------------
// meta: ids/starts/counts/gmap + sizes/offsets (f64 cum: margin >> error)
// ---------------------------------------------------------------------------
__global__ __launch_bounds__(256)
void meta_kernel(const float* __restrict__ mw, const float* __restrict__ mb,
                 const float* __restrict__ gw, const float* __restrict__ gb,
                 int* __restrict__ mi,
                 int* __restrict__ start1, float* __restrict__ cnt1,
                 int* __restrict__ start2, float* __restrict__ cnt2,
                 int* __restrict__ gmap)
{
  __shared__ int ids1[TT];
  __shared__ int ids2[TT];
  __shared__ int sh[1];
  const int t = threadIdx.x;
  if (t == 0) {
    double c1 = 0.0;
    for (int i = 0; i < TD; ++i) c1 += (double)mw[i];
    c1 += (double)mb[0];

    int id = 0, run = 0;
    double prev = fracd((double)TT * c1);
    for (int i = 0; i < TT; ++i) {
      double f = fracd((double)(i + 1) * c1);
      if (f < prev) {
        if (id >= 1) { start1[id - 1] = run; cnt1[id - 1] = (float)(i - run); }
        ++id; run = i;
      }
      ids1[i] = id;
      prev = f;
    }
    if (id >= 1) { start1[id - 1] = run; cnt1[id - 1] = (float)(TT - run); }
    const int m1 = id;

    double c2 = 0.0;
    for (int i = 0; i < TD; ++i) c2 += (double)gw[i];
    c2 += (double)gb[0];

    int id2 = 0, run2 = 0, j0 = -1;
    prev = fracd((double)m1 * c2);
    for (int i = 0; i < m1; ++i) {
      double f = fracd((double)(i + 1) * c2);
      if (f < prev) {
        if (id2 >= 1) { start2[id2 - 1] = run2; cnt2[id2 - 1] = (float)(i - run2); }
        ++id2; run2 = i;
        if (id2 == 1) j0 = i;
      }
      ids2[i] = id2;
      prev = f;
    }
    if (id2 >= 1) { start2[id2 - 1] = run2; cnt2[id2 - 1] = (float)(m1 - run2); }
    const int m2 = id2;

    int i0 = TT;
    if (m1 >= 1 && m2 >= 1 && j0 >= 0) i0 = start1[j0];
    const int ntok = TT - i0;
    sh[0] = i0;

    mi[MI_M1] = m1; mi[MI_M2] = m2; mi[MI_NTOK] = ntok;
    const int offcw = TB * ntok * TD;
    mi[MI_OFF_CW] = offcw;
    mi[MI_OFF_BW] = offcw + TB * TT * TT;
    mi[MI_OFF_GW] = offcw + TB * TT * TT + TB * m1 * m1;
    mi[MI_MCHAR] = TB * TT;
    mi[MI_MBLOCK] = TB * m1;
    mi[MI_MGLOB] = TB * m2;
    mi[MI_SEQC] = TT;
    mi[MI_SEQB] = m1;
    mi[MI_SEQG] = m2;
  }
  __syncthreads();
  const int i0 = sh[0];
  for (int i = i0 + t; i < TT; i += 256)
    gmap[i - i0] = ids2[ids1[i] - 1] - 1;
}

// ---------------------------------------------------------------------------
// GEMM: C[M,N] = A[M,512] @ W[N,512]^T + bias, split-f16 MFMA (3 products).
// 128x128 tile, 4 waves x (2 m-pos x 8 n-pos) of 16x16x32.
// LDS tiles staged pre-split as f16 hi/lo (stride 40 halves: 2-way free).
// ---------------------------------------------------------------------------
__global__ __launch_bounds__(256)
void gemm_mfma(const float* __restrict__ A, const float* __restrict__ W,
               const float* __restrict__ bias, float* __restrict__ C,
               const int* __restrict__ mi, int m_slot, int N)
{
  const int M = mi[m_slot];
  const int bm = blockIdx.y * 128;
  if (bm >= M) return;
  const int bn = blockIdx.x * 128;
  __shared__ _Float16 Ah[128][40];
  __shared__ _Float16 Al[128][40];
  __shared__ _Float16 Wh[128][40];
  __shared__ _Float16 Wl[128][40];

  const int t = threadIdx.x;
  const int wv = t >> 6;
  const int lane = t & 63;
  const int l15 = lane & 15;
  const int quad = lane >> 4;
  const int srow = t >> 1;
  const int sseg = (t & 1) * 16;

  floatx4 acc[2][8];
#pragma unroll
  for (int i = 0; i < 2; ++i)
#pragma unroll
    for (int j = 0; j < 8; ++j) acc[i][j] = (floatx4){0.f, 0.f, 0.f, 0.f};

  for (int kk = 0; kk < TD; kk += 32) {
    __syncthreads();
    {
      const int ar = bm + srow;
      const int wr = bn + srow;
#pragma unroll
      for (int u = 0; u < 4; ++u) {
        float4 av = make_float4(0.f, 0.f, 0.f, 0.f);
        if (ar < M) av = *(const float4*)&A[(size_t)ar * TD + kk + sseg + u * 4];
        const float4 wvv = *(const float4*)&W[(size_t)wr * TD + kk + sseg + u * 4];
        half4 ahh, all, whh, wll;
        const float aa[4] = {av.x, av.y, av.z, av.w};
        const float ww[4] = {wvv.x, wvv.y, wvv.z, wvv.w};
#pragma unroll
        for (int e = 0; e < 4; ++e) {
          _Float16 h = (_Float16)aa[e];
          ahh[e] = h; all[e] = (_Float16)(aa[e] - (float)h);
          h = (_Float16)ww[e];
          whh[e] = h; wll[e] = (_Float16)(ww[e] - (float)h);
        }
        *(half4*)&Ah[srow][sseg + u * 4] = ahh;
        *(half4*)&Al[srow][sseg + u * 4] = all;
        *(half4*)&Wh[srow][sseg + u * 4] = whh;
        *(half4*)&Wl[srow][sseg + u * 4] = wll;
      }
    }
    __syncthreads();
    half8 ah[2], al[2];
#pragma unroll
    for (int mp = 0; mp < 2; ++mp) {
      ah[mp] = *(const half8*)&Ah[wv * 32 + mp * 16 + l15][quad * 8];
      al[mp] = *(const half8*)&Al[wv * 32 + mp * 16 + l15][quad * 8];
    }
#pragma unroll
    for (int np = 0; np < 8; ++np) {
      const half8 bh = *(const half8*)&Wh[np * 16 + l15][quad * 8];
      const half8 bl = *(const half8*)&Wl[np * 16 + l15][quad * 8];
#pragma unroll
      for (int mp = 0; mp < 2; ++mp) {
        acc[mp][np] = mfma16(al[mp], bh, acc[mp][np]);
        acc[mp][np] = mfma16(ah[mp], bl, acc[mp][np]);
        acc[mp][np] = mfma16(ah[mp], bh, acc[mp][np]);
      }
    }
  }
  float bv[8];
#pragma unroll
  for (int np = 0; np < 8; ++np) bv[np] = bias[bn + np * 16 + l15];
#pragma unroll
  for (int mp = 0; mp < 2; ++mp) {
#pragma unroll
    for (int r = 0; r < 4; ++r) {
      const int row = bm + wv * 32 + mp * 16 + quad * 4 + r;
      if (row < M) {
        float* cp = &C[(size_t)row * N + bn];
#pragma unroll
        for (int np = 0; np < 8; ++np)
          cp[np * 16 + l15] = acc[mp][np][r] + bv[np];
      }
    }
  }
}

// ---------------------------------------------------------------------------
// attn pass1 (split-f16 MFMA): per (b,h,64-q tile): l[q]=sum exp(s/8),
// attn_out = (E@V)/l.  Waves own 16-q strips; K,Vt staged fp32 in LDS;
// E round-trips LDS (C-layout -> A-layout transpose).
// ---------------------------------------------------------------------------
__global__ __launch_bounds__(256)
void attn1_mfma(const float* __restrict__ qkv, float* __restrict__ lbuf,
                float* __restrict__ aout, const int* __restrict__ mi, int seq_slot)
{
  const int seq = mi[seq_slot];
  const int q0 = blockIdx.x * 64;
  if (q0 >= seq) return;
  const int b = blockIdx.y >> 3, h = blockIdx.y & 7;
  const int t = threadIdx.x;
  const int wv = t >> 6;
  const int lane = t & 63;
  const int l15 = lane & 15;
  const int quad = lane >> 4;

  __shared__ float Ks[64][68];      // [k-row][d]
  __shared__ float Vt[64][68];      // [d][k-row]
  __shared__ float Es[4][16][68];   // per-wave [q][k]

  // Q fragments (held in regs across whole k loop)
  half8 qh[2], ql[2];
  {
    const int qrow = q0 + wv * 16 + l15;
#pragma unroll
    for (int c = 0; c < 2; ++c) {
      float v[8];
      if (qrow < seq) {
        const float* p = &qkv[((size_t)(b * seq + qrow)) * 1536 + h * 64 + c * 32 + quad * 8];
        *(float4*)&v[0] = *(const float4*)p;
        *(float4*)&v[4] = *(const float4*)(p + 4);
      } else {
#pragma unroll
        for (int j = 0; j < 8; ++j) v[j] = 0.f;
      }
      split8(v, qh[c], ql[c]);
    }
  }

  floatx4 oacc[4];
#pragma unroll
  for (int p = 0; p < 4; ++p) oacc[p] = (floatx4){0.f, 0.f, 0.f, 0.f};
  float lac[4] = {0.f, 0.f, 0.f, 0.f};

  const int nkt = (seq + 63) >> 6;
  for (int kt = 0; kt < nkt; ++kt) {
    const int k0 = kt * 64;
    __syncthreads();
    { // stage K [64][64]
      const int row = t >> 2;
      const int seg = (t & 3) * 16;
      const int kg = k0 + row;
      const float* base = &qkv[((size_t)(b * seq + kg)) * 1536 + 512 + h * 64 + seg];
#pragma unroll
      for (int u = 0; u < 4; ++u) {
        float4 v = make_float4(0.f, 0.f, 0.f, 0.f);
        if (kg < seq) v = *(const float4*)(base + u * 4);
        *(float4*)&Ks[row][seg + u * 4] = v;
      }
    }
    { // stage V transposed: wave wv handles d in [wv*16, wv*16+16), r = lane
      const int r = lane;
      const int kg = k0 + r;
      const int dbase = wv * 16;
      float vvv[16];
      if (kg < seq) {
        const float* base = &qkv[((size_t)(b * seq + kg)) * 1536 + 1024 + h * 64 + dbase];
#pragma unroll
        for (int u = 0; u < 4; ++u) *(float4*)&vvv[u * 4] = *(const float4*)(base + u * 4);
      } else {
#pragma unroll
        for (int j = 0; j < 16; ++j) vvv[j] = 0.f;
      }
#pragma unroll
      for (int j = 0; j < 16; ++j) Vt[dbase + j][r] = vvv[j];
    }
    __syncthreads();

    // S = Q K^T (split), exp, E to LDS, partial l
    float lp[4] = {0.f, 0.f, 0.f, 0.f};
#pragma unroll
    for (int p = 0; p < 4; ++p) {
      floatx4 s = (floatx4){0.f, 0.f, 0.f, 0.f};
#pragma unroll
      for (int c = 0; c < 2; ++c) {
        float v[8];
        const float* kp = &Ks[p * 16 + l15][c * 32 + quad * 8];
        *(float4*)&v[0] = *(const float4*)kp;
        *(float4*)&v[4] = *(const float4*)(kp + 4);
        half8 kh, kl;
        split8(v, kh, kl);
        s = mfma16(ql[c], kh, s);
        s = mfma16(qh[c], kl, s);
        s = mfma16(qh[c], kh, s);
      }
      const int kg = k0 + p * 16 + l15;
#pragma unroll
      for (int r = 0; r < 4; ++r) {
        const float e = (kg < seq) ? __expf(s[r] * 0.125f) : 0.f;
        Es[wv][quad * 4 + r][p * 16 + l15] = e;
        lp[r] += e;
      }
    }
#pragma unroll
    for (int m = 1; m < 16; m <<= 1) {
#pragma unroll
      for (int r = 0; r < 4; ++r) lp[r] += __shfl_xor(lp[r], m, 64);
    }
#pragma unroll
    for (int r = 0; r < 4; ++r) lac[r] += lp[r];

    // O += E @ V (split)
#pragma unroll
    for (int c2 = 0; c2 < 2; ++c2) {
      float ev[8];
      const float* ep = &Es[wv][l15][c2 * 32 + quad * 8];
      *(float4*)&ev[0] = *(const float4*)ep;
      *(float4*)&ev[4] = *(const float4*)(ep + 4);
      half8 eh, el;
      split8(ev, eh, el);
#pragma unroll
      for (int p2 = 0; p2 < 4; ++p2) {
        float vv[8];
        const float* vp = &Vt[p2 * 16 + l15][c2 * 32 + quad * 8];
        *(float4*)&vv[0] = *(const float4*)vp;
        *(float4*)&vv[4] = *(const float4*)(vp + 4);
        half8 vh, vl;
        split8(vv, vh, vl);
        oacc[p2] = mfma16(el, vh, oacc[p2]);
        oacc[p2] = mfma16(eh, vl, oacc[p2]);
        oacc[p2] = mfma16(eh, vh, oacc[p2]);
      }
    }
  }

#pragma unroll
  for (int r = 0; r < 4; ++r) {
    const int qg = q0 + wv * 16 + quad * 4 + r;
    if (qg < seq) {
      const float invl = 1.f / lac[r];
      float* op = &aout[((size_t)(b * seq + qg)) * 512 + h * 64];
#pragma unroll
      for (int p2 = 0; p2 < 4; ++p2)
        op[p2 * 16 + l15] = oacc[p2][r] * invl;
      if (l15 == 0)
        lbuf[((size_t)(b * TH + h)) * 2048 + qg] = lac[r];
    }
  }
}

// ---------------------------------------------------------------------------
// attn pass2 (plain f16 MFMA): w[b,q,k] = (1/8) sum_h exp(s/8)/l.
// 128x128 tile per block, loop heads; Q/K staged as f16.
// ---------------------------------------------------------------------------
__global__ __launch_bounds__(256)
void attn2_mfma(const float* __restrict__ qkv, const float* __restrict__ lbuf,
                float* __restrict__ outb, const int* __restrict__ mi,
                int seq_slot, int off_slot)
{
  const int seq = mi[seq_slot];
  const int q0 = blockIdx.y * 128;
  const int k0 = blockIdx.x * 128;
  if (q0 >= seq || k0 >= seq) return;
  const int b = blockIdx.z;
  const int woff = mi[off_slot];
  float* wout = outb + (size_t)woff + (size_t)b * seq * seq;

  __shared__ _Float16 Qs[128][72];
  __shared__ _Float16 Ksh[128][72];
  __shared__ float Linv[128];

  const int t = threadIdx.x;
  const int wv = t >> 6;
  const int lane = t & 63;
  const int l15 = lane & 15;
  const int quad = lane >> 4;
  const int srow = t >> 1;
  const int sseg = (t & 1) * 32;

  floatx4 acc[2][8];
#pragma unroll
  for (int i = 0; i < 2; ++i)
#pragma unroll
    for (int j = 0; j < 8; ++j) acc[i][j] = (floatx4){0.f, 0.f, 0.f, 0.f};

  for (int h = 0; h < TH; ++h) {
    __syncthreads();
    { // stage Q and K slices (f16), rows: srow, d: [sseg, sseg+32)
      const int qr = q0 + srow;
      const int kr = k0 + srow;
#pragma unroll
      for (int u = 0; u < 8; ++u) {
        float4 qv = make_float4(0.f, 0.f, 0.f, 0.f);
        float4 kv = make_float4(0.f, 0.f, 0.f, 0.f);
        if (qr < seq) qv = *(const float4*)&qkv[((size_t)(b * seq + qr)) * 1536 + h * 64 + sseg + u * 4];
        if (kr < seq) kv = *(const float4*)&qkv[((size_t)(b * seq + kr)) * 1536 + 512 + h * 64 + sseg + u * 4];
        half4 qh, kh;
        qh[0] = (_Float16)qv.x; qh[1] = (_Float16)qv.y; qh[2] = (_Float16)qv.z; qh[3] = (_Float16)qv.w;
        kh[0] = (_Float16)kv.x; kh[1] = (_Float16)kv.y; kh[2] = (_Float16)kv.z; kh[3] = (_Float16)kv.w;
        *(half4*)&Qs[srow][sseg + u * 4] = qh;
        *(half4*)&Ksh[srow][sseg + u * 4] = kh;
      }
      if (t < 128) {
        const float lv = (q0 + t < seq) ? lbuf[((size_t)(b * TH + h)) * 2048 + q0 + t] : 1.f;
        Linv[t] = 1.f / lv;
      }
    }
    __syncthreads();

    half8 af[2][2];
#pragma unroll
    for (int mp = 0; mp < 2; ++mp)
#pragma unroll
      for (int c = 0; c < 2; ++c)
        af[mp][c] = *(const half8*)&Qs[wv * 32 + mp * 16 + l15][c * 32 + quad * 8];
    float lv[2][4];
#pragma unroll
    for (int mp = 0; mp < 2; ++mp)
#pragma unroll
      for (int r = 0; r < 4; ++r)
        lv[mp][r] = Linv[wv * 32 + mp * 16 + quad * 4 + r];

#pragma unroll
    for (int np = 0; np < 8; ++np) {
      half8 bf[2];
#pragma unroll
      for (int c = 0; c < 2; ++c)
        bf[c] = *(const half8*)&Ksh[np * 16 + l15][c * 32 + quad * 8];
#pragma unroll
      for (int mp = 0; mp < 2; ++mp) {
        floatx4 s = (floatx4){0.f, 0.f, 0.f, 0.f};
        s = mfma16(af[mp][0], bf[0], s);
        s = mfma16(af[mp][1], bf[1], s);
#pragma unroll
        for (int r = 0; r < 4; ++r)
          acc[mp][np][r] += __expf(s[r] * 0.125f) * lv[mp][r];
      }
    }
  }

#pragma unroll
  for (int mp = 0; mp < 2; ++mp) {
#pragma unroll
    for (int r = 0; r < 4; ++r) {
      const int qg = q0 + wv * 32 + mp * 16 + quad * 4 + r;
      if (qg >= seq) continue;
      float* rowp = wout + (size_t)qg * seq;
#pragma unroll
      for (int np = 0; np < 8; ++np) {
        const int col = k0 + np * 16 + l15;
        if (col < seq) rowp[col] = acc[mp][np][r] * 0.125f;
      }
    }
  }
}

// ---------------------------------------------------------------------------
// merge: dst[b,j,:] = mean over contiguous run [start[j], start[j]+cnt[j]).
// ---------------------------------------------------------------------------
__global__ __launch_bounds__(256)
void merge_kernel(const float* __restrict__ src, float* __restrict__ dst,
                  const int* __restrict__ start, const float* __restrict__ cnt,
                  const int* __restrict__ mi, int seqin_slot, int seqout_slot)
{
  const int j = blockIdx.x;
  const int b = blockIdx.y;
  const int seqo = mi[seqout_slot];
  if (j >= seqo) return;
  const int seqi = mi[seqin_slot];
  const int s = start[j];
  const float cf = cnt[j];
  const int n = (int)cf;
  const int d0 = threadIdx.x * 2;
  float s0 = 0.f, s1 = 0.f;
  const float* p = &src[((size_t)b * seqi + s) * TD + d0];
  for (int i = 0; i < n; ++i) {
    const float2 v = *(const float2*)p;
    s0 += v.x; s1 += v.y;
    p += TD;
  }
  const float inv = 1.f / (cf + 1e-10f);
  float2 o; o.x = s0 * inv; o.y = s1 * inv;
  *(float2*)&dst[((size_t)b * seqo + j) * TD + d0] = o;
}

__global__ __launch_bounds__(256)
void expand_kernel(const float* __restrict__ gout, float* __restrict__ dout,
                   const int* __restrict__ gmap, const int* __restrict__ mi)
{
  const int j = blockIdx.x;
  const int b = blockIdx.y;
  const int ntok = mi[MI_NTOK];
  if (j >= ntok) return;
  const int m2 = mi[MI_M2];
  const int g = gmap[j];
  const int d0 = threadIdx.x * 2;
  const float2 v = *(const float2*)&gout[((size_t)b * m2 + g) * TD + d0];
  *(float2*)&dout[((size_t)b * ntok + j) * TD + d0] = v;
}

// ---------------------------------------------------------------------------
extern "C" void kernel_launch(void* const* d_in, const int* in_sizes, int n_in,
                              void* d_out, int out_size, void* d_ws, size_t ws_size,
                              hipStream_t stream)
{
  const float* x   = (const float*)d_in[0];
  const float* cWi = (const float*)d_in[1];
  const float* cbi = (const float*)d_in[2];
  const float* cWo = (const float*)d_in[3];
  const float* cbo = (const float*)d_in[4];
  const float* bWi = (const float*)d_in[5];
  const float* bbi = (const float*)d_in[6];
  const float* bWo = (const float*)d_in[7];
  const float* bbo = (const float*)d_in[8];
  const float* gWi = (const float*)d_in[9];
  const float* gbi = (const float*)d_in[10];
  const float* gWo = (const float*)d_in[11];
  const float* gbo = (const float*)d_in[12];
  const float* mw  = (const float*)d_in[13];
  const float* mbv = (const float*)d_in[14];
  const float* gw  = (const float*)d_in[15];
  const float* gbv = (const float*)d_in[16];
  float* outf = (float*)d_out;

  char* wsb = (char*)d_ws;
  int*   mi     = (int*)(wsb);
  int*   start1 = (int*)(wsb + 1024);
  float* cnt1   = (float*)(wsb + 1024 + 8192);
  int*   start2 = (int*)(wsb + 1024 + 2 * 8192);
  float* cnt2   = (float*)(wsb + 1024 + 3 * 8192);
  int*   gmap   = (int*)(wsb + 1024 + 4 * 8192);
  float* lbuf   = (float*)(wsb + 1024 + 5 * 8192);   // 32768 floats
  float* qkv    = (float*)(wsb + 196608);            // 4096 x 1536
  float* attn_o = qkv + 6291456;                     // 4096 x 512
  float* stg_o  = attn_o + 2097152;
  float* stg_m  = stg_o + 2097152;

  const dim3 blk(256);

  meta_kernel<<<dim3(1), blk, 0, stream>>>(mw, mbv, gw, gbv, mi, start1, cnt1, start2, cnt2, gmap);

  // ---- char stage ----
  gemm_mfma<<<dim3(12, 32), blk, 0, stream>>>(x, cWi, cbi, qkv, mi, MI_MCHAR, 1536);
  attn1_mfma<<<dim3(32, 16), blk, 0, stream>>>(qkv, lbuf, attn_o, mi, MI_SEQC);
  attn2_mfma<<<dim3(16, 16, 2), blk, 0, stream>>>(qkv, lbuf, outf, mi, MI_SEQC, MI_OFF_CW);
  gemm_mfma<<<dim3(4, 32), blk, 0, stream>>>(attn_o, cWo, cbo, stg_o, mi, MI_MCHAR, 512);
  merge_kernel<<<dim3(2048, 2), blk, 0, stream>>>(stg_o, stg_m, start1, cnt1, mi, MI_SEQC, MI_SEQB);

  // ---- block stage ----
  gemm_mfma<<<dim3(12, 32), blk, 0, stream>>>(stg_m, bWi, bbi, qkv, mi, MI_MBLOCK, 1536);
  attn1_mfma<<<dim3(32, 16), blk, 0, stream>>>(qkv, lbuf, attn_o, mi, MI_SEQB);
  attn2_mfma<<<dim3(16, 16, 2), blk, 0, stream>>>(qkv, lbuf, outf, mi, MI_SEQB, MI_OFF_BW);
  gemm_mfma<<<dim3(4, 32), blk, 0, stream>>>(attn_o, bWo, bbo, stg_o, mi, MI_MBLOCK, 512);
  merge_kernel<<<dim3(2048, 2), blk, 0, stream>>>(stg_o, stg_m, start2, cnt2, mi, MI_SEQB, MI_SEQG);

  // ---- glob stage ----
  gemm_mfma<<<dim3(12, 32), blk, 0, stream>>>(stg_m, gWi, gbi, qkv, mi, MI_MGLOB, 1536);
  attn1_mfma<<<dim3(32, 16), blk, 0, stream>>>(qkv, lbuf, attn_o, mi, MI_SEQG);
  attn2_mfma<<<dim3(16, 16, 2), blk, 0, stream>>>(qkv, lbuf, outf, mi, MI_SEQG, MI_OFF_GW);
  gemm_mfma<<<dim3(4, 32), blk, 0, stream>>>(attn_o, gWo, gbo, stg_o, mi, MI_MGLOB, 512);
  expand_kernel<<<dim3(2048, 2), blk, 0, stream>>>(stg_o, outf, gmap, mi);

  (void)in_sizes; (void)n_in; (void)out_size; (void)ws_size;
}

// Round 3
// 711.896 us; speedup vs baseline: 2.1891x; 1.2425x over previous
//
#include <hip/hip_runtime.h>
#include <cstdint>
#include <cstddef>

// DynamicHierarchicalAttention — split-f16 MFMA pipeline, parallel meta.
// B=2 T=2048 D=512 H=8 HD=64.  Precision-critical matmuls (QKV/proj GEMM,
// QK^T, E@V) use fp32->2xf16 split with 3 MFMAs (error ~2^-22, fp32-grade).
// attn_pass2 (head-mean attention weights) uses plain f16 MFMA.
// meta: closed-form cum = (i+1)*c -> fully parallel flags + block scan.

#define TB 2
#define TT 2048
#define TD 512
#define TH 8
#define THD 64

#define MI_M1 0
#define MI_M2 1
#define MI_NTOK 2
#define MI_OFF_CW 3
#define MI_OFF_BW 4
#define MI_OFF_GW 5
#define MI_MCHAR 6
#define MI_MBLOCK 7
#define MI_MGLOB 8
#define MI_SEQC 9
#define MI_SEQB 10
#define MI_SEQG 11

typedef _Float16 half8 __attribute__((ext_vector_type(8)));
typedef _Float16 half4 __attribute__((ext_vector_type(4)));
typedef float floatx4 __attribute__((ext_vector_type(4)));

__device__ __forceinline__ floatx4 mfma16(half8 a, half8 b, floatx4 c) {
  return __builtin_amdgcn_mfma_f32_16x16x32_f16(a, b, c, 0, 0, 0);
}

__device__ __forceinline__ void split8(const float* v, half8& hi, half8& lo) {
#pragma unroll
  for (int j = 0; j < 8; ++j) {
    const _Float16 h = (_Float16)v[j];
    hi[j] = h;
    lo[j] = (_Float16)(v[j] - (float)h);
  }
}

__device__ __forceinline__ double fracd(double x) { return x - floor(x); }

// ---------------------------------------------------------------------------
// parallel boundary scan for one phase: n elements, increment c.
// ids[i] = inclusive cumsum of flags; start/cnt per segment id>=1.
// Returns m = number of segments. (block-wide; ends with __syncthreads)
// ---------------------------------------------------------------------------
__device__ int scan_phase(int n, double c, int* __restrict__ ids,
                          int* __restrict__ startg, float* __restrict__ cntg,
                          int* __restrict__ wsum, int t)
{
  int loc[8];
  const int base = t * 8;
#pragma unroll
  for (int j = 0; j < 8; ++j) {
    const int i = base + j;
    int f = 0;
    if (i < n) {
      const int pidx = (i == 0) ? n : i;   // roll: prev of elem 0 is elem n-1
      f = (fracd((double)(i + 1) * c) < fracd((double)pidx * c)) ? 1 : 0;
    }
    loc[j] = f + ((j > 0) ? loc[j - 1] : 0);
  }
  wsum[t] = loc[7];
  __syncthreads();
  for (int off = 1; off < 256; off <<= 1) {
    int u = 0;
    if (t >= off) u = wsum[t - off];
    __syncthreads();
    wsum[t] += u;
    __syncthreads();
  }
  const int excl = wsum[t] - loc[7];
  const int m = wsum[255];
#pragma unroll
  for (int j = 0; j < 8; ++j) {
    const int i = base + j;
    if (i < n) {
      const int id = excl + loc[j];
      ids[i] = id;
      const int f = loc[j] - ((j > 0) ? loc[j - 1] : 0);
      if (f) startg[id - 1] = i;
    }
  }
  __syncthreads();   // start[] global writes visible block-wide
  for (int j = t; j < m; j += 256)
    cntg[j] = (float)((((j + 1) < m) ? startg[j + 1] : n) - startg[j]);
  __syncthreads();
  return m;
}

// ---------------------------------------------------------------------------
// meta: ids/starts/counts/gmap + sizes/offsets (f64: margin >> error)
// ---------------------------------------------------------------------------
__global__ __launch_bounds__(256)
void meta_kernel(const float* __restrict__ mw, const float* __restrict__ mb,
                 const float* __restrict__ gw, const float* __restrict__ gb,
                 int* __restrict__ mi,
                 int* __restrict__ start1, float* __restrict__ cnt1,
                 int* __restrict__ start2, float* __restrict__ cnt2,
                 int* __restrict__ gmap)
{
  __shared__ int ids1[TT];
  __shared__ int ids2[TT];
  __shared__ int wsum[256];
  __shared__ double dsh[256];
  const int t = threadIdx.x;

  double s1 = 0.0, s2 = 0.0;
  for (int i = t; i < TD; i += 256) { s1 += (double)mw[i]; s2 += (double)gw[i]; }
  dsh[t] = s1; __syncthreads();
  for (int off = 128; off > 0; off >>= 1) {
    if (t < off) dsh[t] += dsh[t + off];
    __syncthreads();
  }
  const double c1 = dsh[0] + (double)mb[0];
  __syncthreads();
  dsh[t] = s2; __syncthreads();
  for (int off = 128; off > 0; off >>= 1) {
    if (t < off) dsh[t] += dsh[t + off];
    __syncthreads();
  }
  const double c2 = dsh[0] + (double)gb[0];
  __syncthreads();

  const int m1 = scan_phase(TT, c1, ids1, start1, cnt1, wsum, t);
  const int m2 = scan_phase(m1, c2, ids2, start2, cnt2, wsum, t);

  int i0 = TT;
  if (m1 >= 1 && m2 >= 1) i0 = start1[start2[0]];
  const int ntok = TT - i0;

  if (t == 0) {
    mi[MI_M1] = m1; mi[MI_M2] = m2; mi[MI_NTOK] = ntok;
    const int offcw = TB * ntok * TD;
    mi[MI_OFF_CW] = offcw;
    mi[MI_OFF_BW] = offcw + TB * TT * TT;
    mi[MI_OFF_GW] = offcw + TB * TT * TT + TB * m1 * m1;
    mi[MI_MCHAR] = TB * TT;
    mi[MI_MBLOCK] = TB * m1;
    mi[MI_MGLOB] = TB * m2;
    mi[MI_SEQC] = TT;
    mi[MI_SEQB] = m1;
    mi[MI_SEQG] = m2;
  }
  for (int i = i0 + t; i < TT; i += 256)
    gmap[i - i0] = ids2[ids1[i] - 1] - 1;
}

// ---------------------------------------------------------------------------
// GEMM: C[M,N] = A[M,512] @ W[N,512]^T + bias, split-f16 MFMA (3 products).
// ---------------------------------------------------------------------------
__global__ __launch_bounds__(256)
void gemm_mfma(const float* __restrict__ A, const float* __restrict__ W,
               const float* __restrict__ bias, float* __restrict__ C,
               const int* __restrict__ mi, int m_slot, int N)
{
  const int M = mi[m_slot];
  const int bm = blockIdx.y * 128;
  if (bm >= M) return;
  const int bn = blockIdx.x * 128;
  __shared__ _Float16 Ah[128][40];
  __shared__ _Float16 Al[128][40];
  __shared__ _Float16 Wh[128][40];
  __shared__ _Float16 Wl[128][40];

  const int t = threadIdx.x;
  const int wv = t >> 6;
  const int lane = t & 63;
  const int l15 = lane & 15;
  const int quad = lane >> 4;
  const int srow = t >> 1;
  const int sseg = (t & 1) * 16;

  floatx4 acc[2][8];
#pragma unroll
  for (int i = 0; i < 2; ++i)
#pragma unroll
    for (int j = 0; j < 8; ++j) acc[i][j] = (floatx4){0.f, 0.f, 0.f, 0.f};

  for (int kk = 0; kk < TD; kk += 32) {
    __syncthreads();
    {
      const int ar = bm + srow;
      const int wr = bn + srow;
#pragma unroll
      for (int u = 0; u < 4; ++u) {
        float4 av = make_float4(0.f, 0.f, 0.f, 0.f);
        if (ar < M) av = *(const float4*)&A[(size_t)ar * TD + kk + sseg + u * 4];
        const float4 wvv = *(const float4*)&W[(size_t)wr * TD + kk + sseg + u * 4];
        half4 ahh, all, whh, wll;
        const float aa[4] = {av.x, av.y, av.z, av.w};
        const float ww[4] = {wvv.x, wvv.y, wvv.z, wvv.w};
#pragma unroll
        for (int e = 0; e < 4; ++e) {
          _Float16 h = (_Float16)aa[e];
          ahh[e] = h; all[e] = (_Float16)(aa[e] - (float)h);
          h = (_Float16)ww[e];
          whh[e] = h; wll[e] = (_Float16)(ww[e] - (float)h);
        }
        *(half4*)&Ah[srow][sseg + u * 4] = ahh;
        *(half4*)&Al[srow][sseg + u * 4] = all;
        *(half4*)&Wh[srow][sseg + u * 4] = whh;
        *(half4*)&Wl[srow][sseg + u * 4] = wll;
      }
    }
    __syncthreads();
    half8 ah[2], al[2];
#pragma unroll
    for (int mp = 0; mp < 2; ++mp) {
      ah[mp] = *(const half8*)&Ah[wv * 32 + mp * 16 + l15][quad * 8];
      al[mp] = *(const half8*)&Al[wv * 32 + mp * 16 + l15][quad * 8];
    }
#pragma unroll
    for (int np = 0; np < 8; ++np) {
      const half8 bh = *(const half8*)&Wh[np * 16 + l15][quad * 8];
      const half8 bl = *(const half8*)&Wl[np * 16 + l15][quad * 8];
#pragma unroll
      for (int mp = 0; mp < 2; ++mp) {
        acc[mp][np] = mfma16(al[mp], bh, acc[mp][np]);
        acc[mp][np] = mfma16(ah[mp], bl, acc[mp][np]);
        acc[mp][np] = mfma16(ah[mp], bh, acc[mp][np]);
      }
    }
  }
  float bv[8];
#pragma unroll
  for (int np = 0; np < 8; ++np) bv[np] = bias[bn + np * 16 + l15];
#pragma unroll
  for (int mp = 0; mp < 2; ++mp) {
#pragma unroll
    for (int r = 0; r < 4; ++r) {
      const int row = bm + wv * 32 + mp * 16 + quad * 4 + r;
      if (row < M) {
        float* cp = &C[(size_t)row * N + bn];
#pragma unroll
        for (int np = 0; np < 8; ++np)
          cp[np * 16 + l15] = acc[mp][np][r] + bv[np];
      }
    }
  }
}

// ---------------------------------------------------------------------------
// attn pass1 (split-f16 MFMA)
// ---------------------------------------------------------------------------
__global__ __launch_bounds__(256)
void attn1_mfma(const float* __restrict__ qkv, float* __restrict__ lbuf,
                float* __restrict__ aout, const int* __restrict__ mi, int seq_slot)
{
  const int seq = mi[seq_slot];
  const int q0 = blockIdx.x * 64;
  if (q0 >= seq) return;
  const int b = blockIdx.y >> 3, h = blockIdx.y & 7;
  const int t = threadIdx.x;
  const int wv = t >> 6;
  const int lane = t & 63;
  const int l15 = lane & 15;
  const int quad = lane >> 4;

  __shared__ float Ks[64][68];      // [k-row][d]
  __shared__ float Vt[64][68];      // [d][k-row]
  __shared__ float Es[4][16][68];   // per-wave [q][k]

  half8 qh[2], ql[2];
  {
    const int qrow = q0 + wv * 16 + l15;
#pragma unroll
    for (int c = 0; c < 2; ++c) {
      float v[8];
      if (qrow < seq) {
        const float* p = &qkv[((size_t)(b * seq + qrow)) * 1536 + h * 64 + c * 32 + quad * 8];
        *(float4*)&v[0] = *(const float4*)p;
        *(float4*)&v[4] = *(const float4*)(p + 4);
      } else {
#pragma unroll
        for (int j = 0; j < 8; ++j) v[j] = 0.f;
      }
      split8(v, qh[c], ql[c]);
    }
  }

  floatx4 oacc[4];
#pragma unroll
  for (int p = 0; p < 4; ++p) oacc[p] = (floatx4){0.f, 0.f, 0.f, 0.f};
  float lac[4] = {0.f, 0.f, 0.f, 0.f};

  const int nkt = (seq + 63) >> 6;
  for (int kt = 0; kt < nkt; ++kt) {
    const int k0 = kt * 64;
    __syncthreads();
    {
      const int row = t >> 2;
      const int seg = (t & 3) * 16;
      const int kg = k0 + row;
      const float* base = &qkv[((size_t)(b * seq + kg)) * 1536 + 512 + h * 64 + seg];
#pragma unroll
      for (int u = 0; u < 4; ++u) {
        float4 v = make_float4(0.f, 0.f, 0.f, 0.f);
        if (kg < seq) v = *(const float4*)(base + u * 4);
        *(float4*)&Ks[row][seg + u * 4] = v;
      }
    }
    {
      const int r = lane;
      const int kg = k0 + r;
      const int dbase = wv * 16;
      float vvv[16];
      if (kg < seq) {
        const float* base = &qkv[((size_t)(b * seq + kg)) * 1536 + 1024 + h * 64 + dbase];
#pragma unroll
        for (int u = 0; u < 4; ++u) *(float4*)&vvv[u * 4] = *(const float4*)(base + u * 4);
      } else {
#pragma unroll
        for (int j = 0; j < 16; ++j) vvv[j] = 0.f;
      }
#pragma unroll
      for (int j = 0; j < 16; ++j) Vt[dbase + j][r] = vvv[j];
    }
    __syncthreads();

    float lp[4] = {0.f, 0.f, 0.f, 0.f};
#pragma unroll
    for (int p = 0; p < 4; ++p) {
      floatx4 s = (floatx4){0.f, 0.f, 0.f, 0.f};
#pragma unroll
      for (int c = 0; c < 2; ++c) {
        float v[8];
        const float* kp = &Ks[p * 16 + l15][c * 32 + quad * 8];
        *(float4*)&v[0] = *(const float4*)kp;
        *(float4*)&v[4] = *(const float4*)(kp + 4);
        half8 kh, kl;
        split8(v, kh, kl);
        s = mfma16(ql[c], kh, s);
        s = mfma16(qh[c], kl, s);
        s = mfma16(qh[c], kh, s);
      }
      const int kg = k0 + p * 16 + l15;
#pragma unroll
      for (int r = 0; r < 4; ++r) {
        const float e = (kg < seq) ? __expf(s[r] * 0.125f) : 0.f;
        Es[wv][quad * 4 + r][p * 16 + l15] = e;
        lp[r] += e;
      }
    }
#pragma unroll
    for (int m = 1; m < 16; m <<= 1) {
#pragma unroll
      for (int r = 0; r < 4; ++r) lp[r] += __shfl_xor(lp[r], m, 64);
    }
#pragma unroll
    for (int r = 0; r < 4; ++r) lac[r] += lp[r];

#pragma unroll
    for (int c2 = 0; c2 < 2; ++c2) {
      float ev[8];
      const float* ep = &Es[wv][l15][c2 * 32 + quad * 8];
      *(float4*)&ev[0] = *(const float4*)ep;
      *(float4*)&ev[4] = *(const float4*)(ep + 4);
      half8 eh, el;
      split8(ev, eh, el);
#pragma unroll
      for (int p2 = 0; p2 < 4; ++p2) {
        float vv[8];
        const float* vp = &Vt[p2 * 16 + l15][c2 * 32 + quad * 8];
        *(float4*)&vv[0] = *(const float4*)vp;
        *(float4*)&vv[4] = *(const float4*)(vp + 4);
        half8 vh, vl;
        split8(vv, vh, vl);
        oacc[p2] = mfma16(el, vh, oacc[p2]);
        oacc[p2] = mfma16(eh, vl, oacc[p2]);
        oacc[p2] = mfma16(eh, vh, oacc[p2]);
      }
    }
  }

#pragma unroll
  for (int r = 0; r < 4; ++r) {
    const int qg = q0 + wv * 16 + quad * 4 + r;
    if (qg < seq) {
      const float invl = 1.f / lac[r];
      float* op = &aout[((size_t)(b * seq + qg)) * 512 + h * 64];
#pragma unroll
      for (int p2 = 0; p2 < 4; ++p2)
        op[p2 * 16 + l15] = oacc[p2][r] * invl;
      if (l15 == 0)
        lbuf[((size_t)(b * TH + h)) * 2048 + qg] = lac[r];
    }
  }
}

// ---------------------------------------------------------------------------
// attn pass2 (plain f16 MFMA)
// ---------------------------------------------------------------------------
__global__ __launch_bounds__(256)
void attn2_mfma(const float* __restrict__ qkv, const float* __restrict__ lbuf,
                float* __restrict__ outb, const int* __restrict__ mi,
                int seq_slot, int off_slot)
{
  const int seq = mi[seq_slot];
  const int q0 = blockIdx.y * 128;
  const int k0 = blockIdx.x * 128;
  if (q0 >= seq || k0 >= seq) return;
  const int b = blockIdx.z;
  const int woff = mi[off_slot];
  float* wout = outb + (size_t)woff + (size_t)b * seq * seq;

  __shared__ _Float16 Qs[128][72];
  __shared__ _Float16 Ksh[128][72];
  __shared__ float Linv[128];

  const int t = threadIdx.x;
  const int wv = t >> 6;
  const int lane = t & 63;
  const int l15 = lane & 15;
  const int quad = lane >> 4;
  const int srow = t >> 1;
  const int sseg = (t & 1) * 32;

  floatx4 acc[2][8];
#pragma unroll
  for (int i = 0; i < 2; ++i)
#pragma unroll
    for (int j = 0; j < 8; ++j) acc[i][j] = (floatx4){0.f, 0.f, 0.f, 0.f};

  for (int h = 0; h < TH; ++h) {
    __syncthreads();
    {
      const int qr = q0 + srow;
      const int kr = k0 + srow;
#pragma unroll
      for (int u = 0; u < 8; ++u) {
        float4 qv = make_float4(0.f, 0.f, 0.f, 0.f);
        float4 kv = make_float4(0.f, 0.f, 0.f, 0.f);
        if (qr < seq) qv = *(const float4*)&qkv[((size_t)(b * seq + qr)) * 1536 + h * 64 + sseg + u * 4];
        if (kr < seq) kv = *(const float4*)&qkv[((size_t)(b * seq + kr)) * 1536 + 512 + h * 64 + sseg + u * 4];
        half4 qh, kh;
        qh[0] = (_Float16)qv.x; qh[1] = (_Float16)qv.y; qh[2] = (_Float16)qv.z; qh[3] = (_Float16)qv.w;
        kh[0] = (_Float16)kv.x; kh[1] = (_Float16)kv.y; kh[2] = (_Float16)kv.z; kh[3] = (_Float16)kv.w;
        *(half4*)&Qs[srow][sseg + u * 4] = qh;
        *(half4*)&Ksh[srow][sseg + u * 4] = kh;
      }
      if (t < 128) {
        const float lv = (q0 + t < seq) ? lbuf[((size_t)(b * TH + h)) * 2048 + q0 + t] : 1.f;
        Linv[t] = 1.f / lv;
      }
    }
    __syncthreads();

    half8 af[2][2];
#pragma unroll
    for (int mp = 0; mp < 2; ++mp)
#pragma unroll
      for (int c = 0; c < 2; ++c)
        af[mp][c] = *(const half8*)&Qs[wv * 32 + mp * 16 + l15][c * 32 + quad * 8];
    float lv[2][4];
#pragma unroll
    for (int mp = 0; mp < 2; ++mp)
#pragma unroll
      for (int r = 0; r < 4; ++r)
        lv[mp][r] = Linv[wv * 32 + mp * 16 + quad * 4 + r];

#pragma unroll
    for (int np = 0; np < 8; ++np) {
      half8 bf[2];
#pragma unroll
      for (int c = 0; c < 2; ++c)
        bf[c] = *(const half8*)&Ksh[np * 16 + l15][c * 32 + quad * 8];
#pragma unroll
      for (int mp = 0; mp < 2; ++mp) {
        floatx4 s = (floatx4){0.f, 0.f, 0.f, 0.f};
        s = mfma16(af[mp][0], bf[0], s);
        s = mfma16(af[mp][1], bf[1], s);
#pragma unroll
        for (int r = 0; r < 4; ++r)
          acc[mp][np][r] += __expf(s[r] * 0.125f) * lv[mp][r];
      }
    }
  }

#pragma unroll
  for (int mp = 0; mp < 2; ++mp) {
#pragma unroll
    for (int r = 0; r < 4; ++r) {
      const int qg = q0 + wv * 32 + mp * 16 + quad * 4 + r;
      if (qg >= seq) continue;
      float* rowp = wout + (size_t)qg * seq;
#pragma unroll
      for (int np = 0; np < 8; ++np) {
        const int col = k0 + np * 16 + l15;
        if (col < seq) rowp[col] = acc[mp][np][r] * 0.125f;
      }
    }
  }
}

// ---------------------------------------------------------------------------
__global__ __launch_bounds__(256)
void merge_kernel(const float* __restrict__ src, float* __restrict__ dst,
                  const int* __restrict__ start, const float* __restrict__ cnt,
                  const int* __restrict__ mi, int seqin_slot, int seqout_slot)
{
  const int j = blockIdx.x;
  const int b = blockIdx.y;
  const int seqo = mi[seqout_slot];
  if (j >= seqo) return;
  const int seqi = mi[seqin_slot];
  const int s = start[j];
  const float cf = cnt[j];
  const int n = (int)cf;
  const int d0 = threadIdx.x * 2;
  float s0 = 0.f, s1 = 0.f;
  const float* p = &src[((size_t)b * seqi + s) * TD + d0];
  for (int i = 0; i < n; ++i) {
    const float2 v = *(const float2*)p;
    s0 += v.x; s1 += v.y;
    p += TD;
  }
  const float inv = 1.f / (cf + 1e-10f);
  float2 o; o.x = s0 * inv; o.y = s1 * inv;
  *(float2*)&dst[((size_t)b * seqo + j) * TD + d0] = o;
}

__global__ __launch_bounds__(256)
void expand_kernel(const float* __restrict__ gout, float* __restrict__ dout,
                   const int* __restrict__ gmap, const int* __restrict__ mi)
{
  const int j = blockIdx.x;
  const int b = blockIdx.y;
  const int ntok = mi[MI_NTOK];
  if (j >= ntok) return;
  const int m2 = mi[MI_M2];
  const int g = gmap[j];
  const int d0 = threadIdx.x * 2;
  const float2 v = *(const float2*)&gout[((size_t)b * m2 + g) * TD + d0];
  *(float2*)&dout[((size_t)b * ntok + j) * TD + d0] = v;
}

// ---------------------------------------------------------------------------
extern "C" void kernel_launch(void* const* d_in, const int* in_sizes, int n_in,
                              void* d_out, int out_size, void* d_ws, size_t ws_size,
                              hipStream_t stream)
{
  const float* x   = (const float*)d_in[0];
  const float* cWi = (const float*)d_in[1];
  const float* cbi = (const float*)d_in[2];
  const float* cWo = (const float*)d_in[3];
  const float* cbo = (const float*)d_in[4];
  const float* bWi = (const float*)d_in[5];
  const float* bbi = (const float*)d_in[6];
  const float* bWo = (const float*)d_in[7];
  const float* bbo = (const float*)d_in[8];
  const float* gWi = (const float*)d_in[9];
  const float* gbi = (const float*)d_in[10];
  const float* gWo = (const float*)d_in[11];
  const float* gbo = (const float*)d_in[12];
  const float* mw  = (const float*)d_in[13];
  const float* mbv = (const float*)d_in[14];
  const float* gw  = (const float*)d_in[15];
  const float* gbv = (const float*)d_in[16];
  float* outf = (float*)d_out;

  char* wsb = (char*)d_ws;
  int*   mi     = (int*)(wsb);
  int*   start1 = (int*)(wsb + 1024);
  float* cnt1   = (float*)(wsb + 1024 + 8192);
  int*   start2 = (int*)(wsb + 1024 + 2 * 8192);
  float* cnt2   = (float*)(wsb + 1024 + 3 * 8192);
  int*   gmap   = (int*)(wsb + 1024 + 4 * 8192);
  float* lbuf   = (float*)(wsb + 1024 + 5 * 8192);   // 32768 floats
  float* qkv    = (float*)(wsb + 196608);            // 4096 x 1536
  float* attn_o = qkv + 6291456;                     // 4096 x 512
  float* stg_o  = attn_o + 2097152;
  float* stg_m  = stg_o + 2097152;

  const dim3 blk(256);

  meta_kernel<<<dim3(1), blk, 0, stream>>>(mw, mbv, gw, gbv, mi, start1, cnt1, start2, cnt2, gmap);

  // ---- char stage ----
  gemm_mfma<<<dim3(12, 32), blk, 0, stream>>>(x, cWi, cbi, qkv, mi, MI_MCHAR, 1536);
  attn1_mfma<<<dim3(32, 16), blk, 0, stream>>>(qkv, lbuf, attn_o, mi, MI_SEQC);
  attn2_mfma<<<dim3(16, 16, 2), blk, 0, stream>>>(qkv, lbuf, outf, mi, MI_SEQC, MI_OFF_CW);
  gemm_mfma<<<dim3(4, 32), blk, 0, stream>>>(attn_o, cWo, cbo, stg_o, mi, MI_MCHAR, 512);
  merge_kernel<<<dim3(2048, 2), blk, 0, stream>>>(stg_o, stg_m, start1, cnt1, mi, MI_SEQC, MI_SEQB);

  // ---- block stage ----
  gemm_mfma<<<dim3(12, 32), blk, 0, stream>>>(stg_m, bWi, bbi, qkv, mi, MI_MBLOCK, 1536);
  attn1_mfma<<<dim3(32, 16), blk, 0, stream>>>(qkv, lbuf, attn_o, mi, MI_SEQB);
  attn2_mfma<<<dim3(16, 16, 2), blk, 0, stream>>>(qkv, lbuf, outf, mi, MI_SEQB, MI_OFF_BW);
  gemm_mfma<<<dim3(4, 32), blk, 0, stream>>>(attn_o, bWo, bbo, stg_o, mi, MI_MBLOCK, 512);
  merge_kernel<<<dim3(2048, 2), blk, 0, stream>>>(stg_o, stg_m, start2, cnt2, mi, MI_SEQB, MI_SEQG);

  // ---- glob stage ----
  gemm_mfma<<<dim3(12, 32), blk, 0, stream>>>(stg_m, gWi, gbi, qkv, mi, MI_MGLOB, 1536);
  attn1_mfma<<<dim3(32, 16), blk, 0, stream>>>(qkv, lbuf, attn_o, mi, MI_SEQG);
  attn2_mfma<<<dim3(16, 16, 2), blk, 0, stream>>>(qkv, lbuf, outf, mi, MI_SEQG, MI_OFF_GW);
  gemm_mfma<<<dim3(4, 32), blk, 0, stream>>>(attn_o, gWo, gbo, stg_o, mi, MI_MGLOB, 512);
  expand_kernel<<<dim3(2048, 2), blk, 0, stream>>>(stg_o, outf, gmap, mi);

  (void)in_sizes; (void)n_in; (void)out_size; (void)ws_size;
}

// Round 4
// 686.766 us; speedup vs baseline: 2.2692x; 1.0366x over previous
//
#include <hip/hip_runtime.h>
#include <cstdint>
#include <cstddef>

// DynamicHierarchicalAttention — split-f16 MFMA pipeline, parallel meta.
// R3: attn1 stages K/V pre-split (hi/lo f16) in LDS — split once per block
// instead of once per wave (4x redundancy removed); inner loop is pure
// ds_read_b128 + MFMA on the K/V path.

#define TB 2
#define TT 2048
#define TD 512
#define TH 8
#define THD 64

#define MI_M1 0
#define MI_M2 1
#define MI_NTOK 2
#define MI_OFF_CW 3
#define MI_OFF_BW 4
#define MI_OFF_GW 5
#define MI_MCHAR 6
#define MI_MBLOCK 7
#define MI_MGLOB 8
#define MI_SEQC 9
#define MI_SEQB 10
#define MI_SEQG 11

typedef _Float16 half8 __attribute__((ext_vector_type(8)));
typedef _Float16 half4 __attribute__((ext_vector_type(4)));
typedef float floatx4 __attribute__((ext_vector_type(4)));

__device__ __forceinline__ floatx4 mfma16(half8 a, half8 b, floatx4 c) {
  return __builtin_amdgcn_mfma_f32_16x16x32_f16(a, b, c, 0, 0, 0);
}

__device__ __forceinline__ void split8(const float* v, half8& hi, half8& lo) {
#pragma unroll
  for (int j = 0; j < 8; ++j) {
    const _Float16 h = (_Float16)v[j];
    hi[j] = h;
    lo[j] = (_Float16)(v[j] - (float)h);
  }
}

__device__ __forceinline__ double fracd(double x) { return x - floor(x); }

// ---------------------------------------------------------------------------
// parallel boundary scan for one phase: n elements, increment c.
// ---------------------------------------------------------------------------
__device__ int scan_phase(int n, double c, int* __restrict__ ids,
                          int* __restrict__ startg, float* __restrict__ cntg,
                          int* __restrict__ wsum, int t)
{
  int loc[8];
  const int base = t * 8;
#pragma unroll
  for (int j = 0; j < 8; ++j) {
    const int i = base + j;
    int f = 0;
    if (i < n) {
      const int pidx = (i == 0) ? n : i;   // roll: prev of elem 0 is elem n-1
      f = (fracd((double)(i + 1) * c) < fracd((double)pidx * c)) ? 1 : 0;
    }
    loc[j] = f + ((j > 0) ? loc[j - 1] : 0);
  }
  wsum[t] = loc[7];
  __syncthreads();
  for (int off = 1; off < 256; off <<= 1) {
    int u = 0;
    if (t >= off) u = wsum[t - off];
    __syncthreads();
    wsum[t] += u;
    __syncthreads();
  }
  const int excl = wsum[t] - loc[7];
  const int m = wsum[255];
#pragma unroll
  for (int j = 0; j < 8; ++j) {
    const int i = base + j;
    if (i < n) {
      const int id = excl + loc[j];
      ids[i] = id;
      const int f = loc[j] - ((j > 0) ? loc[j - 1] : 0);
      if (f) startg[id - 1] = i;
    }
  }
  __syncthreads();
  for (int j = t; j < m; j += 256)
    cntg[j] = (float)((((j + 1) < m) ? startg[j + 1] : n) - startg[j]);
  __syncthreads();
  return m;
}

// ---------------------------------------------------------------------------
__global__ __launch_bounds__(256)
void meta_kernel(const float* __restrict__ mw, const float* __restrict__ mb,
                 const float* __restrict__ gw, const float* __restrict__ gb,
                 int* __restrict__ mi,
                 int* __restrict__ start1, float* __restrict__ cnt1,
                 int* __restrict__ start2, float* __restrict__ cnt2,
                 int* __restrict__ gmap)
{
  __shared__ int ids1[TT];
  __shared__ int ids2[TT];
  __shared__ int wsum[256];
  __shared__ double dsh[256];
  const int t = threadIdx.x;

  double s1 = 0.0, s2 = 0.0;
  for (int i = t; i < TD; i += 256) { s1 += (double)mw[i]; s2 += (double)gw[i]; }
  dsh[t] = s1; __syncthreads();
  for (int off = 128; off > 0; off >>= 1) {
    if (t < off) dsh[t] += dsh[t + off];
    __syncthreads();
  }
  const double c1 = dsh[0] + (double)mb[0];
  __syncthreads();
  dsh[t] = s2; __syncthreads();
  for (int off = 128; off > 0; off >>= 1) {
    if (t < off) dsh[t] += dsh[t + off];
    __syncthreads();
  }
  const double c2 = dsh[0] + (double)gb[0];
  __syncthreads();

  const int m1 = scan_phase(TT, c1, ids1, start1, cnt1, wsum, t);
  const int m2 = scan_phase(m1, c2, ids2, start2, cnt2, wsum, t);

  int i0 = TT;
  if (m1 >= 1 && m2 >= 1) i0 = start1[start2[0]];
  const int ntok = TT - i0;

  if (t == 0) {
    mi[MI_M1] = m1; mi[MI_M2] = m2; mi[MI_NTOK] = ntok;
    const int offcw = TB * ntok * TD;
    mi[MI_OFF_CW] = offcw;
    mi[MI_OFF_BW] = offcw + TB * TT * TT;
    mi[MI_OFF_GW] = offcw + TB * TT * TT + TB * m1 * m1;
    mi[MI_MCHAR] = TB * TT;
    mi[MI_MBLOCK] = TB * m1;
    mi[MI_MGLOB] = TB * m2;
    mi[MI_SEQC] = TT;
    mi[MI_SEQB] = m1;
    mi[MI_SEQG] = m2;
  }
  for (int i = i0 + t; i < TT; i += 256)
    gmap[i - i0] = ids2[ids1[i] - 1] - 1;
}

// ---------------------------------------------------------------------------
// GEMM: C[M,N] = A[M,512] @ W[N,512]^T + bias, split-f16 MFMA (3 products).
// ---------------------------------------------------------------------------
__global__ __launch_bounds__(256)
void gemm_mfma(const float* __restrict__ A, const float* __restrict__ W,
               const float* __restrict__ bias, float* __restrict__ C,
               const int* __restrict__ mi, int m_slot, int N)
{
  const int M = mi[m_slot];
  const int bm = blockIdx.y * 128;
  if (bm >= M) return;
  const int bn = blockIdx.x * 128;
  __shared__ _Float16 Ah[128][40];
  __shared__ _Float16 Al[128][40];
  __shared__ _Float16 Wh[128][40];
  __shared__ _Float16 Wl[128][40];

  const int t = threadIdx.x;
  const int wv = t >> 6;
  const int lane = t & 63;
  const int l15 = lane & 15;
  const int quad = lane >> 4;
  const int srow = t >> 1;
  const int sseg = (t & 1) * 16;

  floatx4 acc[2][8];
#pragma unroll
  for (int i = 0; i < 2; ++i)
#pragma unroll
    for (int j = 0; j < 8; ++j) acc[i][j] = (floatx4){0.f, 0.f, 0.f, 0.f};

  for (int kk = 0; kk < TD; kk += 32) {
    __syncthreads();
    {
      const int ar = bm + srow;
      const int wr = bn + srow;
#pragma unroll
      for (int u = 0; u < 4; ++u) {
        float4 av = make_float4(0.f, 0.f, 0.f, 0.f);
        if (ar < M) av = *(const float4*)&A[(size_t)ar * TD + kk + sseg + u * 4];
        const float4 wvv = *(const float4*)&W[(size_t)wr * TD + kk + sseg + u * 4];
        half4 ahh, all, whh, wll;
        const float aa[4] = {av.x, av.y, av.z, av.w};
        const float ww[4] = {wvv.x, wvv.y, wvv.z, wvv.w};
#pragma unroll
        for (int e = 0; e < 4; ++e) {
          _Float16 h = (_Float16)aa[e];
          ahh[e] = h; all[e] = (_Float16)(aa[e] - (float)h);
          h = (_Float16)ww[e];
          whh[e] = h; wll[e] = (_Float16)(ww[e] - (float)h);
        }
        *(half4*)&Ah[srow][sseg + u * 4] = ahh;
        *(half4*)&Al[srow][sseg + u * 4] = all;
        *(half4*)&Wh[srow][sseg + u * 4] = whh;
        *(half4*)&Wl[srow][sseg + u * 4] = wll;
      }
    }
    __syncthreads();
    half8 ah[2], al[2];
#pragma unroll
    for (int mp = 0; mp < 2; ++mp) {
      ah[mp] = *(const half8*)&Ah[wv * 32 + mp * 16 + l15][quad * 8];
      al[mp] = *(const half8*)&Al[wv * 32 + mp * 16 + l15][quad * 8];
    }
#pragma unroll
    for (int np = 0; np < 8; ++np) {
      const half8 bh = *(const half8*)&Wh[np * 16 + l15][quad * 8];
      const half8 bl = *(const half8*)&Wl[np * 16 + l15][quad * 8];
#pragma unroll
      for (int mp = 0; mp < 2; ++mp) {
        acc[mp][np] = mfma16(al[mp], bh, acc[mp][np]);
        acc[mp][np] = mfma16(ah[mp], bl, acc[mp][np]);
        acc[mp][np] = mfma16(ah[mp], bh, acc[mp][np]);
      }
    }
  }
  float bv[8];
#pragma unroll
  for (int np = 0; np < 8; ++np) bv[np] = bias[bn + np * 16 + l15];
#pragma unroll
  for (int mp = 0; mp < 2; ++mp) {
#pragma unroll
    for (int r = 0; r < 4; ++r) {
      const int row = bm + wv * 32 + mp * 16 + quad * 4 + r;
      if (row < M) {
        float* cp = &C[(size_t)row * N + bn];
#pragma unroll
        for (int np = 0; np < 8; ++np)
          cp[np * 16 + l15] = acc[mp][np][r] + bv[np];
      }
    }
  }
}

// ---------------------------------------------------------------------------
// attn pass1 (split-f16 MFMA): K/V staged PRE-SPLIT as f16 hi/lo in LDS.
// stride 72 halves = 36 dwords = 4 mod 32 -> 2-way (free) on half8 reads.
// ---------------------------------------------------------------------------
__global__ __launch_bounds__(256)
void attn1_mfma(const float* __restrict__ qkv, float* __restrict__ lbuf,
                float* __restrict__ aout, const int* __restrict__ mi, int seq_slot)
{
  const int seq = mi[seq_slot];
  const int q0 = blockIdx.x * 64;
  if (q0 >= seq) return;
  const int b = blockIdx.y >> 3, h = blockIdx.y & 7;
  const int t = threadIdx.x;
  const int wv = t >> 6;
  const int lane = t & 63;
  const int l15 = lane & 15;
  const int quad = lane >> 4;

  __shared__ _Float16 Kh[64][72];   // [k][d] hi
  __shared__ _Float16 Kl[64][72];   // [k][d] lo
  __shared__ _Float16 Vh[64][72];   // [d][k] hi (transposed)
  __shared__ _Float16 Vl[64][72];   // [d][k] lo
  __shared__ float Es[4][16][68];   // per-wave [q][k] f32

  half8 qh[2], ql[2];
  {
    const int qrow = q0 + wv * 16 + l15;
#pragma unroll
    for (int c = 0; c < 2; ++c) {
      float v[8];
      if (qrow < seq) {
        const float* p = &qkv[((size_t)(b * seq + qrow)) * 1536 + h * 64 + c * 32 + quad * 8];
        *(float4*)&v[0] = *(const float4*)p;
        *(float4*)&v[4] = *(const float4*)(p + 4);
      } else {
#pragma unroll
        for (int j = 0; j < 8; ++j) v[j] = 0.f;
      }
      split8(v, qh[c], ql[c]);
    }
  }

  floatx4 oacc[4];
#pragma unroll
  for (int p = 0; p < 4; ++p) oacc[p] = (floatx4){0.f, 0.f, 0.f, 0.f};
  float lac[4] = {0.f, 0.f, 0.f, 0.f};

  const int nkt = (seq + 63) >> 6;
  for (int kt = 0; kt < nkt; ++kt) {
    const int k0 = kt * 64;
    __syncthreads();
    { // stage K pre-split: thread handles row t>>2, 16 d at seg
      const int row = t >> 2;
      const int seg = (t & 3) * 16;
      const int kg = k0 + row;
      const float* base = &qkv[((size_t)(b * seq + kg)) * 1536 + 512 + h * 64 + seg];
#pragma unroll
      for (int u = 0; u < 4; ++u) {
        float4 v = make_float4(0.f, 0.f, 0.f, 0.f);
        if (kg < seq) v = *(const float4*)(base + u * 4);
        const float vv[4] = {v.x, v.y, v.z, v.w};
        half4 hi, lo;
#pragma unroll
        for (int e = 0; e < 4; ++e) {
          const _Float16 hh = (_Float16)vv[e];
          hi[e] = hh; lo[e] = (_Float16)(vv[e] - (float)hh);
        }
        *(half4*)&Kh[row][seg + u * 4] = hi;
        *(half4*)&Kl[row][seg + u * 4] = lo;
      }
    }
    { // stage V transposed pre-split: wave wv owns d in [wv*16, wv*16+16), k = lane
      const int r = lane;
      const int kg = k0 + r;
      const int dbase = wv * 16;
      float vvv[16];
      if (kg < seq) {
        const float* base = &qkv[((size_t)(b * seq + kg)) * 1536 + 1024 + h * 64 + dbase];
#pragma unroll
        for (int u = 0; u < 4; ++u) *(float4*)&vvv[u * 4] = *(const float4*)(base + u * 4);
      } else {
#pragma unroll
        for (int j = 0; j < 16; ++j) vvv[j] = 0.f;
      }
#pragma unroll
      for (int j = 0; j < 16; ++j) {
        const _Float16 hh = (_Float16)vvv[j];
        Vh[dbase + j][r] = hh;
        Vl[dbase + j][r] = (_Float16)(vvv[j] - (float)hh);
      }
    }
    __syncthreads();

    // S = Q K^T (split), exp, E to LDS, partial l
    float lp[4] = {0.f, 0.f, 0.f, 0.f};
#pragma unroll
    for (int p = 0; p < 4; ++p) {
      floatx4 s = (floatx4){0.f, 0.f, 0.f, 0.f};
#pragma unroll
      for (int c = 0; c < 2; ++c) {
        const half8 kh = *(const half8*)&Kh[p * 16 + l15][c * 32 + quad * 8];
        const half8 kl = *(const half8*)&Kl[p * 16 + l15][c * 32 + quad * 8];
        s = mfma16(ql[c], kh, s);
        s = mfma16(qh[c], kl, s);
        s = mfma16(qh[c], kh, s);
      }
      const int kg = k0 + p * 16 + l15;
#pragma unroll
      for (int r = 0; r < 4; ++r) {
        const float e = (kg < seq) ? __expf(s[r] * 0.125f) : 0.f;
        Es[wv][quad * 4 + r][p * 16 + l15] = e;
        lp[r] += e;
      }
    }
#pragma unroll
    for (int m = 1; m < 16; m <<= 1) {
#pragma unroll
      for (int r = 0; r < 4; ++r) lp[r] += __shfl_xor(lp[r], m, 64);
    }
#pragma unroll
    for (int r = 0; r < 4; ++r) lac[r] += lp[r];

    // O += E @ V (split; E split is wave-private, K/V fragments direct)
#pragma unroll
    for (int c2 = 0; c2 < 2; ++c2) {
      float ev[8];
      const float* ep = &Es[wv][l15][c2 * 32 + quad * 8];
      *(float4*)&ev[0] = *(const float4*)ep;
      *(float4*)&ev[4] = *(const float4*)(ep + 4);
      half8 eh, el;
      split8(ev, eh, el);
#pragma unroll
      for (int p2 = 0; p2 < 4; ++p2) {
        const half8 vh = *(const half8*)&Vh[p2 * 16 + l15][c2 * 32 + quad * 8];
        const half8 vl = *(const half8*)&Vl[p2 * 16 + l15][c2 * 32 + quad * 8];
        oacc[p2] = mfma16(el, vh, oacc[p2]);
        oacc[p2] = mfma16(eh, vl, oacc[p2]);
        oacc[p2] = mfma16(eh, vh, oacc[p2]);
      }
    }
  }

#pragma unroll
  for (int r = 0; r < 4; ++r) {
    const int qg = q0 + wv * 16 + quad * 4 + r;
    if (qg < seq) {
      const float invl = 1.f / lac[r];
      float* op = &aout[((size_t)(b * seq + qg)) * 512 + h * 64];
#pragma unroll
      for (int p2 = 0; p2 < 4; ++p2)
        op[p2 * 16 + l15] = oacc[p2][r] * invl;
      if (l15 == 0)
        lbuf[((size_t)(b * TH + h)) * 2048 + qg] = lac[r];
    }
  }
}

// ---------------------------------------------------------------------------
// attn pass2 (plain f16 MFMA)
// ---------------------------------------------------------------------------
__global__ __launch_bounds__(256)
void attn2_mfma(const float* __restrict__ qkv, const float* __restrict__ lbuf,
                float* __restrict__ outb, const int* __restrict__ mi,
                int seq_slot, int off_slot)
{
  const int seq = mi[seq_slot];
  const int q0 = blockIdx.y * 128;
  const int k0 = blockIdx.x * 128;
  if (q0 >= seq || k0 >= seq) return;
  const int b = blockIdx.z;
  const int woff = mi[off_slot];
  float* wout = outb + (size_t)woff + (size_t)b * seq * seq;

  __shared__ _Float16 Qs[128][72];
  __shared__ _Float16 Ksh[128][72];
  __shared__ float Linv[128];

  const int t = threadIdx.x;
  const int wv = t >> 6;
  const int lane = t & 63;
  const int l15 = lane & 15;
  const int quad = lane >> 4;
  const int srow = t >> 1;
  const int sseg = (t & 1) * 32;

  floatx4 acc[2][8];
#pragma unroll
  for (int i = 0; i < 2; ++i)
#pragma unroll
    for (int j = 0; j < 8; ++j) acc[i][j] = (floatx4){0.f, 0.f, 0.f, 0.f};

  for (int h = 0; h < TH; ++h) {
    __syncthreads();
    {
      const int qr = q0 + srow;
      const int kr = k0 + srow;
#pragma unroll
      for (int u = 0; u < 8; ++u) {
        float4 qv = make_float4(0.f, 0.f, 0.f, 0.f);
        float4 kv = make_float4(0.f, 0.f, 0.f, 0.f);
        if (qr < seq) qv = *(const float4*)&qkv[((size_t)(b * seq + qr)) * 1536 + h * 64 + sseg + u * 4];
        if (kr < seq) kv = *(const float4*)&qkv[((size_t)(b * seq + kr)) * 1536 + 512 + h * 64 + sseg + u * 4];
        half4 qh, kh;
        qh[0] = (_Float16)qv.x; qh[1] = (_Float16)qv.y; qh[2] = (_Float16)qv.z; qh[3] = (_Float16)qv.w;
        kh[0] = (_Float16)kv.x; kh[1] = (_Float16)kv.y; kh[2] = (_Float16)kv.z; kh[3] = (_Float16)kv.w;
        *(half4*)&Qs[srow][sseg + u * 4] = qh;
        *(half4*)&Ksh[srow][sseg + u * 4] = kh;
      }
      if (t < 128) {
        const float lv = (q0 + t < seq) ? lbuf[((size_t)(b * TH + h)) * 2048 + q0 + t] : 1.f;
        Linv[t] = 1.f / lv;
      }
    }
    __syncthreads();

    half8 af[2][2];
#pragma unroll
    for (int mp = 0; mp < 2; ++mp)
#pragma unroll
      for (int c = 0; c < 2; ++c)
        af[mp][c] = *(const half8*)&Qs[wv * 32 + mp * 16 + l15][c * 32 + quad * 8];
    float lv[2][4];
#pragma unroll
    for (int mp = 0; mp < 2; ++mp)
#pragma unroll
      for (int r = 0; r < 4; ++r)
        lv[mp][r] = Linv[wv * 32 + mp * 16 + quad * 4 + r];

#pragma unroll
    for (int np = 0; np < 8; ++np) {
      half8 bf[2];
#pragma unroll
      for (int c = 0; c < 2; ++c)
        bf[c] = *(const half8*)&Ksh[np * 16 + l15][c * 32 + quad * 8];
#pragma unroll
      for (int mp = 0; mp < 2; ++mp) {
        floatx4 s = (floatx4){0.f, 0.f, 0.f, 0.f};
        s = mfma16(af[mp][0], bf[0], s);
        s = mfma16(af[mp][1], bf[1], s);
#pragma unroll
        for (int r = 0; r < 4; ++r)
          acc[mp][np][r] += __expf(s[r] * 0.125f) * lv[mp][r];
      }
    }
  }

#pragma unroll
  for (int mp = 0; mp < 2; ++mp) {
#pragma unroll
    for (int r = 0; r < 4; ++r) {
      const int qg = q0 + wv * 32 + mp * 16 + quad * 4 + r;
      if (qg >= seq) continue;
      float* rowp = wout + (size_t)qg * seq;
#pragma unroll
      for (int np = 0; np < 8; ++np) {
        const int col = k0 + np * 16 + l15;
        if (col < seq) rowp[col] = acc[mp][np][r] * 0.125f;
      }
    }
  }
}

// ---------------------------------------------------------------------------
__global__ __launch_bounds__(256)
void merge_kernel(const float* __restrict__ src, float* __restrict__ dst,
                  const int* __restrict__ start, const float* __restrict__ cnt,
                  const int* __restrict__ mi, int seqin_slot, int seqout_slot)
{
  const int j = blockIdx.x;
  const int b = blockIdx.y;
  const int seqo = mi[seqout_slot];
  if (j >= seqo) return;
  const int seqi = mi[seqin_slot];
  const int s = start[j];
  const float cf = cnt[j];
  const int n = (int)cf;
  const int d0 = threadIdx.x * 2;
  float s0 = 0.f, s1 = 0.f;
  const float* p = &src[((size_t)b * seqi + s) * TD + d0];
  for (int i = 0; i < n; ++i) {
    const float2 v = *(const float2*)p;
    s0 += v.x; s1 += v.y;
    p += TD;
  }
  const float inv = 1.f / (cf + 1e-10f);
  float2 o; o.x = s0 * inv; o.y = s1 * inv;
  *(float2*)&dst[((size_t)b * seqo + j) * TD + d0] = o;
}

__global__ __launch_bounds__(256)
void expand_kernel(const float* __restrict__ gout, float* __restrict__ dout,
                   const int* __restrict__ gmap, const int* __restrict__ mi)
{
  const int j = blockIdx.x;
  const int b = blockIdx.y;
  const int ntok = mi[MI_NTOK];
  if (j >= ntok) return;
  const int m2 = mi[MI_M2];
  const int g = gmap[j];
  const int d0 = threadIdx.x * 2;
  const float2 v = *(const float2*)&gout[((size_t)b * m2 + g) * TD + d0];
  *(float2*)&dout[((size_t)b * ntok + j) * TD + d0] = v;
}

// ---------------------------------------------------------------------------
extern "C" void kernel_launch(void* const* d_in, const int* in_sizes, int n_in,
                              void* d_out, int out_size, void* d_ws, size_t ws_size,
                              hipStream_t stream)
{
  const float* x   = (const float*)d_in[0];
  const float* cWi = (const float*)d_in[1];
  const float* cbi = (const float*)d_in[2];
  const float* cWo = (const float*)d_in[3];
  const float* cbo = (const float*)d_in[4];
  const float* bWi = (const float*)d_in[5];
  const float* bbi = (const float*)d_in[6];
  const float* bWo = (const float*)d_in[7];
  const float* bbo = (const float*)d_in[8];
  const float* gWi = (const float*)d_in[9];
  const float* gbi = (const float*)d_in[10];
  const float* gWo = (const float*)d_in[11];
  const float* gbo = (const float*)d_in[12];
  const float* mw  = (const float*)d_in[13];
  const float* mbv = (const float*)d_in[14];
  const float* gw  = (const float*)d_in[15];
  const float* gbv = (const float*)d_in[16];
  float* outf = (float*)d_out;

  char* wsb = (char*)d_ws;
  int*   mi     = (int*)(wsb);
  int*   start1 = (int*)(wsb + 1024);
  float* cnt1   = (float*)(wsb + 1024 + 8192);
  int*   start2 = (int*)(wsb + 1024 + 2 * 8192);
  float* cnt2   = (float*)(wsb + 1024 + 3 * 8192);
  int*   gmap   = (int*)(wsb + 1024 + 4 * 8192);
  float* lbuf   = (float*)(wsb + 1024 + 5 * 8192);   // 32768 floats
  float* qkv    = (float*)(wsb + 196608);            // 4096 x 1536
  float* attn_o = qkv + 6291456;                     // 4096 x 512
  float* stg_o  = attn_o + 2097152;
  float* stg_m  = stg_o + 2097152;

  const dim3 blk(256);

  meta_kernel<<<dim3(1), blk, 0, stream>>>(mw, mbv, gw, gbv, mi, start1, cnt1, start2, cnt2, gmap);

  // ---- char stage ----
  gemm_mfma<<<dim3(12, 32), blk, 0, stream>>>(x, cWi, cbi, qkv, mi, MI_MCHAR, 1536);
  attn1_mfma<<<dim3(32, 16), blk, 0, stream>>>(qkv, lbuf, attn_o, mi, MI_SEQC);
  attn2_mfma<<<dim3(16, 16, 2), blk, 0, stream>>>(qkv, lbuf, outf, mi, MI_SEQC, MI_OFF_CW);
  gemm_mfma<<<dim3(4, 32), blk, 0, stream>>>(attn_o, cWo, cbo, stg_o, mi, MI_MCHAR, 512);
  merge_kernel<<<dim3(2048, 2), blk, 0, stream>>>(stg_o, stg_m, start1, cnt1, mi, MI_SEQC, MI_SEQB);

  // ---- block stage ----
  gemm_mfma<<<dim3(12, 32), blk, 0, stream>>>(stg_m, bWi, bbi, qkv, mi, MI_MBLOCK, 1536);
  attn1_mfma<<<dim3(32, 16), blk, 0, stream>>>(qkv, lbuf, attn_o, mi, MI_SEQB);
  attn2_mfma<<<dim3(16, 16, 2), blk, 0, stream>>>(qkv, lbuf, outf, mi, MI_SEQB, MI_OFF_BW);
  gemm_mfma<<<dim3(4, 32), blk, 0, stream>>>(attn_o, bWo, bbo, stg_o, mi, MI_MBLOCK, 512);
  merge_kernel<<<dim3(2048, 2), blk, 0, stream>>>(stg_o, stg_m, start2, cnt2, mi, MI_SEQB, MI_SEQG);

  // ---- glob stage ----
  gemm_mfma<<<dim3(12, 32), blk, 0, stream>>>(stg_m, gWi, gbi, qkv, mi, MI_MGLOB, 1536);
  attn1_mfma<<<dim3(32, 16), blk, 0, stream>>>(qkv, lbuf, attn_o, mi, MI_SEQG);
  attn2_mfma<<<dim3(16, 16, 2), blk, 0, stream>>>(qkv, lbuf, outf, mi, MI_SEQG, MI_OFF_GW);
  gemm_mfma<<<dim3(4, 32), blk, 0, stream>>>(attn_o, gWo, gbo, stg_o, mi, MI_MGLOB, 512);
  expand_kernel<<<dim3(2048, 2), blk, 0, stream>>>(stg_o, outf, gmap, mi);

  (void)in_sizes; (void)n_in; (void)out_size; (void)ws_size;
}

// Round 5
// 632.080 us; speedup vs baseline: 2.4655x; 1.0865x over previous
//
#include <hip/hip_runtime.h>
#include <cstdint>
#include <cstddef>

// DynamicHierarchicalAttention — MFMA pipeline.
// R4: attn1 all-f16 fragments (Q,K,V,E) with f32 accumulation + f32 exp/l.
// Error budget: QK f16 ds~1.6e-3 -> dw/w~2e-4; E,V f16 ~4.9e-4 rel; final
// output contribution ~1e-5 vs 4.49e-5 threshold. QKV/proj GEMMs stay
// split-f16 (fp32-grade).

#define TB 2
#define TT 2048
#define TD 512
#define TH 8
#define THD 64

#define MI_M1 0
#define MI_M2 1
#define MI_NTOK 2
#define MI_OFF_CW 3
#define MI_OFF_BW 4
#define MI_OFF_GW 5
#define MI_MCHAR 6
#define MI_MBLOCK 7
#define MI_MGLOB 8
#define MI_SEQC 9
#define MI_SEQB 10
#define MI_SEQG 11

typedef _Float16 half8 __attribute__((ext_vector_type(8)));
typedef _Float16 half4 __attribute__((ext_vector_type(4)));
typedef float floatx4 __attribute__((ext_vector_type(4)));

__device__ __forceinline__ floatx4 mfma16(half8 a, half8 b, floatx4 c) {
  return __builtin_amdgcn_mfma_f32_16x16x32_f16(a, b, c, 0, 0, 0);
}

__device__ __forceinline__ void split8(const float* v, half8& hi, half8& lo) {
#pragma unroll
  for (int j = 0; j < 8; ++j) {
    const _Float16 h = (_Float16)v[j];
    hi[j] = h;
    lo[j] = (_Float16)(v[j] - (float)h);
  }
}

__device__ __forceinline__ double fracd(double x) { return x - floor(x); }

// ---------------------------------------------------------------------------
// parallel boundary scan for one phase: n elements, increment c.
// ---------------------------------------------------------------------------
__device__ int scan_phase(int n, double c, int* __restrict__ ids,
                          int* __restrict__ startg, float* __restrict__ cntg,
                          int* __restrict__ wsum, int t)
{
  int loc[8];
  const int base = t * 8;
#pragma unroll
  for (int j = 0; j < 8; ++j) {
    const int i = base + j;
    int f = 0;
    if (i < n) {
      const int pidx = (i == 0) ? n : i;   // roll: prev of elem 0 is elem n-1
      f = (fracd((double)(i + 1) * c) < fracd((double)pidx * c)) ? 1 : 0;
    }
    loc[j] = f + ((j > 0) ? loc[j - 1] : 0);
  }
  wsum[t] = loc[7];
  __syncthreads();
  for (int off = 1; off < 256; off <<= 1) {
    int u = 0;
    if (t >= off) u = wsum[t - off];
    __syncthreads();
    wsum[t] += u;
    __syncthreads();
  }
  const int excl = wsum[t] - loc[7];
  const int m = wsum[255];
#pragma unroll
  for (int j = 0; j < 8; ++j) {
    const int i = base + j;
    if (i < n) {
      const int id = excl + loc[j];
      ids[i] = id;
      const int f = loc[j] - ((j > 0) ? loc[j - 1] : 0);
      if (f) startg[id - 1] = i;
    }
  }
  __syncthreads();
  for (int j = t; j < m; j += 256)
    cntg[j] = (float)((((j + 1) < m) ? startg[j + 1] : n) - startg[j]);
  __syncthreads();
  return m;
}

// ---------------------------------------------------------------------------
__global__ __launch_bounds__(256)
void meta_kernel(const float* __restrict__ mw, const float* __restrict__ mb,
                 const float* __restrict__ gw, const float* __restrict__ gb,
                 int* __restrict__ mi,
                 int* __restrict__ start1, float* __restrict__ cnt1,
                 int* __restrict__ start2, float* __restrict__ cnt2,
                 int* __restrict__ gmap)
{
  __shared__ int ids1[TT];
  __shared__ int ids2[TT];
  __shared__ int wsum[256];
  __shared__ double dsh[256];
  const int t = threadIdx.x;

  double s1 = 0.0, s2 = 0.0;
  for (int i = t; i < TD; i += 256) { s1 += (double)mw[i]; s2 += (double)gw[i]; }
  dsh[t] = s1; __syncthreads();
  for (int off = 128; off > 0; off >>= 1) {
    if (t < off) dsh[t] += dsh[t + off];
    __syncthreads();
  }
  const double c1 = dsh[0] + (double)mb[0];
  __syncthreads();
  dsh[t] = s2; __syncthreads();
  for (int off = 128; off > 0; off >>= 1) {
    if (t < off) dsh[t] += dsh[t + off];
    __syncthreads();
  }
  const double c2 = dsh[0] + (double)gb[0];
  __syncthreads();

  const int m1 = scan_phase(TT, c1, ids1, start1, cnt1, wsum, t);
  const int m2 = scan_phase(m1, c2, ids2, start2, cnt2, wsum, t);

  int i0 = TT;
  if (m1 >= 1 && m2 >= 1) i0 = start1[start2[0]];
  const int ntok = TT - i0;

  if (t == 0) {
    mi[MI_M1] = m1; mi[MI_M2] = m2; mi[MI_NTOK] = ntok;
    const int offcw = TB * ntok * TD;
    mi[MI_OFF_CW] = offcw;
    mi[MI_OFF_BW] = offcw + TB * TT * TT;
    mi[MI_OFF_GW] = offcw + TB * TT * TT + TB * m1 * m1;
    mi[MI_MCHAR] = TB * TT;
    mi[MI_MBLOCK] = TB * m1;
    mi[MI_MGLOB] = TB * m2;
    mi[MI_SEQC] = TT;
    mi[MI_SEQB] = m1;
    mi[MI_SEQG] = m2;
  }
  for (int i = i0 + t; i < TT; i += 256)
    gmap[i - i0] = ids2[ids1[i] - 1] - 1;
}

// ---------------------------------------------------------------------------
// GEMM: C[M,N] = A[M,512] @ W[N,512]^T + bias, split-f16 MFMA (3 products).
// ---------------------------------------------------------------------------
__global__ __launch_bounds__(256)
void gemm_mfma(const float* __restrict__ A, const float* __restrict__ W,
               const float* __restrict__ bias, float* __restrict__ C,
               const int* __restrict__ mi, int m_slot, int N)
{
  const int M = mi[m_slot];
  const int bm = blockIdx.y * 128;
  if (bm >= M) return;
  const int bn = blockIdx.x * 128;
  __shared__ _Float16 Ah[128][40];
  __shared__ _Float16 Al[128][40];
  __shared__ _Float16 Wh[128][40];
  __shared__ _Float16 Wl[128][40];

  const int t = threadIdx.x;
  const int wv = t >> 6;
  const int lane = t & 63;
  const int l15 = lane & 15;
  const int quad = lane >> 4;
  const int srow = t >> 1;
  const int sseg = (t & 1) * 16;

  floatx4 acc[2][8];
#pragma unroll
  for (int i = 0; i < 2; ++i)
#pragma unroll
    for (int j = 0; j < 8; ++j) acc[i][j] = (floatx4){0.f, 0.f, 0.f, 0.f};

  for (int kk = 0; kk < TD; kk += 32) {
    __syncthreads();
    {
      const int ar = bm + srow;
      const int wr = bn + srow;
#pragma unroll
      for (int u = 0; u < 4; ++u) {
        float4 av = make_float4(0.f, 0.f, 0.f, 0.f);
        if (ar < M) av = *(const float4*)&A[(size_t)ar * TD + kk + sseg + u * 4];
        const float4 wvv = *(const float4*)&W[(size_t)wr * TD + kk + sseg + u * 4];
        half4 ahh, all, whh, wll;
        const float aa[4] = {av.x, av.y, av.z, av.w};
        const float ww[4] = {wvv.x, wvv.y, wvv.z, wvv.w};
#pragma unroll
        for (int e = 0; e < 4; ++e) {
          _Float16 h = (_Float16)aa[e];
          ahh[e] = h; all[e] = (_Float16)(aa[e] - (float)h);
          h = (_Float16)ww[e];
          whh[e] = h; wll[e] = (_Float16)(ww[e] - (float)h);
        }
        *(half4*)&Ah[srow][sseg + u * 4] = ahh;
        *(half4*)&Al[srow][sseg + u * 4] = all;
        *(half4*)&Wh[srow][sseg + u * 4] = whh;
        *(half4*)&Wl[srow][sseg + u * 4] = wll;
      }
    }
    __syncthreads();
    half8 ah[2], al[2];
#pragma unroll
    for (int mp = 0; mp < 2; ++mp) {
      ah[mp] = *(const half8*)&Ah[wv * 32 + mp * 16 + l15][quad * 8];
      al[mp] = *(const half8*)&Al[wv * 32 + mp * 16 + l15][quad * 8];
    }
#pragma unroll
    for (int np = 0; np < 8; ++np) {
      const half8 bh = *(const half8*)&Wh[np * 16 + l15][quad * 8];
      const half8 bl = *(const half8*)&Wl[np * 16 + l15][quad * 8];
#pragma unroll
      for (int mp = 0; mp < 2; ++mp) {
        acc[mp][np] = mfma16(al[mp], bh, acc[mp][np]);
        acc[mp][np] = mfma16(ah[mp], bl, acc[mp][np]);
        acc[mp][np] = mfma16(ah[mp], bh, acc[mp][np]);
      }
    }
  }
  float bv[8];
#pragma unroll
  for (int np = 0; np < 8; ++np) bv[np] = bias[bn + np * 16 + l15];
#pragma unroll
  for (int mp = 0; mp < 2; ++mp) {
#pragma unroll
    for (int r = 0; r < 4; ++r) {
      const int row = bm + wv * 32 + mp * 16 + quad * 4 + r;
      if (row < M) {
        float* cp = &C[(size_t)row * N + bn];
#pragma unroll
        for (int np = 0; np < 8; ++np)
          cp[np * 16 + l15] = acc[mp][np][r] + bv[np];
      }
    }
  }
}

// ---------------------------------------------------------------------------
// attn pass1 (all-f16 MFMA, f32 accum/exp/l): per (b,h,64-q tile):
// l[q] = sum_k exp(s/8); attn_out = (E@V)/l.  16 MFMA per K-tile per wave.
// LDS 27.6 KB: K[64][72]f16, V^T[64][72]f16, Es[4][16][72]f16.
// ---------------------------------------------------------------------------
__global__ __launch_bounds__(256)
void attn1_mfma(const float* __restrict__ qkv, float* __restrict__ lbuf,
                float* __restrict__ aout, const int* __restrict__ mi, int seq_slot)
{
  const int seq = mi[seq_slot];
  const int q0 = blockIdx.x * 64;
  if (q0 >= seq) return;
  const int b = blockIdx.y >> 3, h = blockIdx.y & 7;
  const int t = threadIdx.x;
  const int wv = t >> 6;
  const int lane = t & 63;
  const int l15 = lane & 15;
  const int quad = lane >> 4;

  __shared__ _Float16 Kf[64][72];   // [k][d]
  __shared__ _Float16 Vt[64][72];   // [d][k] (transposed)
  __shared__ _Float16 Es[4][16][72];// per-wave [q][k]

  // Q fragment f16 (held in regs across whole k loop)
  half8 qf[2];
  {
    const int qrow = q0 + wv * 16 + l15;
#pragma unroll
    for (int c = 0; c < 2; ++c) {
      float v[8];
      if (qrow < seq) {
        const float* p = &qkv[((size_t)(b * seq + qrow)) * 1536 + h * 64 + c * 32 + quad * 8];
        *(float4*)&v[0] = *(const float4*)p;
        *(float4*)&v[4] = *(const float4*)(p + 4);
      } else {
#pragma unroll
        for (int j = 0; j < 8; ++j) v[j] = 0.f;
      }
#pragma unroll
      for (int j = 0; j < 8; ++j) qf[c][j] = (_Float16)v[j];
    }
  }

  floatx4 oacc[4];
#pragma unroll
  for (int p = 0; p < 4; ++p) oacc[p] = (floatx4){0.f, 0.f, 0.f, 0.f};
  float lac[4] = {0.f, 0.f, 0.f, 0.f};

  const int nkt = (seq + 63) >> 6;
  for (int kt = 0; kt < nkt; ++kt) {
    const int k0 = kt * 64;
    __syncthreads();
    { // stage K f16: thread handles row t>>2, 16 d at seg
      const int row = t >> 2;
      const int seg = (t & 3) * 16;
      const int kg = k0 + row;
      const float* base = &qkv[((size_t)(b * seq + kg)) * 1536 + 512 + h * 64 + seg];
#pragma unroll
      for (int u = 0; u < 4; ++u) {
        float4 v = make_float4(0.f, 0.f, 0.f, 0.f);
        if (kg < seq) v = *(const float4*)(base + u * 4);
        half4 hv;
        hv[0] = (_Float16)v.x; hv[1] = (_Float16)v.y;
        hv[2] = (_Float16)v.z; hv[3] = (_Float16)v.w;
        *(half4*)&Kf[row][seg + u * 4] = hv;
      }
    }
    { // stage V transposed f16: wave wv owns d in [wv*16, wv*16+16), k = lane
      const int r = lane;
      const int kg = k0 + r;
      const int dbase = wv * 16;
      float vvv[16];
      if (kg < seq) {
        const float* base = &qkv[((size_t)(b * seq + kg)) * 1536 + 1024 + h * 64 + dbase];
#pragma unroll
        for (int u = 0; u < 4; ++u) *(float4*)&vvv[u * 4] = *(const float4*)(base + u * 4);
      } else {
#pragma unroll
        for (int j = 0; j < 16; ++j) vvv[j] = 0.f;
      }
#pragma unroll
      for (int j = 0; j < 16; ++j) Vt[dbase + j][r] = (_Float16)vvv[j];
    }
    __syncthreads();

    // S = Q K^T (f16), exp (f32), E to LDS f16, partial l (f32)
    float lp[4] = {0.f, 0.f, 0.f, 0.f};
#pragma unroll
    for (int p = 0; p < 4; ++p) {
      floatx4 s = (floatx4){0.f, 0.f, 0.f, 0.f};
#pragma unroll
      for (int c = 0; c < 2; ++c) {
        const half8 kf = *(const half8*)&Kf[p * 16 + l15][c * 32 + quad * 8];
        s = mfma16(qf[c], kf, s);
      }
      const int kg = k0 + p * 16 + l15;
#pragma unroll
      for (int r = 0; r < 4; ++r) {
        const float e = (kg < seq) ? __expf(s[r] * 0.125f) : 0.f;
        Es[wv][quad * 4 + r][p * 16 + l15] = (_Float16)e;
        lp[r] += e;
      }
    }
#pragma unroll
    for (int m = 1; m < 16; m <<= 1) {
#pragma unroll
      for (int r = 0; r < 4; ++r) lp[r] += __shfl_xor(lp[r], m, 64);
    }
#pragma unroll
    for (int r = 0; r < 4; ++r) lac[r] += lp[r];

    // O += E @ V (f16 frags, f32 accum)
#pragma unroll
    for (int c2 = 0; c2 < 2; ++c2) {
      const half8 ef = *(const half8*)&Es[wv][l15][c2 * 32 + quad * 8];
#pragma unroll
      for (int p2 = 0; p2 < 4; ++p2) {
        const half8 vf = *(const half8*)&Vt[p2 * 16 + l15][c2 * 32 + quad * 8];
        oacc[p2] = mfma16(ef, vf, oacc[p2]);
      }
    }
  }

#pragma unroll
  for (int r = 0; r < 4; ++r) {
    const int qg = q0 + wv * 16 + quad * 4 + r;
    if (qg < seq) {
      const float invl = 1.f / lac[r];
      float* op = &aout[((size_t)(b * seq + qg)) * 512 + h * 64];
#pragma unroll
      for (int p2 = 0; p2 < 4; ++p2)
        op[p2 * 16 + l15] = oacc[p2][r] * invl;
      if (l15 == 0)
        lbuf[((size_t)(b * TH + h)) * 2048 + qg] = lac[r];
    }
  }
}

// ---------------------------------------------------------------------------
// attn pass2 (plain f16 MFMA)
// ---------------------------------------------------------------------------
__global__ __launch_bounds__(256)
void attn2_mfma(const float* __restrict__ qkv, const float* __restrict__ lbuf,
                float* __restrict__ outb, const int* __restrict__ mi,
                int seq_slot, int off_slot)
{
  const int seq = mi[seq_slot];
  const int q0 = blockIdx.y * 128;
  const int k0 = blockIdx.x * 128;
  if (q0 >= seq || k0 >= seq) return;
  const int b = blockIdx.z;
  const int woff = mi[off_slot];
  float* wout = outb + (size_t)woff + (size_t)b * seq * seq;

  __shared__ _Float16 Qs[128][72];
  __shared__ _Float16 Ksh[128][72];
  __shared__ float Linv[128];

  const int t = threadIdx.x;
  const int wv = t >> 6;
  const int lane = t & 63;
  const int l15 = lane & 15;
  const int quad = lane >> 4;
  const int srow = t >> 1;
  const int sseg = (t & 1) * 32;

  floatx4 acc[2][8];
#pragma unroll
  for (int i = 0; i < 2; ++i)
#pragma unroll
    for (int j = 0; j < 8; ++j) acc[i][j] = (floatx4){0.f, 0.f, 0.f, 0.f};

  for (int h = 0; h < TH; ++h) {
    __syncthreads();
    {
      const int qr = q0 + srow;
      const int kr = k0 + srow;
#pragma unroll
      for (int u = 0; u < 8; ++u) {
        float4 qv = make_float4(0.f, 0.f, 0.f, 0.f);
        float4 kv = make_float4(0.f, 0.f, 0.f, 0.f);
        if (qr < seq) qv = *(const float4*)&qkv[((size_t)(b * seq + qr)) * 1536 + h * 64 + sseg + u * 4];
        if (kr < seq) kv = *(const float4*)&qkv[((size_t)(b * seq + kr)) * 1536 + 512 + h * 64 + sseg + u * 4];
        half4 qh, kh;
        qh[0] = (_Float16)qv.x; qh[1] = (_Float16)qv.y; qh[2] = (_Float16)qv.z; qh[3] = (_Float16)qv.w;
        kh[0] = (_Float16)kv.x; kh[1] = (_Float16)kv.y; kh[2] = (_Float16)kv.z; kh[3] = (_Float16)kv.w;
        *(half4*)&Qs[srow][sseg + u * 4] = qh;
        *(half4*)&Ksh[srow][sseg + u * 4] = kh;
      }
      if (t < 128) {
        const float lv = (q0 + t < seq) ? lbuf[((size_t)(b * TH + h)) * 2048 + q0 + t] : 1.f;
        Linv[t] = 1.f / lv;
      }
    }
    __syncthreads();

    half8 af[2][2];
#pragma unroll
    for (int mp = 0; mp < 2; ++mp)
#pragma unroll
      for (int c = 0; c < 2; ++c)
        af[mp][c] = *(const half8*)&Qs[wv * 32 + mp * 16 + l15][c * 32 + quad * 8];
    float lv[2][4];
#pragma unroll
    for (int mp = 0; mp < 2; ++mp)
#pragma unroll
      for (int r = 0; r < 4; ++r)
        lv[mp][r] = Linv[wv * 32 + mp * 16 + quad * 4 + r];

#pragma unroll
    for (int np = 0; np < 8; ++np) {
      half8 bf[2];
#pragma unroll
      for (int c = 0; c < 2; ++c)
        bf[c] = *(const half8*)&Ksh[np * 16 + l15][c * 32 + quad * 8];
#pragma unroll
      for (int mp = 0; mp < 2; ++mp) {
        floatx4 s = (floatx4){0.f, 0.f, 0.f, 0.f};
        s = mfma16(af[mp][0], bf[0], s);
        s = mfma16(af[mp][1], bf[1], s);
#pragma unroll
        for (int r = 0; r < 4; ++r)
          acc[mp][np][r] += __expf(s[r] * 0.125f) * lv[mp][r];
      }
    }
  }

#pragma unroll
  for (int mp = 0; mp < 2; ++mp) {
#pragma unroll
    for (int r = 0; r < 4; ++r) {
      const int qg = q0 + wv * 32 + mp * 16 + quad * 4 + r;
      if (qg >= seq) continue;
      float* rowp = wout + (size_t)qg * seq;
#pragma unroll
      for (int np = 0; np < 8; ++np) {
        const int col = k0 + np * 16 + l15;
        if (col < seq) rowp[col] = acc[mp][np][r] * 0.125f;
      }
    }
  }
}

// ---------------------------------------------------------------------------
__global__ __launch_bounds__(256)
void merge_kernel(const float* __restrict__ src, float* __restrict__ dst,
                  const int* __restrict__ start, const float* __restrict__ cnt,
                  const int* __restrict__ mi, int seqin_slot, int seqout_slot)
{
  const int j = blockIdx.x;
  const int b = blockIdx.y;
  const int seqo = mi[seqout_slot];
  if (j >= seqo) return;
  const int seqi = mi[seqin_slot];
  const int s = start[j];
  const float cf = cnt[j];
  const int n = (int)cf;
  const int d0 = threadIdx.x * 2;
  float s0 = 0.f, s1 = 0.f;
  const float* p = &src[((size_t)b * seqi + s) * TD + d0];
  for (int i = 0; i < n; ++i) {
    const float2 v = *(const float2*)p;
    s0 += v.x; s1 += v.y;
    p += TD;
  }
  const float inv = 1.f / (cf + 1e-10f);
  float2 o; o.x = s0 * inv; o.y = s1 * inv;
  *(float2*)&dst[((size_t)b * seqo + j) * TD + d0] = o;
}

__global__ __launch_bounds__(256)
void expand_kernel(const float* __restrict__ gout, float* __restrict__ dout,
                   const int* __restrict__ gmap, const int* __restrict__ mi)
{
  const int j = blockIdx.x;
  const int b = blockIdx.y;
  const int ntok = mi[MI_NTOK];
  if (j >= ntok) return;
  const int m2 = mi[MI_M2];
  const int g = gmap[j];
  const int d0 = threadIdx.x * 2;
  const float2 v = *(const float2*)&gout[((size_t)b * m2 + g) * TD + d0];
  *(float2*)&dout[((size_t)b * ntok + j) * TD + d0] = v;
}

// ---------------------------------------------------------------------------
extern "C" void kernel_launch(void* const* d_in, const int* in_sizes, int n_in,
                              void* d_out, int out_size, void* d_ws, size_t ws_size,
                              hipStream_t stream)
{
  const float* x   = (const float*)d_in[0];
  const float* cWi = (const float*)d_in[1];
  const float* cbi = (const float*)d_in[2];
  const float* cWo = (const float*)d_in[3];
  const float* cbo = (const float*)d_in[4];
  const float* bWi = (const float*)d_in[5];
  const float* bbi = (const float*)d_in[6];
  const float* bWo = (const float*)d_in[7];
  const float* bbo = (const float*)d_in[8];
  const float* gWi = (const float*)d_in[9];
  const float* gbi = (const float*)d_in[10];
  const float* gWo = (const float*)d_in[11];
  const float* gbo = (const float*)d_in[12];
  const float* mw  = (const float*)d_in[13];
  const float* mbv = (const float*)d_in[14];
  const float* gw  = (const float*)d_in[15];
  const float* gbv = (const float*)d_in[16];
  float* outf = (float*)d_out;

  char* wsb = (char*)d_ws;
  int*   mi     = (int*)(wsb);
  int*   start1 = (int*)(wsb + 1024);
  float* cnt1   = (float*)(wsb + 1024 + 8192);
  int*   start2 = (int*)(wsb + 1024 + 2 * 8192);
  float* cnt2   = (float*)(wsb + 1024 + 3 * 8192);
  int*   gmap   = (int*)(wsb + 1024 + 4 * 8192);
  float* lbuf   = (float*)(wsb + 1024 + 5 * 8192);   // 32768 floats
  float* qkv    = (float*)(wsb + 196608);            // 4096 x 1536
  float* attn_o = qkv + 6291456;                     // 4096 x 512
  float* stg_o  = attn_o + 2097152;
  float* stg_m  = stg_o + 2097152;

  const dim3 blk(256);

  meta_kernel<<<dim3(1), blk, 0, stream>>>(mw, mbv, gw, gbv, mi, start1, cnt1, start2, cnt2, gmap);

  // ---- char stage ----
  gemm_mfma<<<dim3(12, 32), blk, 0, stream>>>(x, cWi, cbi, qkv, mi, MI_MCHAR, 1536);
  attn1_mfma<<<dim3(32, 16), blk, 0, stream>>>(qkv, lbuf, attn_o, mi, MI_SEQC);
  attn2_mfma<<<dim3(16, 16, 2), blk, 0, stream>>>(qkv, lbuf, outf, mi, MI_SEQC, MI_OFF_CW);
  gemm_mfma<<<dim3(4, 32), blk, 0, stream>>>(attn_o, cWo, cbo, stg_o, mi, MI_MCHAR, 512);
  merge_kernel<<<dim3(2048, 2), blk, 0, stream>>>(stg_o, stg_m, start1, cnt1, mi, MI_SEQC, MI_SEQB);

  // ---- block stage ----
  gemm_mfma<<<dim3(12, 32), blk, 0, stream>>>(stg_m, bWi, bbi, qkv, mi, MI_MBLOCK, 1536);
  attn1_mfma<<<dim3(32, 16), blk, 0, stream>>>(qkv, lbuf, attn_o, mi, MI_SEQB);
  attn2_mfma<<<dim3(16, 16, 2), blk, 0, stream>>>(qkv, lbuf, outf, mi, MI_SEQB, MI_OFF_BW);
  gemm_mfma<<<dim3(4, 32), blk, 0, stream>>>(attn_o, bWo, bbo, stg_o, mi, MI_MBLOCK, 512);
  merge_kernel<<<dim3(2048, 2), blk, 0, stream>>>(stg_o, stg_m, start2, cnt2, mi, MI_SEQB, MI_SEQG);

  // ---- glob stage ----
  gemm_mfma<<<dim3(12, 32), blk, 0, stream>>>(stg_m, gWi, gbi, qkv, mi, MI_MGLOB, 1536);
  attn1_mfma<<<dim3(32, 16), blk, 0, stream>>>(qkv, lbuf, attn_o, mi, MI_SEQG);
  attn2_mfma<<<dim3(16, 16, 2), blk, 0, stream>>>(qkv, lbuf, outf, mi, MI_SEQG, MI_OFF_GW);
  gemm_mfma<<<dim3(4, 32), blk, 0, stream>>>(attn_o, gWo, gbo, stg_o, mi, MI_MGLOB, 512);
  expand_kernel<<<dim3(2048, 2), blk, 0, stream>>>(stg_o, outf, gmap, mi);

  (void)in_sizes; (void)n_in; (void)out_size; (void)ws_size;
}

// Round 6
// 511.250 us; speedup vs baseline: 3.0482x; 1.2363x over previous
//
#include <hip/hip_runtime.h>
#include <cstdint>
#include <cstddef>

// DynamicHierarchicalAttention — MFMA pipeline.
// R5: qkv buffer stored as f16 directly from the QKV GEMM epilogue.
// qkv is consumed only by attn1 (Q,K,V) and attn2 (Q,K), which rounded to
// f16 anyway — rounding moved earlier, numerics identical, staging bytes
// and all staging cvt VALU removed. attn_o/proj path stays f32 split-f16
// (fp32-grade).

#define TB 2
#define TT 2048
#define TD 512
#define TH 8
#define THD 64

#define MI_M1 0
#define MI_M2 1
#define MI_NTOK 2
#define MI_OFF_CW 3
#define MI_OFF_BW 4
#define MI_OFF_GW 5
#define MI_MCHAR 6
#define MI_MBLOCK 7
#define MI_MGLOB 8
#define MI_SEQC 9
#define MI_SEQB 10
#define MI_SEQG 11

typedef _Float16 half8 __attribute__((ext_vector_type(8)));
typedef _Float16 half4 __attribute__((ext_vector_type(4)));
typedef float floatx4 __attribute__((ext_vector_type(4)));

__device__ __forceinline__ floatx4 mfma16(half8 a, half8 b, floatx4 c) {
  return __builtin_amdgcn_mfma_f32_16x16x32_f16(a, b, c, 0, 0, 0);
}

__device__ __forceinline__ double fracd(double x) { return x - floor(x); }

// ---------------------------------------------------------------------------
// parallel boundary scan for one phase: n elements, increment c.
// ---------------------------------------------------------------------------
__device__ int scan_phase(int n, double c, int* __restrict__ ids,
                          int* __restrict__ startg, float* __restrict__ cntg,
                          int* __restrict__ wsum, int t)
{
  int loc[8];
  const int base = t * 8;
#pragma unroll
  for (int j = 0; j < 8; ++j) {
    const int i = base + j;
    int f = 0;
    if (i < n) {
      const int pidx = (i == 0) ? n : i;   // roll: prev of elem 0 is elem n-1
      f = (fracd((double)(i + 1) * c) < fracd((double)pidx * c)) ? 1 : 0;
    }
    loc[j] = f + ((j > 0) ? loc[j - 1] : 0);
  }
  wsum[t] = loc[7];
  __syncthreads();
  for (int off = 1; off < 256; off <<= 1) {
    int u = 0;
    if (t >= off) u = wsum[t - off];
    __syncthreads();
    wsum[t] += u;
    __syncthreads();
  }
  const int excl = wsum[t] - loc[7];
  const int m = wsum[255];
#pragma unroll
  for (int j = 0; j < 8; ++j) {
    const int i = base + j;
    if (i < n) {
      const int id = excl + loc[j];
      ids[i] = id;
      const int f = loc[j] - ((j > 0) ? loc[j - 1] : 0);
      if (f) startg[id - 1] = i;
    }
  }
  __syncthreads();
  for (int j = t; j < m; j += 256)
    cntg[j] = (float)((((j + 1) < m) ? startg[j + 1] : n) - startg[j]);
  __syncthreads();
  return m;
}

// ---------------------------------------------------------------------------
__global__ __launch_bounds__(256)
void meta_kernel(const float* __restrict__ mw, const float* __restrict__ mb,
                 const float* __restrict__ gw, const float* __restrict__ gb,
                 int* __restrict__ mi,
                 int* __restrict__ start1, float* __restrict__ cnt1,
                 int* __restrict__ start2, float* __restrict__ cnt2,
                 int* __restrict__ gmap)
{
  __shared__ int ids1[TT];
  __shared__ int ids2[TT];
  __shared__ int wsum[256];
  __shared__ double dsh[256];
  const int t = threadIdx.x;

  double s1 = 0.0, s2 = 0.0;
  for (int i = t; i < TD; i += 256) { s1 += (double)mw[i]; s2 += (double)gw[i]; }
  dsh[t] = s1; __syncthreads();
  for (int off = 128; off > 0; off >>= 1) {
    if (t < off) dsh[t] += dsh[t + off];
    __syncthreads();
  }
  const double c1 = dsh[0] + (double)mb[0];
  __syncthreads();
  dsh[t] = s2; __syncthreads();
  for (int off = 128; off > 0; off >>= 1) {
    if (t < off) dsh[t] += dsh[t + off];
    __syncthreads();
  }
  const double c2 = dsh[0] + (double)gb[0];
  __syncthreads();

  const int m1 = scan_phase(TT, c1, ids1, start1, cnt1, wsum, t);
  const int m2 = scan_phase(m1, c2, ids2, start2, cnt2, wsum, t);

  int i0 = TT;
  if (m1 >= 1 && m2 >= 1) i0 = start1[start2[0]];
  const int ntok = TT - i0;

  if (t == 0) {
    mi[MI_M1] = m1; mi[MI_M2] = m2; mi[MI_NTOK] = ntok;
    const int offcw = TB * ntok * TD;
    mi[MI_OFF_CW] = offcw;
    mi[MI_OFF_BW] = offcw + TB * TT * TT;
    mi[MI_OFF_GW] = offcw + TB * TT * TT + TB * m1 * m1;
    mi[MI_MCHAR] = TB * TT;
    mi[MI_MBLOCK] = TB * m1;
    mi[MI_MGLOB] = TB * m2;
    mi[MI_SEQC] = TT;
    mi[MI_SEQB] = m1;
    mi[MI_SEQG] = m2;
  }
  for (int i = i0 + t; i < TT; i += 256)
    gmap[i - i0] = ids2[ids1[i] - 1] - 1;
}

// ---------------------------------------------------------------------------
// GEMM: C[M,N] = A[M,512] @ W[N,512]^T + bias, split-f16 MFMA (3 products).
// OutT = float (proj path) or _Float16 (qkv path, rounding moved earlier).
// ---------------------------------------------------------------------------
template <typename OutT>
__global__ __launch_bounds__(256)
void gemm_mfma(const float* __restrict__ A, const float* __restrict__ W,
               const float* __restrict__ bias, OutT* __restrict__ C,
               const int* __restrict__ mi, int m_slot, int N)
{
  const int M = mi[m_slot];
  const int bm = blockIdx.y * 128;
  if (bm >= M) return;
  const int bn = blockIdx.x * 128;
  __shared__ _Float16 Ah[128][40];
  __shared__ _Float16 Al[128][40];
  __shared__ _Float16 Wh[128][40];
  __shared__ _Float16 Wl[128][40];

  const int t = threadIdx.x;
  const int wv = t >> 6;
  const int lane = t & 63;
  const int l15 = lane & 15;
  const int quad = lane >> 4;
  const int srow = t >> 1;
  const int sseg = (t & 1) * 16;

  floatx4 acc[2][8];
#pragma unroll
  for (int i = 0; i < 2; ++i)
#pragma unroll
    for (int j = 0; j < 8; ++j) acc[i][j] = (floatx4){0.f, 0.f, 0.f, 0.f};

  for (int kk = 0; kk < TD; kk += 32) {
    __syncthreads();
    {
      const int ar = bm + srow;
      const int wr = bn + srow;
#pragma unroll
      for (int u = 0; u < 4; ++u) {
        float4 av = make_float4(0.f, 0.f, 0.f, 0.f);
        if (ar < M) av = *(const float4*)&A[(size_t)ar * TD + kk + sseg + u * 4];
        const float4 wvv = *(const float4*)&W[(size_t)wr * TD + kk + sseg + u * 4];
        half4 ahh, all, whh, wll;
        const float aa[4] = {av.x, av.y, av.z, av.w};
        const float ww[4] = {wvv.x, wvv.y, wvv.z, wvv.w};
#pragma unroll
        for (int e = 0; e < 4; ++e) {
          _Float16 h = (_Float16)aa[e];
          ahh[e] = h; all[e] = (_Float16)(aa[e] - (float)h);
          h = (_Float16)ww[e];
          whh[e] = h; wll[e] = (_Float16)(ww[e] - (float)h);
        }
        *(half4*)&Ah[srow][sseg + u * 4] = ahh;
        *(half4*)&Al[srow][sseg + u * 4] = all;
        *(half4*)&Wh[srow][sseg + u * 4] = whh;
        *(half4*)&Wl[srow][sseg + u * 4] = wll;
      }
    }
    __syncthreads();
    half8 ah[2], al[2];
#pragma unroll
    for (int mp = 0; mp < 2; ++mp) {
      ah[mp] = *(const half8*)&Ah[wv * 32 + mp * 16 + l15][quad * 8];
      al[mp] = *(const half8*)&Al[wv * 32 + mp * 16 + l15][quad * 8];
    }
#pragma unroll
    for (int np = 0; np < 8; ++np) {
      const half8 bh = *(const half8*)&Wh[np * 16 + l15][quad * 8];
      const half8 bl = *(const half8*)&Wl[np * 16 + l15][quad * 8];
#pragma unroll
      for (int mp = 0; mp < 2; ++mp) {
        acc[mp][np] = mfma16(al[mp], bh, acc[mp][np]);
        acc[mp][np] = mfma16(ah[mp], bl, acc[mp][np]);
        acc[mp][np] = mfma16(ah[mp], bh, acc[mp][np]);
      }
    }
  }
  float bv[8];
#pragma unroll
  for (int np = 0; np < 8; ++np) bv[np] = bias[bn + np * 16 + l15];
#pragma unroll
  for (int mp = 0; mp < 2; ++mp) {
#pragma unroll
    for (int r = 0; r < 4; ++r) {
      const int row = bm + wv * 32 + mp * 16 + quad * 4 + r;
      if (row < M) {
        OutT* cp = &C[(size_t)row * N + bn];
#pragma unroll
        for (int np = 0; np < 8; ++np)
          cp[np * 16 + l15] = (OutT)(acc[mp][np][r] + bv[np]);
      }
    }
  }
}

// ---------------------------------------------------------------------------
// attn pass1 (all-f16 MFMA, f32 accum/exp/l): qkv is f16 — staging is pure
// 16B load -> 16B LDS store, zero cvt.  16 MFMA per K-tile per wave.
// ---------------------------------------------------------------------------
__global__ __launch_bounds__(256)
void attn1_mfma(const _Float16* __restrict__ qkv, float* __restrict__ lbuf,
                float* __restrict__ aout, const int* __restrict__ mi, int seq_slot)
{
  const int seq = mi[seq_slot];
  const int q0 = blockIdx.x * 64;
  if (q0 >= seq) return;
  const int b = blockIdx.y >> 3, h = blockIdx.y & 7;
  const int t = threadIdx.x;
  const int wv = t >> 6;
  const int lane = t & 63;
  const int l15 = lane & 15;
  const int quad = lane >> 4;

  __shared__ _Float16 Kf[64][72];   // [k][d]
  __shared__ _Float16 Vt[64][72];   // [d][k] (transposed)
  __shared__ _Float16 Es[4][16][72];// per-wave [q][k]

  // Q fragment f16 direct load (held in regs across whole k loop)
  half8 qf[2];
  {
    const int qrow = q0 + wv * 16 + l15;
#pragma unroll
    for (int c = 0; c < 2; ++c) {
      half8 v = {};
      if (qrow < seq)
        v = *(const half8*)&qkv[((size_t)(b * seq + qrow)) * 1536 + h * 64 + c * 32 + quad * 8];
      qf[c] = v;
    }
  }

  floatx4 oacc[4];
#pragma unroll
  for (int p = 0; p < 4; ++p) oacc[p] = (floatx4){0.f, 0.f, 0.f, 0.f};
  float lac[4] = {0.f, 0.f, 0.f, 0.f};

  const int nkt = (seq + 63) >> 6;
  for (int kt = 0; kt < nkt; ++kt) {
    const int k0 = kt * 64;
    __syncthreads();
    { // stage K: thread handles row t>>2, 16 d (=32B) at seg
      const int row = t >> 2;
      const int seg = (t & 3) * 16;
      const int kg = k0 + row;
      half8 v0 = {}, v1 = {};
      if (kg < seq) {
        const _Float16* base = &qkv[((size_t)(b * seq + kg)) * 1536 + 512 + h * 64 + seg];
        v0 = *(const half8*)base;
        v1 = *(const half8*)(base + 8);
      }
      *(half8*)&Kf[row][seg] = v0;
      *(half8*)&Kf[row][seg + 8] = v1;
    }
    { // stage V transposed: wave wv owns d in [wv*16, wv*16+16), k = lane
      const int r = lane;
      const int kg = k0 + r;
      const int dbase = wv * 16;
      half8 v0 = {}, v1 = {};
      if (kg < seq) {
        const _Float16* base = &qkv[((size_t)(b * seq + kg)) * 1536 + 1024 + h * 64 + dbase];
        v0 = *(const half8*)base;
        v1 = *(const half8*)(base + 8);
      }
#pragma unroll
      for (int j = 0; j < 8; ++j) Vt[dbase + j][r] = v0[j];
#pragma unroll
      for (int j = 0; j < 8; ++j) Vt[dbase + 8 + j][r] = v1[j];
    }
    __syncthreads();

    // S = Q K^T (f16), exp (f32), E to LDS f16, partial l (f32)
    float lp[4] = {0.f, 0.f, 0.f, 0.f};
#pragma unroll
    for (int p = 0; p < 4; ++p) {
      floatx4 s = (floatx4){0.f, 0.f, 0.f, 0.f};
#pragma unroll
      for (int c = 0; c < 2; ++c) {
        const half8 kf = *(const half8*)&Kf[p * 16 + l15][c * 32 + quad * 8];
        s = mfma16(qf[c], kf, s);
      }
      const int kg = k0 + p * 16 + l15;
#pragma unroll
      for (int r = 0; r < 4; ++r) {
        const float e = (kg < seq) ? __expf(s[r] * 0.125f) : 0.f;
        Es[wv][quad * 4 + r][p * 16 + l15] = (_Float16)e;
        lp[r] += e;
      }
    }
#pragma unroll
    for (int m = 1; m < 16; m <<= 1) {
#pragma unroll
      for (int r = 0; r < 4; ++r) lp[r] += __shfl_xor(lp[r], m, 64);
    }
#pragma unroll
    for (int r = 0; r < 4; ++r) lac[r] += lp[r];

    // O += E @ V (f16 frags, f32 accum)
#pragma unroll
    for (int c2 = 0; c2 < 2; ++c2) {
      const half8 ef = *(const half8*)&Es[wv][l15][c2 * 32 + quad * 8];
#pragma unroll
      for (int p2 = 0; p2 < 4; ++p2) {
        const half8 vf = *(const half8*)&Vt[p2 * 16 + l15][c2 * 32 + quad * 8];
        oacc[p2] = mfma16(ef, vf, oacc[p2]);
      }
    }
  }

#pragma unroll
  for (int r = 0; r < 4; ++r) {
    const int qg = q0 + wv * 16 + quad * 4 + r;
    if (qg < seq) {
      const float invl = 1.f / lac[r];
      float* op = &aout[((size_t)(b * seq + qg)) * 512 + h * 64];
#pragma unroll
      for (int p2 = 0; p2 < 4; ++p2)
        op[p2 * 16 + l15] = oacc[p2][r] * invl;
      if (l15 == 0)
        lbuf[((size_t)(b * TH + h)) * 2048 + qg] = lac[r];
    }
  }
}

// ---------------------------------------------------------------------------
// attn pass2 (plain f16 MFMA): qkv f16 — staging is a pure copy.
// ---------------------------------------------------------------------------
__global__ __launch_bounds__(256)
void attn2_mfma(const _Float16* __restrict__ qkv, const float* __restrict__ lbuf,
                float* __restrict__ outb, const int* __restrict__ mi,
                int seq_slot, int off_slot)
{
  const int seq = mi[seq_slot];
  const int q0 = blockIdx.y * 128;
  const int k0 = blockIdx.x * 128;
  if (q0 >= seq || k0 >= seq) return;
  const int b = blockIdx.z;
  const int woff = mi[off_slot];
  float* wout = outb + (size_t)woff + (size_t)b * seq * seq;

  __shared__ _Float16 Qs[128][72];
  __shared__ _Float16 Ksh[128][72];
  __shared__ float Linv[128];

  const int t = threadIdx.x;
  const int wv = t >> 6;
  const int lane = t & 63;
  const int l15 = lane & 15;
  const int quad = lane >> 4;
  const int srow = t >> 1;
  const int sseg = (t & 1) * 32;

  floatx4 acc[2][8];
#pragma unroll
  for (int i = 0; i < 2; ++i)
#pragma unroll
    for (int j = 0; j < 8; ++j) acc[i][j] = (floatx4){0.f, 0.f, 0.f, 0.f};

  for (int h = 0; h < TH; ++h) {
    __syncthreads();
    {
      const int qr = q0 + srow;
      const int kr = k0 + srow;
#pragma unroll
      for (int u = 0; u < 4; ++u) {
        half8 qv = {}, kv = {};
        if (qr < seq)
          qv = *(const half8*)&qkv[((size_t)(b * seq + qr)) * 1536 + h * 64 + sseg + u * 8];
        if (kr < seq)
          kv = *(const half8*)&qkv[((size_t)(b * seq + kr)) * 1536 + 512 + h * 64 + sseg + u * 8];
        *(half8*)&Qs[srow][sseg + u * 8] = qv;
        *(half8*)&Ksh[srow][sseg + u * 8] = kv;
      }
      if (t < 128) {
        const float lv = (q0 + t < seq) ? lbuf[((size_t)(b * TH + h)) * 2048 + q0 + t] : 1.f;
        Linv[t] = 1.f / lv;
      }
    }
    __syncthreads();

    half8 af[2][2];
#pragma unroll
    for (int mp = 0; mp < 2; ++mp)
#pragma unroll
      for (int c = 0; c < 2; ++c)
        af[mp][c] = *(const half8*)&Qs[wv * 32 + mp * 16 + l15][c * 32 + quad * 8];
    float lv[2][4];
#pragma unroll
    for (int mp = 0; mp < 2; ++mp)
#pragma unroll
      for (int r = 0; r < 4; ++r)
        lv[mp][r] = Linv[wv * 32 + mp * 16 + quad * 4 + r];

#pragma unroll
    for (int np = 0; np < 8; ++np) {
      half8 bf[2];
#pragma unroll
      for (int c = 0; c < 2; ++c)
        bf[c] = *(const half8*)&Ksh[np * 16 + l15][c * 32 + quad * 8];
#pragma unroll
      for (int mp = 0; mp < 2; ++mp) {
        floatx4 s = (floatx4){0.f, 0.f, 0.f, 0.f};
        s = mfma16(af[mp][0], bf[0], s);
        s = mfma16(af[mp][1], bf[1], s);
#pragma unroll
        for (int r = 0; r < 4; ++r)
          acc[mp][np][r] += __expf(s[r] * 0.125f) * lv[mp][r];
      }
    }
  }

#pragma unroll
  for (int mp = 0; mp < 2; ++mp) {
#pragma unroll
    for (int r = 0; r < 4; ++r) {
      const int qg = q0 + wv * 32 + mp * 16 + quad * 4 + r;
      if (qg >= seq) continue;
      float* rowp = wout + (size_t)qg * seq;
#pragma unroll
      for (int np = 0; np < 8; ++np) {
        const int col = k0 + np * 16 + l15;
        if (col < seq) rowp[col] = acc[mp][np][r] * 0.125f;
      }
    }
  }
}

// ---------------------------------------------------------------------------
__global__ __launch_bounds__(256)
void merge_kernel(const float* __restrict__ src, float* __restrict__ dst,
                  const int* __restrict__ start, const float* __restrict__ cnt,
                  const int* __restrict__ mi, int seqin_slot, int seqout_slot)
{
  const int j = blockIdx.x;
  const int b = blockIdx.y;
  const int seqo = mi[seqout_slot];
  if (j >= seqo) return;
  const int seqi = mi[seqin_slot];
  const int s = start[j];
  const float cf = cnt[j];
  const int n = (int)cf;
  const int d0 = threadIdx.x * 2;
  float s0 = 0.f, s1 = 0.f;
  const float* p = &src[((size_t)b * seqi + s) * TD + d0];
  for (int i = 0; i < n; ++i) {
    const float2 v = *(const float2*)p;
    s0 += v.x; s1 += v.y;
    p += TD;
  }
  const float inv = 1.f / (cf + 1e-10f);
  float2 o; o.x = s0 * inv; o.y = s1 * inv;
  *(float2*)&dst[((size_t)b * seqo + j) * TD + d0] = o;
}

__global__ __launch_bounds__(256)
void expand_kernel(const float* __restrict__ gout, float* __restrict__ dout,
                   const int* __restrict__ gmap, const int* __restrict__ mi)
{
  const int j = blockIdx.x;
  const int b = blockIdx.y;
  const int ntok = mi[MI_NTOK];
  if (j >= ntok) return;
  const int m2 = mi[MI_M2];
  const int g = gmap[j];
  const int d0 = threadIdx.x * 2;
  const float2 v = *(const float2*)&gout[((size_t)b * m2 + g) * TD + d0];
  *(float2*)&dout[((size_t)b * ntok + j) * TD + d0] = v;
}

// ---------------------------------------------------------------------------
extern "C" void kernel_launch(void* const* d_in, const int* in_sizes, int n_in,
                              void* d_out, int out_size, void* d_ws, size_t ws_size,
                              hipStream_t stream)
{
  const float* x   = (const float*)d_in[0];
  const float* cWi = (const float*)d_in[1];
  const float* cbi = (const float*)d_in[2];
  const float* cWo = (const float*)d_in[3];
  const float* cbo = (const float*)d_in[4];
  const float* bWi = (const float*)d_in[5];
  const float* bbi = (const float*)d_in[6];
  const float* bWo = (const float*)d_in[7];
  const float* bbo = (const float*)d_in[8];
  const float* gWi = (const float*)d_in[9];
  const float* gbi = (const float*)d_in[10];
  const float* gWo = (const float*)d_in[11];
  const float* gbo = (const float*)d_in[12];
  const float* mw  = (const float*)d_in[13];
  const float* mbv = (const float*)d_in[14];
  const float* gw  = (const float*)d_in[15];
  const float* gbv = (const float*)d_in[16];
  float* outf = (float*)d_out;

  char* wsb = (char*)d_ws;
  int*   mi     = (int*)(wsb);
  int*   start1 = (int*)(wsb + 1024);
  float* cnt1   = (float*)(wsb + 1024 + 8192);
  int*   start2 = (int*)(wsb + 1024 + 2 * 8192);
  float* cnt2   = (float*)(wsb + 1024 + 3 * 8192);
  int*   gmap   = (int*)(wsb + 1024 + 4 * 8192);
  float* lbuf   = (float*)(wsb + 1024 + 5 * 8192);      // 32768 floats
  _Float16* qkv = (_Float16*)(wsb + 196608);            // 4096 x 1536 f16 (12.6 MB)
  float* attn_o = (float*)(wsb + 196608 + 12582912);    // 4096 x 512 f32
  float* stg_o  = attn_o + 2097152;
  float* stg_m  = stg_o + 2097152;

  const dim3 blk(256);

  meta_kernel<<<dim3(1), blk, 0, stream>>>(mw, mbv, gw, gbv, mi, start1, cnt1, start2, cnt2, gmap);

  // ---- char stage ----
  gemm_mfma<_Float16><<<dim3(12, 32), blk, 0, stream>>>(x, cWi, cbi, qkv, mi, MI_MCHAR, 1536);
  attn1_mfma<<<dim3(32, 16), blk, 0, stream>>>(qkv, lbuf, attn_o, mi, MI_SEQC);
  attn2_mfma<<<dim3(16, 16, 2), blk, 0, stream>>>(qkv, lbuf, outf, mi, MI_SEQC, MI_OFF_CW);
  gemm_mfma<float><<<dim3(4, 32), blk, 0, stream>>>(attn_o, cWo, cbo, stg_o, mi, MI_MCHAR, 512);
  merge_kernel<<<dim3(2048, 2), blk, 0, stream>>>(stg_o, stg_m, start1, cnt1, mi, MI_SEQC, MI_SEQB);

  // ---- block stage ----
  gemm_mfma<_Float16><<<dim3(12, 32), blk, 0, stream>>>(stg_m, bWi, bbi, qkv, mi, MI_MBLOCK, 1536);
  attn1_mfma<<<dim3(32, 16), blk, 0, stream>>>(qkv, lbuf, attn_o, mi, MI_SEQB);
  attn2_mfma<<<dim3(16, 16, 2), blk, 0, stream>>>(qkv, lbuf, outf, mi, MI_SEQB, MI_OFF_BW);
  gemm_mfma<float><<<dim3(4, 32), blk, 0, stream>>>(attn_o, bWo, bbo, stg_o, mi, MI_MBLOCK, 512);
  merge_kernel<<<dim3(2048, 2), blk, 0, stream>>>(stg_o, stg_m, start2, cnt2, mi, MI_SEQB, MI_SEQG);

  // ---- glob stage ----
  gemm_mfma<_Float16><<<dim3(12, 32), blk, 0, stream>>>(stg_m, gWi, gbi, qkv, mi, MI_MGLOB, 1536);
  attn1_mfma<<<dim3(32, 16), blk, 0, stream>>>(qkv, lbuf, attn_o, mi, MI_SEQG);
  attn2_mfma<<<dim3(16, 16, 2), blk, 0, stream>>>(qkv, lbuf, outf, mi, MI_SEQG, MI_OFF_GW);
  gemm_mfma<float><<<dim3(4, 32), blk, 0, stream>>>(attn_o, gWo, gbo, stg_o, mi, MI_MGLOB, 512);
  expand_kernel<<<dim3(2048, 2), blk, 0, stream>>>(stg_o, outf, gmap, mi);

  (void)in_sizes; (void)n_in; (void)out_size; (void)ws_size;
}

// Round 7
// 489.545 us; speedup vs baseline: 3.1833x; 1.0443x over previous
//
#include <hip/hip_runtime.h>
#include <cstdint>
#include <cstddef>

// DynamicHierarchicalAttention — MFMA pipeline.
// R6: attn1 split-K x2 (additive partial O,l — no rescale needed), l via
// ones-MFMA (kills the 16x ds_swizzle reduction), combine kernel normalizes.
// qkv f16 (R5), GEMMs split-f16 (fp32-grade).

#define TB 2
#define TT 2048
#define TD 512
#define TH 8
#define THD 64
#define KC 2   // k-chunks in attn1

#define MI_M1 0
#define MI_M2 1
#define MI_NTOK 2
#define MI_OFF_CW 3
#define MI_OFF_BW 4
#define MI_OFF_GW 5
#define MI_MCHAR 6
#define MI_MBLOCK 7
#define MI_MGLOB 8
#define MI_SEQC 9
#define MI_SEQB 10
#define MI_SEQG 11

typedef _Float16 half8 __attribute__((ext_vector_type(8)));
typedef _Float16 half4 __attribute__((ext_vector_type(4)));
typedef float floatx4 __attribute__((ext_vector_type(4)));

__device__ __forceinline__ floatx4 mfma16(half8 a, half8 b, floatx4 c) {
  return __builtin_amdgcn_mfma_f32_16x16x32_f16(a, b, c, 0, 0, 0);
}

__device__ __forceinline__ double fracd(double x) { return x - floor(x); }

// ---------------------------------------------------------------------------
// parallel boundary scan for one phase: n elements, increment c.
// ---------------------------------------------------------------------------
__device__ int scan_phase(int n, double c, int* __restrict__ ids,
                          int* __restrict__ startg, float* __restrict__ cntg,
                          int* __restrict__ wsum, int t)
{
  int loc[8];
  const int base = t * 8;
#pragma unroll
  for (int j = 0; j < 8; ++j) {
    const int i = base + j;
    int f = 0;
    if (i < n) {
      const int pidx = (i == 0) ? n : i;   // roll: prev of elem 0 is elem n-1
      f = (fracd((double)(i + 1) * c) < fracd((double)pidx * c)) ? 1 : 0;
    }
    loc[j] = f + ((j > 0) ? loc[j - 1] : 0);
  }
  wsum[t] = loc[7];
  __syncthreads();
  for (int off = 1; off < 256; off <<= 1) {
    int u = 0;
    if (t >= off) u = wsum[t - off];
    __syncthreads();
    wsum[t] += u;
    __syncthreads();
  }
  const int excl = wsum[t] - loc[7];
  const int m = wsum[255];
#pragma unroll
  for (int j = 0; j < 8; ++j) {
    const int i = base + j;
    if (i < n) {
      const int id = excl + loc[j];
      ids[i] = id;
      const int f = loc[j] - ((j > 0) ? loc[j - 1] : 0);
      if (f) startg[id - 1] = i;
    }
  }
  __syncthreads();
  for (int j = t; j < m; j += 256)
    cntg[j] = (float)((((j + 1) < m) ? startg[j + 1] : n) - startg[j]);
  __syncthreads();
  return m;
}

// ---------------------------------------------------------------------------
__global__ __launch_bounds__(256)
void meta_kernel(const float* __restrict__ mw, const float* __restrict__ mb,
                 const float* __restrict__ gw, const float* __restrict__ gb,
                 int* __restrict__ mi,
                 int* __restrict__ start1, float* __restrict__ cnt1,
                 int* __restrict__ start2, float* __restrict__ cnt2,
                 int* __restrict__ gmap)
{
  __shared__ int ids1[TT];
  __shared__ int ids2[TT];
  __shared__ int wsum[256];
  __shared__ double dsh[256];
  const int t = threadIdx.x;

  double s1 = 0.0, s2 = 0.0;
  for (int i = t; i < TD; i += 256) { s1 += (double)mw[i]; s2 += (double)gw[i]; }
  dsh[t] = s1; __syncthreads();
  for (int off = 128; off > 0; off >>= 1) {
    if (t < off) dsh[t] += dsh[t + off];
    __syncthreads();
  }
  const double c1 = dsh[0] + (double)mb[0];
  __syncthreads();
  dsh[t] = s2; __syncthreads();
  for (int off = 128; off > 0; off >>= 1) {
    if (t < off) dsh[t] += dsh[t + off];
    __syncthreads();
  }
  const double c2 = dsh[0] + (double)gb[0];
  __syncthreads();

  const int m1 = scan_phase(TT, c1, ids1, start1, cnt1, wsum, t);
  const int m2 = scan_phase(m1, c2, ids2, start2, cnt2, wsum, t);

  int i0 = TT;
  if (m1 >= 1 && m2 >= 1) i0 = start1[start2[0]];
  const int ntok = TT - i0;

  if (t == 0) {
    mi[MI_M1] = m1; mi[MI_M2] = m2; mi[MI_NTOK] = ntok;
    const int offcw = TB * ntok * TD;
    mi[MI_OFF_CW] = offcw;
    mi[MI_OFF_BW] = offcw + TB * TT * TT;
    mi[MI_OFF_GW] = offcw + TB * TT * TT + TB * m1 * m1;
    mi[MI_MCHAR] = TB * TT;
    mi[MI_MBLOCK] = TB * m1;
    mi[MI_MGLOB] = TB * m2;
    mi[MI_SEQC] = TT;
    mi[MI_SEQB] = m1;
    mi[MI_SEQG] = m2;
  }
  for (int i = i0 + t; i < TT; i += 256)
    gmap[i - i0] = ids2[ids1[i] - 1] - 1;
}

// ---------------------------------------------------------------------------
// GEMM: C[M,N] = A[M,512] @ W[N,512]^T + bias, split-f16 MFMA (3 products).
// OutT = float (proj path) or _Float16 (qkv path).
// ---------------------------------------------------------------------------
template <typename OutT>
__global__ __launch_bounds__(256)
void gemm_mfma(const float* __restrict__ A, const float* __restrict__ W,
               const float* __restrict__ bias, OutT* __restrict__ C,
               const int* __restrict__ mi, int m_slot, int N)
{
  const int M = mi[m_slot];
  const int bm = blockIdx.y * 128;
  if (bm >= M) return;
  const int bn = blockIdx.x * 128;
  __shared__ _Float16 Ah[128][40];
  __shared__ _Float16 Al[128][40];
  __shared__ _Float16 Wh[128][40];
  __shared__ _Float16 Wl[128][40];

  const int t = threadIdx.x;
  const int wv = t >> 6;
  const int lane = t & 63;
  const int l15 = lane & 15;
  const int quad = lane >> 4;
  const int srow = t >> 1;
  const int sseg = (t & 1) * 16;

  floatx4 acc[2][8];
#pragma unroll
  for (int i = 0; i < 2; ++i)
#pragma unroll
    for (int j = 0; j < 8; ++j) acc[i][j] = (floatx4){0.f, 0.f, 0.f, 0.f};

  for (int kk = 0; kk < TD; kk += 32) {
    __syncthreads();
    {
      const int ar = bm + srow;
      const int wr = bn + srow;
#pragma unroll
      for (int u = 0; u < 4; ++u) {
        float4 av = make_float4(0.f, 0.f, 0.f, 0.f);
        if (ar < M) av = *(const float4*)&A[(size_t)ar * TD + kk + sseg + u * 4];
        const float4 wvv = *(const float4*)&W[(size_t)wr * TD + kk + sseg + u * 4];
        half4 ahh, all, whh, wll;
        const float aa[4] = {av.x, av.y, av.z, av.w};
        const float ww[4] = {wvv.x, wvv.y, wvv.z, wvv.w};
#pragma unroll
        for (int e = 0; e < 4; ++e) {
          _Float16 h = (_Float16)aa[e];
          ahh[e] = h; all[e] = (_Float16)(aa[e] - (float)h);
          h = (_Float16)ww[e];
          whh[e] = h; wll[e] = (_Float16)(ww[e] - (float)h);
        }
        *(half4*)&Ah[srow][sseg + u * 4] = ahh;
        *(half4*)&Al[srow][sseg + u * 4] = all;
        *(half4*)&Wh[srow][sseg + u * 4] = whh;
        *(half4*)&Wl[srow][sseg + u * 4] = wll;
      }
    }
    __syncthreads();
    half8 ah[2], al[2];
#pragma unroll
    for (int mp = 0; mp < 2; ++mp) {
      ah[mp] = *(const half8*)&Ah[wv * 32 + mp * 16 + l15][quad * 8];
      al[mp] = *(const half8*)&Al[wv * 32 + mp * 16 + l15][quad * 8];
    }
#pragma unroll
    for (int np = 0; np < 8; ++np) {
      const half8 bh = *(const half8*)&Wh[np * 16 + l15][quad * 8];
      const half8 bl = *(const half8*)&Wl[np * 16 + l15][quad * 8];
#pragma unroll
      for (int mp = 0; mp < 2; ++mp) {
        acc[mp][np] = mfma16(al[mp], bh, acc[mp][np]);
        acc[mp][np] = mfma16(ah[mp], bl, acc[mp][np]);
        acc[mp][np] = mfma16(ah[mp], bh, acc[mp][np]);
      }
    }
  }
  float bv[8];
#pragma unroll
  for (int np = 0; np < 8; ++np) bv[np] = bias[bn + np * 16 + l15];
#pragma unroll
  for (int mp = 0; mp < 2; ++mp) {
#pragma unroll
    for (int r = 0; r < 4; ++r) {
      const int row = bm + wv * 32 + mp * 16 + quad * 4 + r;
      if (row < M) {
        OutT* cp = &C[(size_t)row * N + bn];
#pragma unroll
        for (int np = 0; np < 8; ++np)
          cp[np * 16 + l15] = (OutT)(acc[mp][np][r] + bv[np]);
      }
    }
  }
}

// ---------------------------------------------------------------------------
// attn pass1, split-K (z = chunk): partial unnormalized O and partial l for
// this chunk's k-range.  l computed via ones-MFMA (no shuffle reduction).
// ---------------------------------------------------------------------------
__global__ __launch_bounds__(256)
void attn1_mfma(const _Float16* __restrict__ qkv,
                float* __restrict__ l0, float* __restrict__ l1,
                float* __restrict__ O0, float* __restrict__ O1,
                const int* __restrict__ mi, int seq_slot)
{
  const int seq = mi[seq_slot];
  const int q0 = blockIdx.x * 64;
  if (q0 >= seq) return;
  const int b = blockIdx.y >> 3, h = blockIdx.y & 7;
  const int z = blockIdx.z;
  float* lP = z ? l1 : l0;
  float* oP = z ? O1 : O0;
  const int t = threadIdx.x;
  const int wv = t >> 6;
  const int lane = t & 63;
  const int l15 = lane & 15;
  const int quad = lane >> 4;

  __shared__ _Float16 Kf[64][72];   // [k][d]
  __shared__ _Float16 Vt[64][72];   // [d][k] (transposed)
  __shared__ _Float16 Es[4][16][72];// per-wave [q][k]

  half8 qf[2];
  {
    const int qrow = q0 + wv * 16 + l15;
#pragma unroll
    for (int c = 0; c < 2; ++c) {
      half8 v = {};
      if (qrow < seq)
        v = *(const half8*)&qkv[((size_t)(b * seq + qrow)) * 1536 + h * 64 + c * 32 + quad * 8];
      qf[c] = v;
    }
  }
  half8 ones;
#pragma unroll
  for (int j = 0; j < 8; ++j) ones[j] = (_Float16)1.0f;

  floatx4 oacc[4];
#pragma unroll
  for (int p = 0; p < 4; ++p) oacc[p] = (floatx4){0.f, 0.f, 0.f, 0.f};
  floatx4 lacc = (floatx4){0.f, 0.f, 0.f, 0.f};

  const int nkt = (seq + 63) >> 6;
  const int nkc = (nkt + KC - 1) / KC;
  const int kt_beg = z * nkc;
  const int kt_end = min(kt_beg + nkc, nkt);

  for (int kt = kt_beg; kt < kt_end; ++kt) {
    const int k0 = kt * 64;
    __syncthreads();
    { // stage K: thread handles row t>>2, 16 d at seg
      const int row = t >> 2;
      const int seg = (t & 3) * 16;
      const int kg = k0 + row;
      half8 v0 = {}, v1 = {};
      if (kg < seq) {
        const _Float16* base = &qkv[((size_t)(b * seq + kg)) * 1536 + 512 + h * 64 + seg];
        v0 = *(const half8*)base;
        v1 = *(const half8*)(base + 8);
      }
      *(half8*)&Kf[row][seg] = v0;
      *(half8*)&Kf[row][seg + 8] = v1;
    }
    { // stage V transposed: wave wv owns d in [wv*16, wv*16+16), k = lane
      const int r = lane;
      const int kg = k0 + r;
      const int dbase = wv * 16;
      half8 v0 = {}, v1 = {};
      if (kg < seq) {
        const _Float16* base = &qkv[((size_t)(b * seq + kg)) * 1536 + 1024 + h * 64 + dbase];
        v0 = *(const half8*)base;
        v1 = *(const half8*)(base + 8);
      }
#pragma unroll
      for (int j = 0; j < 8; ++j) Vt[dbase + j][r] = v0[j];
#pragma unroll
      for (int j = 0; j < 8; ++j) Vt[dbase + 8 + j][r] = v1[j];
    }
    __syncthreads();

    // S = Q K^T (f16), exp (f32), E to LDS f16
#pragma unroll
    for (int p = 0; p < 4; ++p) {
      floatx4 s = (floatx4){0.f, 0.f, 0.f, 0.f};
#pragma unroll
      for (int c = 0; c < 2; ++c) {
        const half8 kf = *(const half8*)&Kf[p * 16 + l15][c * 32 + quad * 8];
        s = mfma16(qf[c], kf, s);
      }
      const int kg = k0 + p * 16 + l15;
#pragma unroll
      for (int r = 0; r < 4; ++r) {
        const float e = (kg < seq) ? __expf(s[r] * 0.125f) : 0.f;
        Es[wv][quad * 4 + r][p * 16 + l15] = (_Float16)e;
      }
    }
    __syncthreads();   // wave-private Es, but cheap consistency with stage loop

    // O += E @ V ; l += E @ ones (f16 frags, f32 accum)
#pragma unroll
    for (int c2 = 0; c2 < 2; ++c2) {
      const half8 ef = *(const half8*)&Es[wv][l15][c2 * 32 + quad * 8];
      lacc = mfma16(ef, ones, lacc);
#pragma unroll
      for (int p2 = 0; p2 < 4; ++p2) {
        const half8 vf = *(const half8*)&Vt[p2 * 16 + l15][c2 * 32 + quad * 8];
        oacc[p2] = mfma16(ef, vf, oacc[p2]);
      }
    }
  }

#pragma unroll
  for (int r = 0; r < 4; ++r) {
    const int qg = q0 + wv * 16 + quad * 4 + r;
    if (qg < seq) {
      float* op = &oP[((size_t)(b * seq + qg)) * 512 + h * 64];
#pragma unroll
      for (int p2 = 0; p2 < 4; ++p2)
        op[p2 * 16 + l15] = oacc[p2][r];
      if (l15 == 0)
        lP[((size_t)(b * TH + h)) * 2048 + qg] = lacc[r];
    }
  }
}

// ---------------------------------------------------------------------------
// combine: O = (O0+O1)/(l0+l1) into O0; ltot = l0+l1 for attn2.
// One block per row (b*seq+q), 256 threads x 2 floats.
// ---------------------------------------------------------------------------
__global__ __launch_bounds__(256)
void combine_kernel(float* __restrict__ O0, const float* __restrict__ O1,
                    const float* __restrict__ l0, const float* __restrict__ l1,
                    float* __restrict__ ltot,
                    const int* __restrict__ mi, int m_slot, int seq_slot)
{
  const int row = blockIdx.x;
  const int M = mi[m_slot];
  if (row >= M) return;
  const int seq = mi[seq_slot];
  const int b = (row >= seq) ? 1 : 0;
  const int q = row - b * seq;
  const int t = threadIdx.x;
  const int d0 = t * 2;
  const int h = d0 >> 6;
  const size_t lidx = ((size_t)(b * TH + h)) * 2048 + q;
  const float lt = l0[lidx] + l1[lidx];
  const float inv = 1.f / lt;
  float* op = &O0[(size_t)row * 512 + d0];
  const float* o1p = &O1[(size_t)row * 512 + d0];
  const float2 a = *(const float2*)op;
  const float2 c = *(const float2*)o1p;
  float2 o; o.x = (a.x + c.x) * inv; o.y = (a.y + c.y) * inv;
  *(float2*)op = o;
  if ((t & 31) == 0) ltot[((size_t)(b * TH + (t >> 5))) * 2048 + q] =
      l0[((size_t)(b * TH + (t >> 5))) * 2048 + q] +
      l1[((size_t)(b * TH + (t >> 5))) * 2048 + q];
}

// ---------------------------------------------------------------------------
// attn pass2 (plain f16 MFMA): qkv f16 — staging is a pure copy.
// ---------------------------------------------------------------------------
__global__ __launch_bounds__(256)
void attn2_mfma(const _Float16* __restrict__ qkv, const float* __restrict__ lbuf,
                float* __restrict__ outb, const int* __restrict__ mi,
                int seq_slot, int off_slot)
{
  const int seq = mi[seq_slot];
  const int q0 = blockIdx.y * 128;
  const int k0 = blockIdx.x * 128;
  if (q0 >= seq || k0 >= seq) return;
  const int b = blockIdx.z;
  const int woff = mi[off_slot];
  float* wout = outb + (size_t)woff + (size_t)b * seq * seq;

  __shared__ _Float16 Qs[128][72];
  __shared__ _Float16 Ksh[128][72];
  __shared__ float Linv[128];

  const int t = threadIdx.x;
  const int wv = t >> 6;
  const int lane = t & 63;
  const int l15 = lane & 15;
  const int quad = lane >> 4;
  const int srow = t >> 1;
  const int sseg = (t & 1) * 32;

  floatx4 acc[2][8];
#pragma unroll
  for (int i = 0; i < 2; ++i)
#pragma unroll
    for (int j = 0; j < 8; ++j) acc[i][j] = (floatx4){0.f, 0.f, 0.f, 0.f};

  for (int h = 0; h < TH; ++h) {
    __syncthreads();
    {
      const int qr = q0 + srow;
      const int kr = k0 + srow;
#pragma unroll
      for (int u = 0; u < 4; ++u) {
        half8 qv = {}, kv = {};
        if (qr < seq)
          qv = *(const half8*)&qkv[((size_t)(b * seq + qr)) * 1536 + h * 64 + sseg + u * 8];
        if (kr < seq)
          kv = *(const half8*)&qkv[((size_t)(b * seq + kr)) * 1536 + 512 + h * 64 + sseg + u * 8];
        *(half8*)&Qs[srow][sseg + u * 8] = qv;
        *(half8*)&Ksh[srow][sseg + u * 8] = kv;
      }
      if (t < 128) {
        const float lv = (q0 + t < seq) ? lbuf[((size_t)(b * TH + h)) * 2048 + q0 + t] : 1.f;
        Linv[t] = 1.f / lv;
      }
    }
    __syncthreads();

    half8 af[2][2];
#pragma unroll
    for (int mp = 0; mp < 2; ++mp)
#pragma unroll
      for (int c = 0; c < 2; ++c)
        af[mp][c] = *(const half8*)&Qs[wv * 32 + mp * 16 + l15][c * 32 + quad * 8];
    float lv[2][4];
#pragma unroll
    for (int mp = 0; mp < 2; ++mp)
#pragma unroll
      for (int r = 0; r < 4; ++r)
        lv[mp][r] = Linv[wv * 32 + mp * 16 + quad * 4 + r];

#pragma unroll
    for (int np = 0; np < 8; ++np) {
      half8 bf[2];
#pragma unroll
      for (int c = 0; c < 2; ++c)
        bf[c] = *(const half8*)&Ksh[np * 16 + l15][c * 32 + quad * 8];
#pragma unroll
      for (int mp = 0; mp < 2; ++mp) {
        floatx4 s = (floatx4){0.f, 0.f, 0.f, 0.f};
        s = mfma16(af[mp][0], bf[0], s);
        s = mfma16(af[mp][1], bf[1], s);
#pragma unroll
        for (int r = 0; r < 4; ++r)
          acc[mp][np][r] += __expf(s[r] * 0.125f) * lv[mp][r];
      }
    }
  }

#pragma unroll
  for (int mp = 0; mp < 2; ++mp) {
#pragma unroll
    for (int r = 0; r < 4; ++r) {
      const int qg = q0 + wv * 32 + mp * 16 + quad * 4 + r;
      if (qg >= seq) continue;
      float* rowp = wout + (size_t)qg * seq;
#pragma unroll
      for (int np = 0; np < 8; ++np) {
        const int col = k0 + np * 16 + l15;
        if (col < seq) rowp[col] = acc[mp][np][r] * 0.125f;
      }
    }
  }
}

// ---------------------------------------------------------------------------
__global__ __launch_bounds__(256)
void merge_kernel(const float* __restrict__ src, float* __restrict__ dst,
                  const int* __restrict__ start, const float* __restrict__ cnt,
                  const int* __restrict__ mi, int seqin_slot, int seqout_slot)
{
  const int j = blockIdx.x;
  const int b = blockIdx.y;
  const int seqo = mi[seqout_slot];
  if (j >= seqo) return;
  const int seqi = mi[seqin_slot];
  const int s = start[j];
  const float cf = cnt[j];
  const int n = (int)cf;
  const int d0 = threadIdx.x * 2;
  float s0 = 0.f, s1 = 0.f;
  const float* p = &src[((size_t)b * seqi + s) * TD + d0];
  for (int i = 0; i < n; ++i) {
    const float2 v = *(const float2*)p;
    s0 += v.x; s1 += v.y;
    p += TD;
  }
  const float inv = 1.f / (cf + 1e-10f);
  float2 o; o.x = s0 * inv; o.y = s1 * inv;
  *(float2*)&dst[((size_t)b * seqo + j) * TD + d0] = o;
}

__global__ __launch_bounds__(256)
void expand_kernel(const float* __restrict__ gout, float* __restrict__ dout,
                   const int* __restrict__ gmap, const int* __restrict__ mi)
{
  const int j = blockIdx.x;
  const int b = blockIdx.y;
  const int ntok = mi[MI_NTOK];
  if (j >= ntok) return;
  const int m2 = mi[MI_M2];
  const int g = gmap[j];
  const int d0 = threadIdx.x * 2;
  const float2 v = *(const float2*)&gout[((size_t)b * m2 + g) * TD + d0];
  *(float2*)&dout[((size_t)b * ntok + j) * TD + d0] = v;
}

// ---------------------------------------------------------------------------
extern "C" void kernel_launch(void* const* d_in, const int* in_sizes, int n_in,
                              void* d_out, int out_size, void* d_ws, size_t ws_size,
                              hipStream_t stream)
{
  const float* x   = (const float*)d_in[0];
  const float* cWi = (const float*)d_in[1];
  const float* cbi = (const float*)d_in[2];
  const float* cWo = (const float*)d_in[3];
  const float* cbo = (const float*)d_in[4];
  const float* bWi = (const float*)d_in[5];
  const float* bbi = (const float*)d_in[6];
  const float* bWo = (const float*)d_in[7];
  const float* bbo = (const float*)d_in[8];
  const float* gWi = (const float*)d_in[9];
  const float* gbi = (const float*)d_in[10];
  const float* gWo = (const float*)d_in[11];
  const float* gbo = (const float*)d_in[12];
  const float* mw  = (const float*)d_in[13];
  const float* mbv = (const float*)d_in[14];
  const float* gw  = (const float*)d_in[15];
  const float* gbv = (const float*)d_in[16];
  float* outf = (float*)d_out;

  char* wsb = (char*)d_ws;
  int*   mi     = (int*)(wsb);
  int*   start1 = (int*)(wsb + 1024);
  float* cnt1   = (float*)(wsb + 1024 + 8192);
  int*   start2 = (int*)(wsb + 1024 + 2 * 8192);
  float* cnt2   = (float*)(wsb + 1024 + 3 * 8192);
  int*   gmap   = (int*)(wsb + 1024 + 4 * 8192);
  float* l0     = (float*)(wsb + 65536);               // 32768 f32
  float* l1     = (float*)(wsb + 196608);              // 32768 f32
  float* ltot   = (float*)(wsb + 327680);              // 32768 f32
  _Float16* qkv = (_Float16*)(wsb + 458752);           // 4096x1536 f16 (12.6 MB)
  float* O0     = (float*)(wsb + 458752 + 12582912);   // attn_o partial/final, 8 MB
  float* O1     = O0 + 2097152;                        // 8 MB
  float* stg_o  = O1 + 2097152;                        // 8 MB
  float* stg_m  = stg_o + 2097152;                     // 8 MB  (total ~46.5 MB)

  const dim3 blk(256);

  meta_kernel<<<dim3(1), blk, 0, stream>>>(mw, mbv, gw, gbv, mi, start1, cnt1, start2, cnt2, gmap);

  // ---- char stage ----
  gemm_mfma<_Float16><<<dim3(12, 32), blk, 0, stream>>>(x, cWi, cbi, qkv, mi, MI_MCHAR, 1536);
  attn1_mfma<<<dim3(32, 16, KC), blk, 0, stream>>>(qkv, l0, l1, O0, O1, mi, MI_SEQC);
  combine_kernel<<<dim3(4096), blk, 0, stream>>>(O0, O1, l0, l1, ltot, mi, MI_MCHAR, MI_SEQC);
  attn2_mfma<<<dim3(16, 16, 2), blk, 0, stream>>>(qkv, ltot, outf, mi, MI_SEQC, MI_OFF_CW);
  gemm_mfma<float><<<dim3(4, 32), blk, 0, stream>>>(O0, cWo, cbo, stg_o, mi, MI_MCHAR, 512);
  merge_kernel<<<dim3(2048, 2), blk, 0, stream>>>(stg_o, stg_m, start1, cnt1, mi, MI_SEQC, MI_SEQB);

  // ---- block stage ----
  gemm_mfma<_Float16><<<dim3(12, 32), blk, 0, stream>>>(stg_m, bWi, bbi, qkv, mi, MI_MBLOCK, 1536);
  attn1_mfma<<<dim3(32, 16, KC), blk, 0, stream>>>(qkv, l0, l1, O0, O1, mi, MI_SEQB);
  combine_kernel<<<dim3(4096), blk, 0, stream>>>(O0, O1, l0, l1, ltot, mi, MI_MBLOCK, MI_SEQB);
  attn2_mfma<<<dim3(16, 16, 2), blk, 0, stream>>>(qkv, ltot, outf, mi, MI_SEQB, MI_OFF_BW);
  gemm_mfma<float><<<dim3(4, 32), blk, 0, stream>>>(O0, bWo, bbo, stg_o, mi, MI_MBLOCK, 512);
  merge_kernel<<<dim3(2048, 2), blk, 0, stream>>>(stg_o, stg_m, start2, cnt2, mi, MI_SEQB, MI_SEQG);

  // ---- glob stage ----
  gemm_mfma<_Float16><<<dim3(12, 32), blk, 0, stream>>>(stg_m, gWi, gbi, qkv, mi, MI_MGLOB, 1536);
  attn1_mfma<<<dim3(32, 16, KC), blk, 0, stream>>>(qkv, l0, l1, O0, O1, mi, MI_SEQG);
  combine_kernel<<<dim3(4096), blk, 0, stream>>>(O0, O1, l0, l1, ltot, mi, MI_MGLOB, MI_SEQG);
  attn2_mfma<<<dim3(16, 16, 2), blk, 0, stream>>>(qkv, ltot, outf, mi, MI_SEQG, MI_OFF_GW);
  gemm_mfma<float><<<dim3(4, 32), blk, 0, stream>>>(O0, gWo, gbo, stg_o, mi, MI_MGLOB, 512);
  expand_kernel<<<dim3(2048, 2), blk, 0, stream>>>(stg_o, outf, gmap, mi);

  (void)in_sizes; (void)n_in; (void)out_size; (void)ws_size;
}

// Round 8
// 457.285 us; speedup vs baseline: 3.4079x; 1.0705x over previous
//
#include <hip/hip_runtime.h>
#include <cstdint>
#include <cstddef>

// DynamicHierarchicalAttention — MFMA pipeline.
// R7: GEMM retiled 128x64 (3-5 blocks/CU), attn2 retiled q=64 (4-5 blocks/CU),
// combine fused into proj-GEMM A-stage and attn2 Linv, attn1 barrier/V-stage
// trim.  qkv f16 (R5), split-K x2 attn1 (R6), GEMMs split-f16 (fp32-grade).

#define TB 2
#define TT 2048
#define TD 512
#define TH 8
#define THD 64
#define KC 2   // k-chunks in attn1

#define MI_M1 0
#define MI_M2 1
#define MI_NTOK 2
#define MI_OFF_CW 3
#define MI_OFF_BW 4
#define MI_OFF_GW 5
#define MI_MCHAR 6
#define MI_MBLOCK 7
#define MI_MGLOB 8
#define MI_SEQC 9
#define MI_SEQB 10
#define MI_SEQG 11

typedef _Float16 half8 __attribute__((ext_vector_type(8)));
typedef _Float16 half4 __attribute__((ext_vector_type(4)));
typedef _Float16 half2_t __attribute__((ext_vector_type(2)));
typedef float floatx4 __attribute__((ext_vector_type(4)));

__device__ __forceinline__ floatx4 mfma16(half8 a, half8 b, floatx4 c) {
  return __builtin_amdgcn_mfma_f32_16x16x32_f16(a, b, c, 0, 0, 0);
}

__device__ __forceinline__ double fracd(double x) { return x - floor(x); }

// ---------------------------------------------------------------------------
// parallel boundary scan for one phase: n elements, increment c.
// ---------------------------------------------------------------------------
__device__ int scan_phase(int n, double c, int* __restrict__ ids,
                          int* __restrict__ startg, float* __restrict__ cntg,
                          int* __restrict__ wsum, int t)
{
  int loc[8];
  const int base = t * 8;
#pragma unroll
  for (int j = 0; j < 8; ++j) {
    const int i = base + j;
    int f = 0;
    if (i < n) {
      const int pidx = (i == 0) ? n : i;   // roll: prev of elem 0 is elem n-1
      f = (fracd((double)(i + 1) * c) < fracd((double)pidx * c)) ? 1 : 0;
    }
    loc[j] = f + ((j > 0) ? loc[j - 1] : 0);
  }
  wsum[t] = loc[7];
  __syncthreads();
  for (int off = 1; off < 256; off <<= 1) {
    int u = 0;
    if (t >= off) u = wsum[t - off];
    __syncthreads();
    wsum[t] += u;
    __syncthreads();
  }
  const int excl = wsum[t] - loc[7];
  const int m = wsum[255];
#pragma unroll
  for (int j = 0; j < 8; ++j) {
    const int i = base + j;
    if (i < n) {
      const int id = excl + loc[j];
      ids[i] = id;
      const int f = loc[j] - ((j > 0) ? loc[j - 1] : 0);
      if (f) startg[id - 1] = i;
    }
  }
  __syncthreads();
  for (int j = t; j < m; j += 256)
    cntg[j] = (float)((((j + 1) < m) ? startg[j + 1] : n) - startg[j]);
  __syncthreads();
  return m;
}

// ---------------------------------------------------------------------------
__global__ __launch_bounds__(256)
void meta_kernel(const float* __restrict__ mw, const float* __restrict__ mb,
                 const float* __restrict__ gw, const float* __restrict__ gb,
                 int* __restrict__ mi,
                 int* __restrict__ start1, float* __restrict__ cnt1,
                 int* __restrict__ start2, float* __restrict__ cnt2,
                 int* __restrict__ gmap)
{
  __shared__ int ids1[TT];
  __shared__ int ids2[TT];
  __shared__ int wsum[256];
  __shared__ double dsh[256];
  const int t = threadIdx.x;

  double s1 = 0.0, s2 = 0.0;
  for (int i = t; i < TD; i += 256) { s1 += (double)mw[i]; s2 += (double)gw[i]; }
  dsh[t] = s1; __syncthreads();
  for (int off = 128; off > 0; off >>= 1) {
    if (t < off) dsh[t] += dsh[t + off];
    __syncthreads();
  }
  const double c1 = dsh[0] + (double)mb[0];
  __syncthreads();
  dsh[t] = s2; __syncthreads();
  for (int off = 128; off > 0; off >>= 1) {
    if (t < off) dsh[t] += dsh[t + off];
    __syncthreads();
  }
  const double c2 = dsh[0] + (double)gb[0];
  __syncthreads();

  const int m1 = scan_phase(TT, c1, ids1, start1, cnt1, wsum, t);
  const int m2 = scan_phase(m1, c2, ids2, start2, cnt2, wsum, t);

  int i0 = TT;
  if (m1 >= 1 && m2 >= 1) i0 = start1[start2[0]];
  const int ntok = TT - i0;

  if (t == 0) {
    mi[MI_M1] = m1; mi[MI_M2] = m2; mi[MI_NTOK] = ntok;
    const int offcw = TB * ntok * TD;
    mi[MI_OFF_CW] = offcw;
    mi[MI_OFF_BW] = offcw + TB * TT * TT;
    mi[MI_OFF_GW] = offcw + TB * TT * TT + TB * m1 * m1;
    mi[MI_MCHAR] = TB * TT;
    mi[MI_MBLOCK] = TB * m1;
    mi[MI_MGLOB] = TB * m2;
    mi[MI_SEQC] = TT;
    mi[MI_SEQB] = m1;
    mi[MI_SEQG] = m2;
  }
  for (int i = i0 + t; i < TT; i += 256)
    gmap[i - i0] = ids2[ids1[i] - 1] - 1;
}

// ---------------------------------------------------------------------------
// GEMM 128m x 64n tile: C[M,N] = A[M,512] @ W[N,512]^T + bias, split-f16.
// 4 waves x (2 mp x 4 np).  grid (N/64, ceil(M/128)).
// ---------------------------------------------------------------------------
template <typename OutT>
__global__ __launch_bounds__(256)
void gemm_mfma(const float* __restrict__ A, const float* __restrict__ W,
               const float* __restrict__ bias, OutT* __restrict__ C,
               const int* __restrict__ mi, int m_slot, int N)
{
  const int M = mi[m_slot];
  const int bm = blockIdx.y * 128;
  if (bm >= M) return;
  const int bn = blockIdx.x * 64;
  __shared__ _Float16 Ah[128][40];
  __shared__ _Float16 Al[128][40];
  __shared__ _Float16 Wh[64][40];
  __shared__ _Float16 Wl[64][40];

  const int t = threadIdx.x;
  const int wv = t >> 6;
  const int lane = t & 63;
  const int l15 = lane & 15;
  const int quad = lane >> 4;
  const int srowA = t >> 1;
  const int ssegA = (t & 1) * 16;
  const int srowW = t >> 2;
  const int ssegW = (t & 3) * 8;

  floatx4 acc[2][4];
#pragma unroll
  for (int i = 0; i < 2; ++i)
#pragma unroll
    for (int j = 0; j < 4; ++j) acc[i][j] = (floatx4){0.f, 0.f, 0.f, 0.f};

  for (int kk = 0; kk < TD; kk += 32) {
    __syncthreads();
    {
      const int ar = bm + srowA;
#pragma unroll
      for (int u = 0; u < 4; ++u) {
        float4 av = make_float4(0.f, 0.f, 0.f, 0.f);
        if (ar < M) av = *(const float4*)&A[(size_t)ar * TD + kk + ssegA + u * 4];
        const float aa[4] = {av.x, av.y, av.z, av.w};
        half4 hi, lo;
#pragma unroll
        for (int e = 0; e < 4; ++e) {
          const _Float16 h = (_Float16)aa[e];
          hi[e] = h; lo[e] = (_Float16)(aa[e] - (float)h);
        }
        *(half4*)&Ah[srowA][ssegA + u * 4] = hi;
        *(half4*)&Al[srowA][ssegA + u * 4] = lo;
      }
#pragma unroll
      for (int u = 0; u < 2; ++u) {
        const float4 wvv = *(const float4*)&W[(size_t)(bn + srowW) * TD + kk + ssegW + u * 4];
        const float ww[4] = {wvv.x, wvv.y, wvv.z, wvv.w};
        half4 hi, lo;
#pragma unroll
        for (int e = 0; e < 4; ++e) {
          const _Float16 h = (_Float16)ww[e];
          hi[e] = h; lo[e] = (_Float16)(ww[e] - (float)h);
        }
        *(half4*)&Wh[srowW][ssegW + u * 4] = hi;
        *(half4*)&Wl[srowW][ssegW + u * 4] = lo;
      }
    }
    __syncthreads();
    half8 ah[2], al[2];
#pragma unroll
    for (int mp = 0; mp < 2; ++mp) {
      ah[mp] = *(const half8*)&Ah[wv * 32 + mp * 16 + l15][quad * 8];
      al[mp] = *(const half8*)&Al[wv * 32 + mp * 16 + l15][quad * 8];
    }
#pragma unroll
    for (int np = 0; np < 4; ++np) {
      const half8 bh = *(const half8*)&Wh[np * 16 + l15][quad * 8];
      const half8 bl = *(const half8*)&Wl[np * 16 + l15][quad * 8];
#pragma unroll
      for (int mp = 0; mp < 2; ++mp) {
        acc[mp][np] = mfma16(al[mp], bh, acc[mp][np]);
        acc[mp][np] = mfma16(ah[mp], bl, acc[mp][np]);
        acc[mp][np] = mfma16(ah[mp], bh, acc[mp][np]);
      }
    }
  }
  float bv[4];
#pragma unroll
  for (int np = 0; np < 4; ++np) bv[np] = bias[bn + np * 16 + l15];
#pragma unroll
  for (int mp = 0; mp < 2; ++mp) {
#pragma unroll
    for (int r = 0; r < 4; ++r) {
      const int row = bm + wv * 32 + mp * 16 + quad * 4 + r;
      if (row < M) {
        OutT* cp = &C[(size_t)row * N + bn];
#pragma unroll
        for (int np = 0; np < 4; ++np)
          cp[np * 16 + l15] = (OutT)(acc[mp][np][r] + bv[np]);
      }
    }
  }
}

// ---------------------------------------------------------------------------
// Proj GEMM with fused combine: A-row = (O0+O1) * 1/(l0+l1) (per-head l).
// Same 128x64 tiling.  N = 512.
// ---------------------------------------------------------------------------
__global__ __launch_bounds__(256)
void gemm_norm_mfma(const float* __restrict__ O0, const float* __restrict__ O1,
                    const float* __restrict__ l0, const float* __restrict__ l1,
                    const float* __restrict__ W, const float* __restrict__ bias,
                    float* __restrict__ C, const int* __restrict__ mi,
                    int m_slot, int seq_slot)
{
  const int M = mi[m_slot];
  const int bm = blockIdx.y * 128;
  if (bm >= M) return;
  const int seq = mi[seq_slot];
  const int bn = blockIdx.x * 64;
  __shared__ _Float16 Ah[128][40];
  __shared__ _Float16 Al[128][40];
  __shared__ _Float16 Wh[64][40];
  __shared__ _Float16 Wl[64][40];

  const int t = threadIdx.x;
  const int wv = t >> 6;
  const int lane = t & 63;
  const int l15 = lane & 15;
  const int quad = lane >> 4;
  const int srowA = t >> 1;
  const int ssegA = (t & 1) * 16;
  const int srowW = t >> 2;
  const int ssegW = (t & 3) * 8;

  // row-constant pieces for the fused normalization
  const int ar = bm + srowA;
  const int ab = (ar >= seq) ? 1 : 0;
  const int aq = ar - ab * seq;

  floatx4 acc[2][4];
#pragma unroll
  for (int i = 0; i < 2; ++i)
#pragma unroll
    for (int j = 0; j < 4; ++j) acc[i][j] = (floatx4){0.f, 0.f, 0.f, 0.f};

  for (int kk = 0; kk < TD; kk += 32) {
    __syncthreads();
    {
      float linv = 0.f;
      if (ar < M) {
        const int h = kk >> 6;   // 32-chunk lies within one 64-head block
        const size_t lidx = ((size_t)(ab * TH + h)) * 2048 + aq;
        linv = 1.f / (l0[lidx] + l1[lidx]);
      }
#pragma unroll
      for (int u = 0; u < 4; ++u) {
        float4 av = make_float4(0.f, 0.f, 0.f, 0.f);
        if (ar < M) {
          const size_t off = (size_t)ar * TD + kk + ssegA + u * 4;
          const float4 a0 = *(const float4*)&O0[off];
          const float4 a1 = *(const float4*)&O1[off];
          av.x = (a0.x + a1.x) * linv; av.y = (a0.y + a1.y) * linv;
          av.z = (a0.z + a1.z) * linv; av.w = (a0.w + a1.w) * linv;
        }
        const float aa[4] = {av.x, av.y, av.z, av.w};
        half4 hi, lo;
#pragma unroll
        for (int e = 0; e < 4; ++e) {
          const _Float16 h = (_Float16)aa[e];
          hi[e] = h; lo[e] = (_Float16)(aa[e] - (float)h);
        }
        *(half4*)&Ah[srowA][ssegA + u * 4] = hi;
        *(half4*)&Al[srowA][ssegA + u * 4] = lo;
      }
#pragma unroll
      for (int u = 0; u < 2; ++u) {
        const float4 wvv = *(const float4*)&W[(size_t)(bn + srowW) * TD + kk + ssegW + u * 4];
        const float ww[4] = {wvv.x, wvv.y, wvv.z, wvv.w};
        half4 hi, lo;
#pragma unroll
        for (int e = 0; e < 4; ++e) {
          const _Float16 h = (_Float16)ww[e];
          hi[e] = h; lo[e] = (_Float16)(ww[e] - (float)h);
        }
        *(half4*)&Wh[srowW][ssegW + u * 4] = hi;
        *(half4*)&Wl[srowW][ssegW + u * 4] = lo;
      }
    }
    __syncthreads();
    half8 ah[2], al[2];
#pragma unroll
    for (int mp = 0; mp < 2; ++mp) {
      ah[mp] = *(const half8*)&Ah[wv * 32 + mp * 16 + l15][quad * 8];
      al[mp] = *(const half8*)&Al[wv * 32 + mp * 16 + l15][quad * 8];
    }
#pragma unroll
    for (int np = 0; np < 4; ++np) {
      const half8 bh = *(const half8*)&Wh[np * 16 + l15][quad * 8];
      const half8 bl = *(const half8*)&Wl[np * 16 + l15][quad * 8];
#pragma unroll
      for (int mp = 0; mp < 2; ++mp) {
        acc[mp][np] = mfma16(al[mp], bh, acc[mp][np]);
        acc[mp][np] = mfma16(ah[mp], bl, acc[mp][np]);
        acc[mp][np] = mfma16(ah[mp], bh, acc[mp][np]);
      }
    }
  }
  float bv[4];
#pragma unroll
  for (int np = 0; np < 4; ++np) bv[np] = bias[bn + np * 16 + l15];
#pragma unroll
  for (int mp = 0; mp < 2; ++mp) {
#pragma unroll
    for (int r = 0; r < 4; ++r) {
      const int row = bm + wv * 32 + mp * 16 + quad * 4 + r;
      if (row < M) {
        float* cp = &C[(size_t)row * 512 + bn];
#pragma unroll
        for (int np = 0; np < 4; ++np)
          cp[np * 16 + l15] = acc[mp][np][r] + bv[np];
      }
    }
  }
}

// ---------------------------------------------------------------------------
// attn pass1, split-K (z = chunk): partial unnormalized O and partial l.
// l via ones-MFMA.  V staged via pair-packed b32 stores.  2 barriers/tile.
// ---------------------------------------------------------------------------
__global__ __launch_bounds__(256)
void attn1_mfma(const _Float16* __restrict__ qkv,
                float* __restrict__ l0, float* __restrict__ l1,
                float* __restrict__ O0, float* __restrict__ O1,
                const int* __restrict__ mi, int seq_slot)
{
  const int seq = mi[seq_slot];
  const int q0 = blockIdx.x * 64;
  if (q0 >= seq) return;
  const int b = blockIdx.y >> 3, h = blockIdx.y & 7;
  const int z = blockIdx.z;
  float* lP = z ? l1 : l0;
  float* oP = z ? O1 : O0;
  const int t = threadIdx.x;
  const int wv = t >> 6;
  const int lane = t & 63;
  const int l15 = lane & 15;
  const int quad = lane >> 4;

  __shared__ _Float16 Kf[64][72];   // [k][d]
  __shared__ _Float16 Vt[64][72];   // [d][k] (transposed)
  __shared__ _Float16 Es[4][16][72];// per-wave [q][k]

  half8 qf[2];
  {
    const int qrow = q0 + wv * 16 + l15;
#pragma unroll
    for (int c = 0; c < 2; ++c) {
      half8 v = {};
      if (qrow < seq)
        v = *(const half8*)&qkv[((size_t)(b * seq + qrow)) * 1536 + h * 64 + c * 32 + quad * 8];
      qf[c] = v;
    }
  }
  half8 ones;
#pragma unroll
  for (int j = 0; j < 8; ++j) ones[j] = (_Float16)1.0f;

  floatx4 oacc[4];
#pragma unroll
  for (int p = 0; p < 4; ++p) oacc[p] = (floatx4){0.f, 0.f, 0.f, 0.f};
  floatx4 lacc = (floatx4){0.f, 0.f, 0.f, 0.f};

  const int nkt = (seq + 63) >> 6;
  const int nkc = (nkt + KC - 1) / KC;
  const int kt_beg = z * nkc;
  const int kt_end = min(kt_beg + nkc, nkt);

  for (int kt = kt_beg; kt < kt_end; ++kt) {
    const int k0 = kt * 64;
    __syncthreads();
    { // stage K: thread handles row t>>2, 16 d at seg
      const int row = t >> 2;
      const int seg = (t & 3) * 16;
      const int kg = k0 + row;
      half8 v0 = {}, v1 = {};
      if (kg < seq) {
        const _Float16* base = &qkv[((size_t)(b * seq + kg)) * 1536 + 512 + h * 64 + seg];
        v0 = *(const half8*)base;
        v1 = *(const half8*)(base + 8);
      }
      *(half8*)&Kf[row][seg] = v0;
      *(half8*)&Kf[row][seg + 8] = v1;
    }
    { // stage V transposed: pair-packed b32 stores.
      // lane -> token-pair tp (0..31), d-chunk dsel (0..1); wave owns 16 d.
      const int tp = lane & 31;
      const int dsel = lane >> 5;
      const int dbase = wv * 16 + dsel * 8;
      const int kg0 = k0 + tp * 2;
      half8 vA = {}, vB = {};
      if (kg0 < seq)
        vA = *(const half8*)&qkv[((size_t)(b * seq + kg0)) * 1536 + 1024 + h * 64 + dbase];
      if (kg0 + 1 < seq)
        vB = *(const half8*)&qkv[((size_t)(b * seq + kg0 + 1)) * 1536 + 1024 + h * 64 + dbase];
#pragma unroll
      for (int j = 0; j < 8; ++j) {
        half2_t pk; pk[0] = vA[j]; pk[1] = vB[j];
        *(half2_t*)&Vt[dbase + j][tp * 2] = pk;
      }
    }
    __syncthreads();

    // S = Q K^T (f16), exp (f32), E to LDS f16 (wave-private: no barrier)
#pragma unroll
    for (int p = 0; p < 4; ++p) {
      floatx4 s = (floatx4){0.f, 0.f, 0.f, 0.f};
#pragma unroll
      for (int c = 0; c < 2; ++c) {
        const half8 kf = *(const half8*)&Kf[p * 16 + l15][c * 32 + quad * 8];
        s = mfma16(qf[c], kf, s);
      }
      const int kg = k0 + p * 16 + l15;
#pragma unroll
      for (int r = 0; r < 4; ++r) {
        const float e = (kg < seq) ? __expf(s[r] * 0.125f) : 0.f;
        Es[wv][quad * 4 + r][p * 16 + l15] = (_Float16)e;
      }
    }

    // O += E @ V ; l += E @ ones (f16 frags, f32 accum)
#pragma unroll
    for (int c2 = 0; c2 < 2; ++c2) {
      const half8 ef = *(const half8*)&Es[wv][l15][c2 * 32 + quad * 8];
      lacc = mfma16(ef, ones, lacc);
#pragma unroll
      for (int p2 = 0; p2 < 4; ++p2) {
        const half8 vf = *(const half8*)&Vt[p2 * 16 + l15][c2 * 32 + quad * 8];
        oacc[p2] = mfma16(ef, vf, oacc[p2]);
      }
    }
  }

#pragma unroll
  for (int r = 0; r < 4; ++r) {
    const int qg = q0 + wv * 16 + quad * 4 + r;
    if (qg < seq) {
      float* op = &oP[((size_t)(b * seq + qg)) * 512 + h * 64];
#pragma unroll
      for (int p2 = 0; p2 < 4; ++p2)
        op[p2 * 16 + l15] = oacc[p2][r];
      if (l15 == 0)
        lP[((size_t)(b * TH + h)) * 2048 + qg] = lacc[r];
    }
  }
}

// ---------------------------------------------------------------------------
// attn pass2 (plain f16 MFMA), q-tile 64 x k-tile 128; Linv = 1/(l0+l1).
// grid (seq/128, seq/64, B) worst-case.
// ---------------------------------------------------------------------------
__global__ __launch_bounds__(256)
void attn2_mfma(const _Float16* __restrict__ qkv,
                const float* __restrict__ l0, const float* __restrict__ l1,
                float* __restrict__ outb, const int* __restrict__ mi,
                int seq_slot, int off_slot)
{
  const int seq = mi[seq_slot];
  const int q0 = blockIdx.y * 64;
  const int k0 = blockIdx.x * 128;
  if (q0 >= seq || k0 >= seq) return;
  const int b = blockIdx.z;
  const int woff = mi[off_slot];
  float* wout = outb + (size_t)woff + (size_t)b * seq * seq;

  __shared__ _Float16 Qs[64][72];
  __shared__ _Float16 Ksh[128][72];
  __shared__ float Linv[64];

  const int t = threadIdx.x;
  const int wv = t >> 6;
  const int lane = t & 63;
  const int l15 = lane & 15;
  const int quad = lane >> 4;
  const int srowQ = t >> 2;
  const int ssegQ = (t & 3) * 16;
  const int srowK = t >> 1;
  const int ssegK = (t & 1) * 32;

  floatx4 acc[8];
#pragma unroll
  for (int j = 0; j < 8; ++j) acc[j] = (floatx4){0.f, 0.f, 0.f, 0.f};

  for (int h = 0; h < TH; ++h) {
    __syncthreads();
    {
      const int qr = q0 + srowQ;
      half8 q0v = {}, q1v = {};
      if (qr < seq) {
        const _Float16* base = &qkv[((size_t)(b * seq + qr)) * 1536 + h * 64 + ssegQ];
        q0v = *(const half8*)base;
        q1v = *(const half8*)(base + 8);
      }
      *(half8*)&Qs[srowQ][ssegQ] = q0v;
      *(half8*)&Qs[srowQ][ssegQ + 8] = q1v;

      const int kr = k0 + srowK;
#pragma unroll
      for (int u = 0; u < 4; ++u) {
        half8 kv = {};
        if (kr < seq)
          kv = *(const half8*)&qkv[((size_t)(b * seq + kr)) * 1536 + 512 + h * 64 + ssegK + u * 8];
        *(half8*)&Ksh[srowK][ssegK + u * 8] = kv;
      }
      if (t < 64) {
        float lv = 1.f;
        if (q0 + t < seq) {
          const size_t lidx = ((size_t)(b * TH + h)) * 2048 + q0 + t;
          lv = l0[lidx] + l1[lidx];
        }
        Linv[t] = 1.f / lv;
      }
    }
    __syncthreads();

    half8 af[2];
#pragma unroll
    for (int c = 0; c < 2; ++c)
      af[c] = *(const half8*)&Qs[wv * 16 + l15][c * 32 + quad * 8];
    float lv[4];
#pragma unroll
    for (int r = 0; r < 4; ++r)
      lv[r] = Linv[wv * 16 + quad * 4 + r];

#pragma unroll
    for (int np = 0; np < 8; ++np) {
      half8 bf[2];
#pragma unroll
      for (int c = 0; c < 2; ++c)
        bf[c] = *(const half8*)&Ksh[np * 16 + l15][c * 32 + quad * 8];
      floatx4 s = (floatx4){0.f, 0.f, 0.f, 0.f};
      s = mfma16(af[0], bf[0], s);
      s = mfma16(af[1], bf[1], s);
#pragma unroll
      for (int r = 0; r < 4; ++r)
        acc[np][r] += __expf(s[r] * 0.125f) * lv[r];
    }
  }

#pragma unroll
  for (int r = 0; r < 4; ++r) {
    const int qg = q0 + wv * 16 + quad * 4 + r;
    if (qg >= seq) continue;
    float* rowp = wout + (size_t)qg * seq;
#pragma unroll
    for (int np = 0; np < 8; ++np) {
      const int col = k0 + np * 16 + l15;
      if (col < seq) rowp[col] = acc[np][r] * 0.125f;
    }
  }
}

// ---------------------------------------------------------------------------
__global__ __launch_bounds__(256)
void merge_kernel(const float* __restrict__ src, float* __restrict__ dst,
                  const int* __restrict__ start, const float* __restrict__ cnt,
                  const int* __restrict__ mi, int seqin_slot, int seqout_slot)
{
  const int j = blockIdx.x;
  const int b = blockIdx.y;
  const int seqo = mi[seqout_slot];
  if (j >= seqo) return;
  const int seqi = mi[seqin_slot];
  const int s = start[j];
  const float cf = cnt[j];
  const int n = (int)cf;
  const int d0 = threadIdx.x * 2;
  float s0 = 0.f, s1 = 0.f;
  const float* p = &src[((size_t)b * seqi + s) * TD + d0];
  for (int i = 0; i < n; ++i) {
    const float2 v = *(const float2*)p;
    s0 += v.x; s1 += v.y;
    p += TD;
  }
  const float inv = 1.f / (cf + 1e-10f);
  float2 o; o.x = s0 * inv; o.y = s1 * inv;
  *(float2*)&dst[((size_t)b * seqo + j) * TD + d0] = o;
}

__global__ __launch_bounds__(256)
void expand_kernel(const float* __restrict__ gout, float* __restrict__ dout,
                   const int* __restrict__ gmap, const int* __restrict__ mi)
{
  const int j = blockIdx.x;
  const int b = blockIdx.y;
  const int ntok = mi[MI_NTOK];
  if (j >= ntok) return;
  const int m2 = mi[MI_M2];
  const int g = gmap[j];
  const int d0 = threadIdx.x * 2;
  const float2 v = *(const float2*)&gout[((size_t)b * m2 + g) * TD + d0];
  *(float2*)&dout[((size_t)b * ntok + j) * TD + d0] = v;
}

// ---------------------------------------------------------------------------
extern "C" void kernel_launch(void* const* d_in, const int* in_sizes, int n_in,
                              void* d_out, int out_size, void* d_ws, size_t ws_size,
                              hipStream_t stream)
{
  const float* x   = (const float*)d_in[0];
  const float* cWi = (const float*)d_in[1];
  const float* cbi = (const float*)d_in[2];
  const float* cWo = (const float*)d_in[3];
  const float* cbo = (const float*)d_in[4];
  const float* bWi = (const float*)d_in[5];
  const float* bbi = (const float*)d_in[6];
  const float* bWo = (const float*)d_in[7];
  const float* bbo = (const float*)d_in[8];
  const float* gWi = (const float*)d_in[9];
  const float* gbi = (const float*)d_in[10];
  const float* gWo = (const float*)d_in[11];
  const float* gbo = (const float*)d_in[12];
  const float* mw  = (const float*)d_in[13];
  const float* mbv = (const float*)d_in[14];
  const float* gw  = (const float*)d_in[15];
  const float* gbv = (const float*)d_in[16];
  float* outf = (float*)d_out;

  char* wsb = (char*)d_ws;
  int*   mi     = (int*)(wsb);
  int*   start1 = (int*)(wsb + 1024);
  float* cnt1   = (float*)(wsb + 1024 + 8192);
  int*   start2 = (int*)(wsb + 1024 + 2 * 8192);
  float* cnt2   = (float*)(wsb + 1024 + 3 * 8192);
  int*   gmap   = (int*)(wsb + 1024 + 4 * 8192);
  float* l0     = (float*)(wsb + 65536);               // 32768 f32
  float* l1     = (float*)(wsb + 196608);              // 32768 f32
  _Float16* qkv = (_Float16*)(wsb + 458752);           // 4096x1536 f16 (12.6 MB)
  float* O0     = (float*)(wsb + 458752 + 12582912);   // 8 MB partial O
  float* O1     = O0 + 2097152;                        // 8 MB
  float* stg_o  = O1 + 2097152;                        // 8 MB
  float* stg_m  = stg_o + 2097152;                     // 8 MB

  const dim3 blk(256);

  meta_kernel<<<dim3(1), blk, 0, stream>>>(mw, mbv, gw, gbv, mi, start1, cnt1, start2, cnt2, gmap);

  // ---- char stage ----
  gemm_mfma<_Float16><<<dim3(24, 32), blk, 0, stream>>>(x, cWi, cbi, qkv, mi, MI_MCHAR, 1536);
  attn1_mfma<<<dim3(32, 16, KC), blk, 0, stream>>>(qkv, l0, l1, O0, O1, mi, MI_SEQC);
  attn2_mfma<<<dim3(16, 32, 2), blk, 0, stream>>>(qkv, l0, l1, outf, mi, MI_SEQC, MI_OFF_CW);
  gemm_norm_mfma<<<dim3(8, 32), blk, 0, stream>>>(O0, O1, l0, l1, cWo, cbo, stg_o, mi, MI_MCHAR, MI_SEQC);
  merge_kernel<<<dim3(2048, 2), blk, 0, stream>>>(stg_o, stg_m, start1, cnt1, mi, MI_SEQC, MI_SEQB);

  // ---- block stage ----
  gemm_mfma<_Float16><<<dim3(24, 32), blk, 0, stream>>>(stg_m, bWi, bbi, qkv, mi, MI_MBLOCK, 1536);
  attn1_mfma<<<dim3(32, 16, KC), blk, 0, stream>>>(qkv, l0, l1, O0, O1, mi, MI_SEQB);
  attn2_mfma<<<dim3(16, 32, 2), blk, 0, stream>>>(qkv, l0, l1, outf, mi, MI_SEQB, MI_OFF_BW);
  gemm_norm_mfma<<<dim3(8, 32), blk, 0, stream>>>(O0, O1, l0, l1, bWo, bbo, stg_o, mi, MI_MBLOCK, MI_SEQB);
  merge_kernel<<<dim3(2048, 2), blk, 0, stream>>>(stg_o, stg_m, start2, cnt2, mi, MI_SEQB, MI_SEQG);

  // ---- glob stage ----
  gemm_mfma<_Float16><<<dim3(24, 32), blk, 0, stream>>>(stg_m, gWi, gbi, qkv, mi, MI_MGLOB, 1536);
  attn1_mfma<<<dim3(32, 16, KC), blk, 0, stream>>>(qkv, l0, l1, O0, O1, mi, MI_SEQG);
  attn2_mfma<<<dim3(16, 32, 2), blk, 0, stream>>>(qkv, l0, l1, outf, mi, MI_SEQG, MI_OFF_GW);
  gemm_norm_mfma<<<dim3(8, 32), blk, 0, stream>>>(O0, O1, l0, l1, gWo, gbo, stg_o, mi, MI_MGLOB, MI_SEQG);
  expand_kernel<<<dim3(2048, 2), blk, 0, stream>>>(stg_o, outf, gmap, mi);

  (void)in_sizes; (void)n_in; (void)out_size; (void)ws_size;
}

// Round 9
// 450.255 us; speedup vs baseline: 3.4611x; 1.0156x over previous
//
#include <hip/hip_runtime.h>
#include <cstdint>
#include <cstddef>

// DynamicHierarchicalAttention — MFMA pipeline.
// R8: attn1 rewritten around the S^T trick: S^T = mfma(K,Q) leaves exp(S^T)
// in registers in EXACTLY the B-operand layout of mfma_f32_16x16x16_f16
// (k=quad*4+j, n=lane&15), so E feeds E@V directly from registers — the Es
// LDS round-trip (16 st + 10 rd per wave per tile) is gone.  Per-wave q=32
// (mp=2) amortizes K-fragment reads; O^T transposed back once per block via
// LDS epilogue.  qkv f16 (R5), split-K x2 (R6), GEMMs split-f16 (fp32-grade).

#define TB 2
#define TT 2048
#define TD 512
#define TH 8
#define THD 64
#define KC 2   // k-chunks in attn1

#define MI_M1 0
#define MI_M2 1
#define MI_NTOK 2
#define MI_OFF_CW 3
#define MI_OFF_BW 4
#define MI_OFF_GW 5
#define MI_MCHAR 6
#define MI_MBLOCK 7
#define MI_MGLOB 8
#define MI_SEQC 9
#define MI_SEQB 10
#define MI_SEQG 11

typedef _Float16 half8 __attribute__((ext_vector_type(8)));
typedef _Float16 half4 __attribute__((ext_vector_type(4)));
typedef _Float16 half2_t __attribute__((ext_vector_type(2)));
typedef float floatx4 __attribute__((ext_vector_type(4)));

__device__ __forceinline__ floatx4 mfma16(half8 a, half8 b, floatx4 c) {
  return __builtin_amdgcn_mfma_f32_16x16x32_f16(a, b, c, 0, 0, 0);
}
__device__ __forceinline__ floatx4 mfma16k16(half4 a, half4 b, floatx4 c) {
  return __builtin_amdgcn_mfma_f32_16x16x16f16(a, b, c, 0, 0, 0);
}

__device__ __forceinline__ double fracd(double x) { return x - floor(x); }

// ---------------------------------------------------------------------------
// parallel boundary scan for one phase: n elements, increment c.
// ---------------------------------------------------------------------------
__device__ int scan_phase(int n, double c, int* __restrict__ ids,
                          int* __restrict__ startg, float* __restrict__ cntg,
                          int* __restrict__ wsum, int t)
{
  int loc[8];
  const int base = t * 8;
#pragma unroll
  for (int j = 0; j < 8; ++j) {
    const int i = base + j;
    int f = 0;
    if (i < n) {
      const int pidx = (i == 0) ? n : i;   // roll: prev of elem 0 is elem n-1
      f = (fracd((double)(i + 1) * c) < fracd((double)pidx * c)) ? 1 : 0;
    }
    loc[j] = f + ((j > 0) ? loc[j - 1] : 0);
  }
  wsum[t] = loc[7];
  __syncthreads();
  for (int off = 1; off < 256; off <<= 1) {
    int u = 0;
    if (t >= off) u = wsum[t - off];
    __syncthreads();
    wsum[t] += u;
    __syncthreads();
  }
  const int excl = wsum[t] - loc[7];
  const int m = wsum[255];
#pragma unroll
  for (int j = 0; j < 8; ++j) {
    const int i = base + j;
    if (i < n) {
      const int id = excl + loc[j];
      ids[i] = id;
      const int f = loc[j] - ((j > 0) ? loc[j - 1] : 0);
      if (f) startg[id - 1] = i;
    }
  }
  __syncthreads();
  for (int j = t; j < m; j += 256)
    cntg[j] = (float)((((j + 1) < m) ? startg[j + 1] : n) - startg[j]);
  __syncthreads();
  return m;
}

// ---------------------------------------------------------------------------
__global__ __launch_bounds__(256)
void meta_kernel(const float* __restrict__ mw, const float* __restrict__ mb,
                 const float* __restrict__ gw, const float* __restrict__ gb,
                 int* __restrict__ mi,
                 int* __restrict__ start1, float* __restrict__ cnt1,
                 int* __restrict__ start2, float* __restrict__ cnt2,
                 int* __restrict__ gmap)
{
  __shared__ int ids1[TT];
  __shared__ int ids2[TT];
  __shared__ int wsum[256];
  __shared__ double dsh[256];
  const int t = threadIdx.x;

  double s1 = 0.0, s2 = 0.0;
  for (int i = t; i < TD; i += 256) { s1 += (double)mw[i]; s2 += (double)gw[i]; }
  dsh[t] = s1; __syncthreads();
  for (int off = 128; off > 0; off >>= 1) {
    if (t < off) dsh[t] += dsh[t + off];
    __syncthreads();
  }
  const double c1 = dsh[0] + (double)mb[0];
  __syncthreads();
  dsh[t] = s2; __syncthreads();
  for (int off = 128; off > 0; off >>= 1) {
    if (t < off) dsh[t] += dsh[t + off];
    __syncthreads();
  }
  const double c2 = dsh[0] + (double)gb[0];
  __syncthreads();

  const int m1 = scan_phase(TT, c1, ids1, start1, cnt1, wsum, t);
  const int m2 = scan_phase(m1, c2, ids2, start2, cnt2, wsum, t);

  int i0 = TT;
  if (m1 >= 1 && m2 >= 1) i0 = start1[start2[0]];
  const int ntok = TT - i0;

  if (t == 0) {
    mi[MI_M1] = m1; mi[MI_M2] = m2; mi[MI_NTOK] = ntok;
    const int offcw = TB * ntok * TD;
    mi[MI_OFF_CW] = offcw;
    mi[MI_OFF_BW] = offcw + TB * TT * TT;
    mi[MI_OFF_GW] = offcw + TB * TT * TT + TB * m1 * m1;
    mi[MI_MCHAR] = TB * TT;
    mi[MI_MBLOCK] = TB * m1;
    mi[MI_MGLOB] = TB * m2;
    mi[MI_SEQC] = TT;
    mi[MI_SEQB] = m1;
    mi[MI_SEQG] = m2;
  }
  for (int i = i0 + t; i < TT; i += 256)
    gmap[i - i0] = ids2[ids1[i] - 1] - 1;
}

// ---------------------------------------------------------------------------
// GEMM 128m x 64n tile: C[M,N] = A[M,512] @ W[N,512]^T + bias, split-f16.
// ---------------------------------------------------------------------------
template <typename OutT>
__global__ __launch_bounds__(256)
void gemm_mfma(const float* __restrict__ A, const float* __restrict__ W,
               const float* __restrict__ bias, OutT* __restrict__ C,
               const int* __restrict__ mi, int m_slot, int N)
{
  const int M = mi[m_slot];
  const int bm = blockIdx.y * 128;
  if (bm >= M) return;
  const int bn = blockIdx.x * 64;
  __shared__ _Float16 Ah[128][40];
  __shared__ _Float16 Al[128][40];
  __shared__ _Float16 Wh[64][40];
  __shared__ _Float16 Wl[64][40];

  const int t = threadIdx.x;
  const int wv = t >> 6;
  const int lane = t & 63;
  const int l15 = lane & 15;
  const int quad = lane >> 4;
  const int srowA = t >> 1;
  const int ssegA = (t & 1) * 16;
  const int srowW = t >> 2;
  const int ssegW = (t & 3) * 8;

  floatx4 acc[2][4];
#pragma unroll
  for (int i = 0; i < 2; ++i)
#pragma unroll
    for (int j = 0; j < 4; ++j) acc[i][j] = (floatx4){0.f, 0.f, 0.f, 0.f};

  for (int kk = 0; kk < TD; kk += 32) {
    __syncthreads();
    {
      const int ar = bm + srowA;
#pragma unroll
      for (int u = 0; u < 4; ++u) {
        float4 av = make_float4(0.f, 0.f, 0.f, 0.f);
        if (ar < M) av = *(const float4*)&A[(size_t)ar * TD + kk + ssegA + u * 4];
        const float aa[4] = {av.x, av.y, av.z, av.w};
        half4 hi, lo;
#pragma unroll
        for (int e = 0; e < 4; ++e) {
          const _Float16 h = (_Float16)aa[e];
          hi[e] = h; lo[e] = (_Float16)(aa[e] - (float)h);
        }
        *(half4*)&Ah[srowA][ssegA + u * 4] = hi;
        *(half4*)&Al[srowA][ssegA + u * 4] = lo;
      }
#pragma unroll
      for (int u = 0; u < 2; ++u) {
        const float4 wvv = *(const float4*)&W[(size_t)(bn + srowW) * TD + kk + ssegW + u * 4];
        const float ww[4] = {wvv.x, wvv.y, wvv.z, wvv.w};
        half4 hi, lo;
#pragma unroll
        for (int e = 0; e < 4; ++e) {
          const _Float16 h = (_Float16)ww[e];
          hi[e] = h; lo[e] = (_Float16)(ww[e] - (float)h);
        }
        *(half4*)&Wh[srowW][ssegW + u * 4] = hi;
        *(half4*)&Wl[srowW][ssegW + u * 4] = lo;
      }
    }
    __syncthreads();
    half8 ah[2], al[2];
#pragma unroll
    for (int mp = 0; mp < 2; ++mp) {
      ah[mp] = *(const half8*)&Ah[wv * 32 + mp * 16 + l15][quad * 8];
      al[mp] = *(const half8*)&Al[wv * 32 + mp * 16 + l15][quad * 8];
    }
#pragma unroll
    for (int np = 0; np < 4; ++np) {
      const half8 bh = *(const half8*)&Wh[np * 16 + l15][quad * 8];
      const half8 bl = *(const half8*)&Wl[np * 16 + l15][quad * 8];
#pragma unroll
      for (int mp = 0; mp < 2; ++mp) {
        acc[mp][np] = mfma16(al[mp], bh, acc[mp][np]);
        acc[mp][np] = mfma16(ah[mp], bl, acc[mp][np]);
        acc[mp][np] = mfma16(ah[mp], bh, acc[mp][np]);
      }
    }
  }
  float bv[4];
#pragma unroll
  for (int np = 0; np < 4; ++np) bv[np] = bias[bn + np * 16 + l15];
#pragma unroll
  for (int mp = 0; mp < 2; ++mp) {
#pragma unroll
    for (int r = 0; r < 4; ++r) {
      const int row = bm + wv * 32 + mp * 16 + quad * 4 + r;
      if (row < M) {
        OutT* cp = &C[(size_t)row * N + bn];
#pragma unroll
        for (int np = 0; np < 4; ++np)
          cp[np * 16 + l15] = (OutT)(acc[mp][np][r] + bv[np]);
      }
    }
  }
}

// ---------------------------------------------------------------------------
// Proj GEMM with fused combine: A-row = (O0+O1) * 1/(l0+l1) (per-head l).
// ---------------------------------------------------------------------------
__global__ __launch_bounds__(256)
void gemm_norm_mfma(const float* __restrict__ O0, const float* __restrict__ O1,
                    const float* __restrict__ l0, const float* __restrict__ l1,
                    const float* __restrict__ W, const float* __restrict__ bias,
                    float* __restrict__ C, const int* __restrict__ mi,
                    int m_slot, int seq_slot)
{
  const int M = mi[m_slot];
  const int bm = blockIdx.y * 128;
  if (bm >= M) return;
  const int seq = mi[seq_slot];
  const int bn = blockIdx.x * 64;
  __shared__ _Float16 Ah[128][40];
  __shared__ _Float16 Al[128][40];
  __shared__ _Float16 Wh[64][40];
  __shared__ _Float16 Wl[64][40];

  const int t = threadIdx.x;
  const int wv = t >> 6;
  const int lane = t & 63;
  const int l15 = lane & 15;
  const int quad = lane >> 4;
  const int srowA = t >> 1;
  const int ssegA = (t & 1) * 16;
  const int srowW = t >> 2;
  const int ssegW = (t & 3) * 8;

  const int ar = bm + srowA;
  const int ab = (ar >= seq) ? 1 : 0;
  const int aq = ar - ab * seq;

  floatx4 acc[2][4];
#pragma unroll
  for (int i = 0; i < 2; ++i)
#pragma unroll
    for (int j = 0; j < 4; ++j) acc[i][j] = (floatx4){0.f, 0.f, 0.f, 0.f};

  for (int kk = 0; kk < TD; kk += 32) {
    __syncthreads();
    {
      float linv = 0.f;
      if (ar < M) {
        const int h = kk >> 6;
        const size_t lidx = ((size_t)(ab * TH + h)) * 2048 + aq;
        linv = 1.f / (l0[lidx] + l1[lidx]);
      }
#pragma unroll
      for (int u = 0; u < 4; ++u) {
        float4 av = make_float4(0.f, 0.f, 0.f, 0.f);
        if (ar < M) {
          const size_t off = (size_t)ar * TD + kk + ssegA + u * 4;
          const float4 a0 = *(const float4*)&O0[off];
          const float4 a1 = *(const float4*)&O1[off];
          av.x = (a0.x + a1.x) * linv; av.y = (a0.y + a1.y) * linv;
          av.z = (a0.z + a1.z) * linv; av.w = (a0.w + a1.w) * linv;
        }
        const float aa[4] = {av.x, av.y, av.z, av.w};
        half4 hi, lo;
#pragma unroll
        for (int e = 0; e < 4; ++e) {
          const _Float16 h = (_Float16)aa[e];
          hi[e] = h; lo[e] = (_Float16)(aa[e] - (float)h);
        }
        *(half4*)&Ah[srowA][ssegA + u * 4] = hi;
        *(half4*)&Al[srowA][ssegA + u * 4] = lo;
      }
#pragma unroll
      for (int u = 0; u < 2; ++u) {
        const float4 wvv = *(const float4*)&W[(size_t)(bn + srowW) * TD + kk + ssegW + u * 4];
        const float ww[4] = {wvv.x, wvv.y, wvv.z, wvv.w};
        half4 hi, lo;
#pragma unroll
        for (int e = 0; e < 4; ++e) {
          const _Float16 h = (_Float16)ww[e];
          hi[e] = h; lo[e] = (_Float16)(ww[e] - (float)h);
        }
        *(half4*)&Wh[srowW][ssegW + u * 4] = hi;
        *(half4*)&Wl[srowW][ssegW + u * 4] = lo;
      }
    }
    __syncthreads();
    half8 ah[2], al[2];
#pragma unroll
    for (int mp = 0; mp < 2; ++mp) {
      ah[mp] = *(const half8*)&Ah[wv * 32 + mp * 16 + l15][quad * 8];
      al[mp] = *(const half8*)&Al[wv * 32 + mp * 16 + l15][quad * 8];
    }
#pragma unroll
    for (int np = 0; np < 4; ++np) {
      const half8 bh = *(const half8*)&Wh[np * 16 + l15][quad * 8];
      const half8 bl = *(const half8*)&Wl[np * 16 + l15][quad * 8];
#pragma unroll
      for (int mp = 0; mp < 2; ++mp) {
        acc[mp][np] = mfma16(al[mp], bh, acc[mp][np]);
        acc[mp][np] = mfma16(ah[mp], bl, acc[mp][np]);
        acc[mp][np] = mfma16(ah[mp], bh, acc[mp][np]);
      }
    }
  }
  float bv[4];
#pragma unroll
  for (int np = 0; np < 4; ++np) bv[np] = bias[bn + np * 16 + l15];
#pragma unroll
  for (int mp = 0; mp < 2; ++mp) {
#pragma unroll
    for (int r = 0; r < 4; ++r) {
      const int row = bm + wv * 32 + mp * 16 + quad * 4 + r;
      if (row < M) {
        float* cp = &C[(size_t)row * 512 + bn];
#pragma unroll
        for (int np = 0; np < 4; ++np)
          cp[np * 16 + l15] = acc[mp][np][r] + bv[np];
      }
    }
  }
}

// ---------------------------------------------------------------------------
// attn pass1, split-K (z = chunk), S^T-trick version.
// Block: q-tile 128 (4 waves x 32 q via mp=2).  Per k-tile:
//   S^T = mfma16x16x32(A=K-frag, B=Q-frag)  -> C-layout (k=quad*4+r, q=l15)
//   E = exp(S^T/8) packed half4            -> EXACTLY B-layout of 16x16x16
//   O^T[d][q] += mfma16x16x16(A=V^T-frag(b64 from LDS), B=E)
//   l[q]      += mfma16x16x16(A=ones, B=E)
// Epilogue: O^T -> O via per-wave LDS transpose (reuses K/V space).
// ---------------------------------------------------------------------------
__global__ __launch_bounds__(256)
void attn1_mfma(const _Float16* __restrict__ qkv,
                float* __restrict__ l0, float* __restrict__ l1,
                float* __restrict__ O0, float* __restrict__ O1,
                const int* __restrict__ mi, int seq_slot)
{
  const int seq = mi[seq_slot];
  const int q0 = blockIdx.x * 128;
  if (q0 >= seq) return;
  const int b = blockIdx.y >> 3, h = blockIdx.y & 7;
  const int z = blockIdx.z;
  float* lP = z ? l1 : l0;
  float* oP = z ? O1 : O0;
  const int t = threadIdx.x;
  const int wv = t >> 6;
  const int lane = t & 63;
  const int l15 = lane & 15;
  const int quad = lane >> 4;

  __shared__ __align__(16) char smem_raw[18432];
  _Float16 (*Kf)[72] = (_Float16 (*)[72])smem_raw;              // 64x72 f16
  _Float16 (*Vt)[72] = (_Float16 (*)[72])(smem_raw + 9216);     // 64x72 f16
  float    (*Ot)[68] = (float (*)[68])smem_raw;                 // epilogue reuse

  // Q B-fragments: lane n=q=l15 of this mp-tile, k(d)=c*32+quad*8+j
  half8 qB[2][2];
#pragma unroll
  for (int mp = 0; mp < 2; ++mp) {
    const int qrow = q0 + wv * 32 + mp * 16 + l15;
#pragma unroll
    for (int c = 0; c < 2; ++c) {
      half8 v = {};
      if (qrow < seq)
        v = *(const half8*)&qkv[((size_t)(b * seq + qrow)) * 1536 + h * 64 + c * 32 + quad * 8];
      qB[mp][c] = v;
    }
  }
  half4 onesA;
#pragma unroll
  for (int j = 0; j < 4; ++j) onesA[j] = (_Float16)1.0f;

  floatx4 oacc[2][4];   // [mp][dblk] — O^T values at (d=dblk*16+quad*4+r, q=l15)
#pragma unroll
  for (int i = 0; i < 2; ++i)
#pragma unroll
    for (int j = 0; j < 4; ++j) oacc[i][j] = (floatx4){0.f, 0.f, 0.f, 0.f};
  floatx4 lacc[2] = {(floatx4){0.f, 0.f, 0.f, 0.f}, (floatx4){0.f, 0.f, 0.f, 0.f}};

  const int nkt = (seq + 63) >> 6;
  const int nkc = (nkt + KC - 1) / KC;
  const int kt_beg = z * nkc;
  const int kt_end = min(kt_beg + nkc, nkt);

  for (int kt = kt_beg; kt < kt_end; ++kt) {
    const int k0 = kt * 64;
    __syncthreads();
    { // stage K [64][64]: thread row t>>2, 16 d at seg
      const int row = t >> 2;
      const int seg = (t & 3) * 16;
      const int kg = k0 + row;
      half8 v0 = {}, v1 = {};
      if (kg < seq) {
        const _Float16* base = &qkv[((size_t)(b * seq + kg)) * 1536 + 512 + h * 64 + seg];
        v0 = *(const half8*)base;
        v1 = *(const half8*)(base + 8);
      }
      *(half8*)&Kf[row][seg] = v0;
      *(half8*)&Kf[row][seg + 8] = v1;
    }
    { // stage V transposed: pair-packed b32 stores
      const int tp = lane & 31;
      const int dsel = lane >> 5;
      const int dbase = wv * 16 + dsel * 8;
      const int kg0 = k0 + tp * 2;
      half8 vA = {}, vB = {};
      if (kg0 < seq)
        vA = *(const half8*)&qkv[((size_t)(b * seq + kg0)) * 1536 + 1024 + h * 64 + dbase];
      if (kg0 + 1 < seq)
        vB = *(const half8*)&qkv[((size_t)(b * seq + kg0 + 1)) * 1536 + 1024 + h * 64 + dbase];
#pragma unroll
      for (int j = 0; j < 8; ++j) {
        half2_t pk; pk[0] = vA[j]; pk[1] = vB[j];
        *(half2_t*)&Vt[dbase + j][tp * 2] = pk;
      }
    }
    __syncthreads();

#pragma unroll
    for (int p = 0; p < 4; ++p) {
      // S^T tile for both mp
      floatx4 sT[2] = {(floatx4){0.f, 0.f, 0.f, 0.f}, (floatx4){0.f, 0.f, 0.f, 0.f}};
#pragma unroll
      for (int c = 0; c < 2; ++c) {
        const half8 kA = *(const half8*)&Kf[p * 16 + l15][c * 32 + quad * 8];
#pragma unroll
        for (int mp = 0; mp < 2; ++mp)
          sT[mp] = mfma16(kA, qB[mp][c], sT[mp]);
      }
      // V^T fragments for this p (shared across mp)
      half4 vA[4];
#pragma unroll
      for (int dblk = 0; dblk < 4; ++dblk)
        vA[dblk] = *(const half4*)&Vt[dblk * 16 + l15][p * 16 + quad * 4];
      const int kg = k0 + p * 16 + quad * 4;
#pragma unroll
      for (int mp = 0; mp < 2; ++mp) {
        half4 eB;
#pragma unroll
        for (int r = 0; r < 4; ++r) {
          const float e = (kg + r < seq) ? __expf(sT[mp][r] * 0.125f) : 0.f;
          eB[r] = (_Float16)e;
        }
        lacc[mp] = mfma16k16(onesA, eB, lacc[mp]);
#pragma unroll
        for (int dblk = 0; dblk < 4; ++dblk)
          oacc[mp][dblk] = mfma16k16(vA[dblk], eB, oacc[mp][dblk]);
      }
    }
  }

  __syncthreads();   // K/V LDS no longer needed by any wave — safe to reuse as Ot

  // Epilogue: per-wave O^T -> O transpose through LDS, coalesced global write.
#pragma unroll
  for (int mp = 0; mp < 2; ++mp) {
#pragma unroll
    for (int dblk = 0; dblk < 4; ++dblk)
      *(floatx4*)&Ot[wv * 16 + l15][dblk * 16 + quad * 4] = oacc[mp][dblk];
    const int ql = lane >> 2;
    const int dseg = (lane & 3) * 4;
    const int qg = q0 + wv * 32 + mp * 16 + ql;
    if (qg < seq) {
      float* op = &oP[((size_t)(b * seq + qg)) * 512 + h * 64];
#pragma unroll
      for (int u = 0; u < 4; ++u)
        *(float4*)(op + u * 16 + dseg) = *(const float4*)&Ot[wv * 16 + ql][u * 16 + dseg];
    }
    if (quad == 0) {
      const int qg2 = q0 + wv * 32 + mp * 16 + l15;
      if (qg2 < seq)
        lP[((size_t)(b * TH + h)) * 2048 + qg2] = lacc[mp][0];
    }
  }
}

// ---------------------------------------------------------------------------
// attn pass2 (plain f16 MFMA), q-tile 64 x k-tile 128; Linv = 1/(l0+l1).
// ---------------------------------------------------------------------------
__global__ __launch_bounds__(256)
void attn2_mfma(const _Float16* __restrict__ qkv,
                const float* __restrict__ l0, const float* __restrict__ l1,
                float* __restrict__ outb, const int* __restrict__ mi,
                int seq_slot, int off_slot)
{
  const int seq = mi[seq_slot];
  const int q0 = blockIdx.y * 64;
  const int k0 = blockIdx.x * 128;
  if (q0 >= seq || k0 >= seq) return;
  const int b = blockIdx.z;
  const int woff = mi[off_slot];
  float* wout = outb + (size_t)woff + (size_t)b * seq * seq;

  __shared__ _Float16 Qs[64][72];
  __shared__ _Float16 Ksh[128][72];
  __shared__ float Linv[64];

  const int t = threadIdx.x;
  const int wv = t >> 6;
  const int lane = t & 63;
  const int l15 = lane & 15;
  const int quad = lane >> 4;
  const int srowQ = t >> 2;
  const int ssegQ = (t & 3) * 16;
  const int srowK = t >> 1;
  const int ssegK = (t & 1) * 32;

  floatx4 acc[8];
#pragma unroll
  for (int j = 0; j < 8; ++j) acc[j] = (floatx4){0.f, 0.f, 0.f, 0.f};

  for (int h = 0; h < TH; ++h) {
    __syncthreads();
    {
      const int qr = q0 + srowQ;
      half8 q0v = {}, q1v = {};
      if (qr < seq) {
        const _Float16* base = &qkv[((size_t)(b * seq + qr)) * 1536 + h * 64 + ssegQ];
        q0v = *(const half8*)base;
        q1v = *(const half8*)(base + 8);
      }
      *(half8*)&Qs[srowQ][ssegQ] = q0v;
      *(half8*)&Qs[srowQ][ssegQ + 8] = q1v;

      const int kr = k0 + srowK;
#pragma unroll
      for (int u = 0; u < 4; ++u) {
        half8 kv = {};
        if (kr < seq)
          kv = *(const half8*)&qkv[((size_t)(b * seq + kr)) * 1536 + 512 + h * 64 + ssegK + u * 8];
        *(half8*)&Ksh[srowK][ssegK + u * 8] = kv;
      }
      if (t < 64) {
        float lv = 1.f;
        if (q0 + t < seq) {
          const size_t lidx = ((size_t)(b * TH + h)) * 2048 + q0 + t;
          lv = l0[lidx] + l1[lidx];
        }
        Linv[t] = 1.f / lv;
      }
    }
    __syncthreads();

    half8 af[2];
#pragma unroll
    for (int c = 0; c < 2; ++c)
      af[c] = *(const half8*)&Qs[wv * 16 + l15][c * 32 + quad * 8];
    float lv[4];
#pragma unroll
    for (int r = 0; r < 4; ++r)
      lv[r] = Linv[wv * 16 + quad * 4 + r];

#pragma unroll
    for (int np = 0; np < 8; ++np) {
      half8 bf[2];
#pragma unroll
      for (int c = 0; c < 2; ++c)
        bf[c] = *(const half8*)&Ksh[np * 16 + l15][c * 32 + quad * 8];
      floatx4 s = (floatx4){0.f, 0.f, 0.f, 0.f};
      s = mfma16(af[0], bf[0], s);
      s = mfma16(af[1], bf[1], s);
#pragma unroll
      for (int r = 0; r < 4; ++r)
        acc[np][r] += __expf(s[r] * 0.125f) * lv[r];
    }
  }

#pragma unroll
  for (int r = 0; r < 4; ++r) {
    const int qg = q0 + wv * 16 + quad * 4 + r;
    if (qg >= seq) continue;
    float* rowp = wout + (size_t)qg * seq;
#pragma unroll
    for (int np = 0; np < 8; ++np) {
      const int col = k0 + np * 16 + l15;
      if (col < seq) rowp[col] = acc[np][r] * 0.125f;
    }
  }
}

// ---------------------------------------------------------------------------
__global__ __launch_bounds__(256)
void merge_kernel(const float* __restrict__ src, float* __restrict__ dst,
                  const int* __restrict__ start, const float* __restrict__ cnt,
                  const int* __restrict__ mi, int seqin_slot, int seqout_slot)
{
  const int j = blockIdx.x;
  const int b = blockIdx.y;
  const int seqo = mi[seqout_slot];
  if (j >= seqo) return;
  const int seqi = mi[seqin_slot];
  const int s = start[j];
  const float cf = cnt[j];
  const int n = (int)cf;
  const int d0 = threadIdx.x * 2;
  float s0 = 0.f, s1 = 0.f;
  const float* p = &src[((size_t)b * seqi + s) * TD + d0];
  for (int i = 0; i < n; ++i) {
    const float2 v = *(const float2*)p;
    s0 += v.x; s1 += v.y;
    p += TD;
  }
  const float inv = 1.f / (cf + 1e-10f);
  float2 o; o.x = s0 * inv; o.y = s1 * inv;
  *(float2*)&dst[((size_t)b * seqo + j) * TD + d0] = o;
}

__global__ __launch_bounds__(256)
void expand_kernel(const float* __restrict__ gout, float* __restrict__ dout,
                   const int* __restrict__ gmap, const int* __restrict__ mi)
{
  const int j = blockIdx.x;
  const int b = blockIdx.y;
  const int ntok = mi[MI_NTOK];
  if (j >= ntok) return;
  const int m2 = mi[MI_M2];
  const int g = gmap[j];
  const int d0 = threadIdx.x * 2;
  const float2 v = *(const float2*)&gout[((size_t)b * m2 + g) * TD + d0];
  *(float2*)&dout[((size_t)b * ntok + j) * TD + d0] = v;
}

// ---------------------------------------------------------------------------
extern "C" void kernel_launch(void* const* d_in, const int* in_sizes, int n_in,
                              void* d_out, int out_size, void* d_ws, size_t ws_size,
                              hipStream_t stream)
{
  const float* x   = (const float*)d_in[0];
  const float* cWi = (const float*)d_in[1];
  const float* cbi = (const float*)d_in[2];
  const float* cWo = (const float*)d_in[3];
  const float* cbo = (const float*)d_in[4];
  const float* bWi = (const float*)d_in[5];
  const float* bbi = (const float*)d_in[6];
  const float* bWo = (const float*)d_in[7];
  const float* bbo = (const float*)d_in[8];
  const float* gWi = (const float*)d_in[9];
  const float* gbi = (const float*)d_in[10];
  const float* gWo = (const float*)d_in[11];
  const float* gbo = (const float*)d_in[12];
  const float* mw  = (const float*)d_in[13];
  const float* mbv = (const float*)d_in[14];
  const float* gw  = (const float*)d_in[15];
  const float* gbv = (const float*)d_in[16];
  float* outf = (float*)d_out;

  char* wsb = (char*)d_ws;
  int*   mi     = (int*)(wsb);
  int*   start1 = (int*)(wsb + 1024);
  float* cnt1   = (float*)(wsb + 1024 + 8192);
  int*   start2 = (int*)(wsb + 1024 + 2 * 8192);
  float* cnt2   = (float*)(wsb + 1024 + 3 * 8192);
  int*   gmap   = (int*)(wsb + 1024 + 4 * 8192);
  float* l0     = (float*)(wsb + 65536);               // 32768 f32
  float* l1     = (float*)(wsb + 196608);              // 32768 f32
  _Float16* qkv = (_Float16*)(wsb + 458752);           // 4096x1536 f16 (12.6 MB)
  float* O0     = (float*)(wsb + 458752 + 12582912);   // 8 MB partial O
  float* O1     = O0 + 2097152;                        // 8 MB
  float* stg_o  = O1 + 2097152;                        // 8 MB
  float* stg_m  = stg_o + 2097152;                     // 8 MB

  const dim3 blk(256);

  meta_kernel<<<dim3(1), blk, 0, stream>>>(mw, mbv, gw, gbv, mi, start1, cnt1, start2, cnt2, gmap);

  // ---- char stage ----
  gemm_mfma<_Float16><<<dim3(24, 32), blk, 0, stream>>>(x, cWi, cbi, qkv, mi, MI_MCHAR, 1536);
  attn1_mfma<<<dim3(16, 16, KC), blk, 0, stream>>>(qkv, l0, l1, O0, O1, mi, MI_SEQC);
  attn2_mfma<<<dim3(16, 32, 2), blk, 0, stream>>>(qkv, l0, l1, outf, mi, MI_SEQC, MI_OFF_CW);
  gemm_norm_mfma<<<dim3(8, 32), blk, 0, stream>>>(O0, O1, l0, l1, cWo, cbo, stg_o, mi, MI_MCHAR, MI_SEQC);
  merge_kernel<<<dim3(2048, 2), blk, 0, stream>>>(stg_o, stg_m, start1, cnt1, mi, MI_SEQC, MI_SEQB);

  // ---- block stage ----
  gemm_mfma<_Float16><<<dim3(24, 32), blk, 0, stream>>>(stg_m, bWi, bbi, qkv, mi, MI_MBLOCK, 1536);
  attn1_mfma<<<dim3(16, 16, KC), blk, 0, stream>>>(qkv, l0, l1, O0, O1, mi, MI_SEQB);
  attn2_mfma<<<dim3(16, 32, 2), blk, 0, stream>>>(qkv, l0, l1, outf, mi, MI_SEQB, MI_OFF_BW);
  gemm_norm_mfma<<<dim3(8, 32), blk, 0, stream>>>(O0, O1, l0, l1, bWo, bbo, stg_o, mi, MI_MBLOCK, MI_SEQB);
  merge_kernel<<<dim3(2048, 2), blk, 0, stream>>>(stg_o, stg_m, start2, cnt2, mi, MI_SEQB, MI_SEQG);

  // ---- glob stage ----
  gemm_mfma<_Float16><<<dim3(24, 32), blk, 0, stream>>>(stg_m, gWi, gbi, qkv, mi, MI_MGLOB, 1536);
  attn1_mfma<<<dim3(16, 16, KC), blk, 0, stream>>>(qkv, l0, l1, O0, O1, mi, MI_SEQG);
  attn2_mfma<<<dim3(16, 32, 2), blk, 0, stream>>>(qkv, l0, l1, outf, mi, MI_SEQG, MI_OFF_GW);
  gemm_norm_mfma<<<dim3(8, 32), blk, 0, stream>>>(O0, O1, l0, l1, gWo, gbo, stg_o, mi, MI_MGLOB, MI_SEQG);
  expand_kernel<<<dim3(2048, 2), blk, 0, stream>>>(stg_o, outf, gmap, mi);

  (void)in_sizes; (void)n_in; (void)out_size; (void)ws_size;
}